// Round 2
// baseline (2023.250 us; speedup 1.0000x reference)
//
#include <hip/hip_runtime.h>
#include <hip/hip_bf16.h>
#include <math.h>

typedef __hip_bfloat16 bf16;

#define Bv 2
#define Cv 96
#define Hv 128
#define Wv 128
#define Pv (Hv*Wv)          /* 16384 */
#define Gv 12
#define Kv 9

__device__ __forceinline__ float b2f(bf16 x) { return __bfloat162float(x); }
__device__ __forceinline__ bf16 f2b(float x) { return __float2bfloat16(x); }

// dual-dtype input load: isf=1 -> float32, isf=0 -> bf16
__device__ __forceinline__ float ldin(const void* p, size_t i, int isf) {
    return isf ? ((const float*)p)[i] : __bfloat162float(((const bf16*)p)[i]);
}
__device__ __forceinline__ float tof(float x) { return x; }
__device__ __forceinline__ float tof(bf16 x) { return __bfloat162float(x); }
__device__ __forceinline__ void sto(float* p, size_t i, float v) { p[i] = v; }
__device__ __forceinline__ void sto(bf16*  p, size_t i, float v) { p[i] = f2b(v); }

// ---------------------------------------------------------------------------
// dtype detection: f32 data read as bf16 shows NaN/Inf bit patterns in the
// low halves (~1/256 of them); genuine bf16 from N(0,1) never does.
// ---------------------------------------------------------------------------
__global__ void detect_dtype(const unsigned short* __restrict__ x, int* __restrict__ flag)
{
    __shared__ int bad;
    if (threadIdx.x == 0) bad = 0;
    __syncthreads();
    int cnt = 0;
    for (int i = threadIdx.x; i < 32768; i += 256) {
        unsigned short u = x[i];
        if ((u & 0x7F80) == 0x7F80) cnt++;
    }
    atomicAdd(&bad, cnt);
    __syncthreads();
    if (threadIdx.x == 0) flag[0] = (bad > 0) ? 1 : 0;   // 1 = float32 inputs
}

// ---------------------------------------------------------------------------
// prep: convert all inputs the hot kernels need into f32 (or bf16) workspace.
// ---------------------------------------------------------------------------
__global__ void prep_all(const int* __restrict__ flag,
    const void* ft, const void* fkv, const void* flow,
    const void* cw1, const void* cb1, const void* a1,
    const void* cw2, const void* cb2, const void* a2,
    const void* cw3, const void* cb3,
    const void* wq, const void* bq, const void* wk, const void* bk,
    const void* wv, const void* bv, const void* wo, const void* bo,
    const void* wm1, const void* bm1, const void* wm2, const void* bm2,
    float* __restrict__ ftf, float* __restrict__ fkvcl, float* __restrict__ flowf,
    float* __restrict__ cw1f, float* __restrict__ cw2f, float* __restrict__ cw3f,
    float* __restrict__ wqT, float* __restrict__ woT,
    bf16* __restrict__ wkTb, bf16* __restrict__ wvTb,
    float* __restrict__ wm1f, float* __restrict__ wm2f, float* __restrict__ biasf)
{
    int isf = flag[0];
    size_t i = (size_t)blockIdx.x * 256 + threadIdx.x;
    if (i < (size_t)Bv*Cv*Pv) {
        ftf[i] = ldin(ft, i, isf);
        // channel-last feat_kv for the deformable gather
        int c = (int)(i % 96);
        size_t rest = i / 96;
        int p = (int)(rest & (Pv-1));
        int b = (int)(rest >> 14);
        fkvcl[i] = ldin(fkv, ((size_t)(b*96 + c))*Pv + p, isf);
    }
    if (i < (size_t)Bv*2*Pv) flowf[i] = ldin(flow, i, isf);
    if (i < 192*194*9) cw1f[i] = ldin(cw1, i, isf);
    if (i < 96*192*9)  cw2f[i] = ldin(cw2, i, isf);
    if (i < 216*96*9)  cw3f[i] = ldin(cw3, i, isf);
    if (i < 96*96) {
        int co = (int)(i % 96), ci = (int)(i / 96);
        size_t j = (size_t)co*96 + ci;          // src [out][in] -> dst [in][out]
        wqT[i]  = ldin(wq, j, isf);
        woT[i]  = ldin(wo, j, isf);
        wkTb[i] = f2b(ldin(wk, j, isf));
        wvTb[i] = f2b(ldin(wv, j, isf));
    }
    if (i < 192*96) { wm1f[i] = ldin(wm1, i, isf); wm2f[i] = ldin(wm2, i, isf); }
    if (i < 192) biasf[i]       = ldin(cb1, i, isf);
    if (i < 192) biasf[192+i]   = ldin(a1, i, isf);
    if (i < 96)  biasf[384+i]   = ldin(cb2, i, isf);
    if (i < 96)  biasf[480+i]   = ldin(a2, i, isf);
    if (i < 216) biasf[576+i]   = ldin(cb3, i, isf);
    if (i < 96) {
        biasf[792+i]  = ldin(bq, i, isf);
        biasf[888+i]  = ldin(bk, i, isf);
        biasf[984+i]  = ldin(bv, i, isf);
        biasf[1080+i] = ldin(bo, i, isf);
        biasf[1368+i] = ldin(bm2, i, isf);
    }
    if (i < 192) biasf[1176+i] = ldin(bm1, i, isf);
}

// ---------------------------------------------------------------------------
// cat[b][194][P] bf16: ch 0..95 feat_t, 96..191 flow-warped feat_kv, 192..193 flow
// ---------------------------------------------------------------------------
__global__ void build_cat(const int* __restrict__ flag, const float* __restrict__ ftf,
                          const void* fkv, const float* __restrict__ flowf,
                          bf16* __restrict__ cat)
{
    size_t idx = (size_t)blockIdx.x * 256 + threadIdx.x;
    if (idx >= (size_t)Bv*194*Pv) return;
    int p  = (int)(idx & (Pv-1));
    int t  = (int)(idx >> 14);
    int ch = t % 194, bb = t / 194;
    float v;
    if (ch < 96) {
        v = ftf[((size_t)bb*Cv + ch)*Pv + p];
    } else if (ch < 192) {
        int isf = flag[0];
        int cc = ch - 96;
        int py = p >> 7, px = p & (Wv-1);
        float xs = (float)px + flowf[((size_t)bb*2 + 0)*Pv + p];
        float ys = (float)py + flowf[((size_t)bb*2 + 1)*Pv + p];
        float x0f = floorf(xs), y0f = floorf(ys);
        float wx = xs - x0f, wy = ys - y0f;
        int x0 = (int)x0f, y0 = (int)y0f;
        size_t base = ((size_t)bb*Cv + cc)*Pv;
        v = 0.f;
        #pragma unroll
        for (int tt = 0; tt < 4; tt++) {
            int xi = x0 + (tt & 1), yi = y0 + (tt >> 1);
            float wt = ((tt & 1) ? wx : 1.f - wx) * ((tt >> 1) ? wy : 1.f - wy);
            if (xi >= 0 && xi < Wv && yi >= 0 && yi < Hv)
                v += wt * ldin(fkv, base + yi*Wv + xi, isf);
        }
    } else {
        v = flowf[((size_t)bb*2 + (ch-192))*Pv + p];
    }
    cat[idx] = f2b(v);
}

// ---------------------------------------------------------------------------
// 3x3 conv, LDS row staging, COG output channels per thread.
// MODE: 1 = PReLU, layout [b][co][P]; 2 = plain, pixel-major [b*P+p][OC]
// ---------------------------------------------------------------------------
template<typename TI, typename TO, int CIN, int COG, int MODE>
__launch_bounds__(128)
__global__ void conv3x3(const TI* __restrict__ in, const float* __restrict__ wgt,
                        const float* __restrict__ bias, const float* __restrict__ alpha,
                        TO* __restrict__ out, int OC)
{
    int x = threadIdx.x;
    int y = blockIdx.x, cog = blockIdx.y, bb = blockIdx.z;
    int co0 = cog * COG;
    const TI* inb = in + (size_t)bb * CIN * Pv;
    __shared__ float buf[2][3*130];
    float acc[COG];
    #pragma unroll
    for (int i = 0; i < COG; i++) acc[i] = 0.f;

    auto stage = [&](int ci) {
        float* dst = buf[ci & 1];
        const TI* src = inb + (size_t)ci * Pv;
        for (int i = x; i < 390; i += 128) {
            int r = i / 130;
            int xx = i - r*130 - 1;
            int yy = y + r - 1;
            float v = 0.f;
            if (xx >= 0 && xx < Wv && yy >= 0 && yy < Hv) v = tof(src[yy*Wv + xx]);
            dst[i] = v;
        }
    };
    stage(0);
    __syncthreads();
    for (int ci = 0; ci < CIN; ci++) {
        if (ci + 1 < CIN) stage(ci + 1);
        const float* cur = buf[ci & 1];
        float n[9];
        #pragma unroll
        for (int r = 0; r < 3; r++)
            #pragma unroll
            for (int d = 0; d < 3; d++)
                n[r*3+d] = cur[r*130 + x + d];
        const float* wp = wgt + ((size_t)co0 * CIN + ci) * 9;
        #pragma unroll
        for (int co = 0; co < COG; co++) {
            const float* w9 = wp + (size_t)co * CIN * 9;
            float a = acc[co];
            #pragma unroll
            for (int t = 0; t < 9; t++) a += n[t] * w9[t];
            acc[co] = a;
        }
        __syncthreads();
    }
    int p = y * Wv + x;
    #pragma unroll
    for (int co = 0; co < COG; co++) {
        float v = acc[co] + bias[co0+co];
        if (MODE == 1) { float a = alpha[co0+co]; v = (v >= 0.f) ? v : a*v; }
        if (MODE == 2) sto(out, ((size_t)bb*Pv + p)*OC + co0 + co, v);
        else           sto(out, ((size_t)bb*OC + co0 + co)*Pv + p, v);
    }
}

// ---------------------------------------------------------------------------
// Fused deformable sampling + attention + output projection + residual.
// Block = 192 threads = 2 pixels x 96 channel-lanes. Wk/Wv (transposed, bf16)
// in LDS; sampled values in LDS; softmax in registers via 8-lane shfl_xor
// (head groups are lane-aligned: 96 % 8 == 0, waves are full).
// ---------------------------------------------------------------------------
__launch_bounds__(192)
__global__ void attn_kernel(const float* __restrict__ ftf, const float* __restrict__ flowf,
    const float* __restrict__ fkvcl, const bf16* __restrict__ off3,
    const bf16* __restrict__ wkTb, const bf16* __restrict__ wvTb,
    const float* __restrict__ wqT, const float* __restrict__ woT,
    const float* __restrict__ bqf, const float* __restrict__ bkf,
    const float* __restrict__ bvf, const float* __restrict__ bof,
    float* __restrict__ xbuf)
{
    __shared__ bf16 wk_s[96*96];
    __shared__ bf16 wv_s[96*96];
    __shared__ float s_s[2][96][12];
    __shared__ float ft_s[2][96];
    __shared__ float o_s[2][96];

    int tid = threadIdx.x;
    for (int i = tid; i < 96*96; i += 192) { wk_s[i] = wkTb[i]; wv_s[i] = wvTb[i]; }
    int u = tid / 96;
    int c = tid - u*96;
    int g = c >> 3;
    float bqc = bqf[c], bkc = bkf[c], bvc = bvf[c], boc = bof[c];
    __syncthreads();

    const int npair = (Bv*Pv) / 2;   // 16384
    for (int pair = blockIdx.x; pair < npair; pair += gridDim.x) {
        int gp = pair*2 + u;
        int bb = gp >> 14;
        int p  = gp & (Pv-1);
        int py = p >> 7, px = p & (Wv-1);
        float fx = flowf[((size_t)bb*2 + 0)*Pv + p];
        float fy = flowf[((size_t)bb*2 + 1)*Pv + p];
        const bf16* offp = off3 + (size_t)gp * 216 + g*18;
        const float* fkv = fkvcl + ((size_t)bb*Pv)*96 + c;

        // --- deformable 3x3 sampling for this (pixel, channel) ---
        #pragma unroll
        for (int k = 0; k < Kv; k++) {
            float dy = b2f(offp[2*k])   + fy;
            float dx = b2f(offp[2*k+1]) + fx;
            float sx = (float)(px + (k % 3) - 1) + dx;
            float sy = (float)(py + (k / 3) - 1) + dy;
            float x0f = floorf(sx), y0f = floorf(sy);
            float wx = sx - x0f, wy = sy - y0f;
            int x0 = (int)x0f, y0 = (int)y0f;
            float v = 0.f;
            #pragma unroll
            for (int t = 0; t < 4; t++) {
                int xi = x0 + (t & 1), yi = y0 + (t >> 1);
                float wt = ((t & 1) ? wx : 1.f - wx) * ((t >> 1) ? wy : 1.f - wy);
                if (xi >= 0 && xi < Wv && yi >= 0 && yi < Hv)
                    v += wt * fkv[(size_t)(yi*Wv + xi)*96];
            }
            s_s[u][c][k] = v;
        }
        float ftv = ftf[((size_t)bb*Cv + c)*Pv + p];
        ft_s[u][c] = ftv;
        __syncthreads();

        // --- q / k / v projections ---
        float kacc[9], vacc[9];
        #pragma unroll
        for (int k = 0; k < 9; k++) { kacc[k] = 0.f; vacc[k] = 0.f; }
        float qv = 0.f;
        for (int cp = 0; cp < 96; cp++) {
            const float4* sp = (const float4*)&s_s[u][cp][0];
            float4 s0 = sp[0], s1 = sp[1];
            float s8 = s_s[u][cp][8];
            float sv[9] = {s0.x, s0.y, s0.z, s0.w, s1.x, s1.y, s1.z, s1.w, s8};
            float wkv = b2f(wk_s[cp*96 + c]);
            float wvv = b2f(wv_s[cp*96 + c]);
            qv += wqT[cp*96 + c] * ft_s[u][cp];
            #pragma unroll
            for (int k = 0; k < 9; k++) {
                kacc[k] += wkv * sv[k];
                vacc[k] += wvv * sv[k];
            }
        }
        qv += bqc;

        // --- logits: reduce q.k over the 8 channels of this head (lane-aligned) ---
        float lg[9];
        #pragma unroll
        for (int k = 0; k < 9; k++) {
            float pr = qv * (kacc[k] + bkc);
            pr += __shfl_xor(pr, 1);
            pr += __shfl_xor(pr, 2);
            pr += __shfl_xor(pr, 4);
            lg[k] = pr * 0.35355339059327373f;   // 1/sqrt(8)
        }
        float m = lg[0];
        #pragma unroll
        for (int k = 1; k < 9; k++) m = fmaxf(m, lg[k]);
        float sum = 0.f;
        #pragma unroll
        for (int k = 0; k < 9; k++) { lg[k] = __expf(lg[k] - m); sum += lg[k]; }
        float inv = 1.f / sum;
        float ov = 0.f;
        #pragma unroll
        for (int k = 0; k < 9; k++) ov += (lg[k] * inv) * (vacc[k] + bvc);

        o_s[u][c] = ov;
        __syncthreads();

        // --- output projection + residual ---
        float xv = ftv + boc;
        for (int cp = 0; cp < 96; cp++)
            xv += woT[cp*96 + c] * o_s[u][cp];
        xbuf[((size_t)bb*Cv + c)*Pv + p] = xv;
        __syncthreads();
    }
}

// ---------------------------------------------------------------------------
// MLP (1x1 convs)
// ---------------------------------------------------------------------------
__launch_bounds__(128)
__global__ void mlp1_kernel(const float* __restrict__ xbuf, const float* __restrict__ wm1f,
                            const float* __restrict__ bm1, float* __restrict__ hidden)
{
    const int COG = 16;
    int x = threadIdx.x;
    int y = blockIdx.x, cog = blockIdx.y, bb = blockIdx.z;
    int co0 = cog * COG;
    int p = y * Wv + x;
    const float* xb = xbuf + (size_t)bb*Cv*Pv + p;
    float acc[COG];
    #pragma unroll
    for (int i = 0; i < COG; i++) acc[i] = 0.f;
    for (int ci = 0; ci < Cv; ci++) {
        float v = xb[(size_t)ci*Pv];
        #pragma unroll
        for (int co = 0; co < COG; co++) acc[co] += wm1f[(size_t)(co0+co)*Cv + ci] * v;
    }
    float* hb = hidden + (size_t)bb*(2*Cv)*Pv + p;
    #pragma unroll
    for (int co = 0; co < COG; co++) {
        float h = acc[co] + bm1[co0+co];
        float g = 0.5f*h*(1.f + tanhf(0.7978845608028654f*(h + 0.044715f*h*h*h)));
        hb[(size_t)(co0+co)*Pv] = g;
    }
}

__launch_bounds__(128)
__global__ void mlp2_kernel(const int* __restrict__ flag,
                            const float* __restrict__ hidden, const float* __restrict__ xbuf,
                            const float* __restrict__ wm2f, const float* __restrict__ bm2,
                            void* __restrict__ out)
{
    const int COG = 16;
    int x = threadIdx.x;
    int y = blockIdx.x, cog = blockIdx.y, bb = blockIdx.z;
    int co0 = cog * COG;
    int p = y * Wv + x;
    const float* hb = hidden + (size_t)bb*(2*Cv)*Pv + p;
    float acc[COG];
    #pragma unroll
    for (int i = 0; i < COG; i++) acc[i] = 0.f;
    for (int ci = 0; ci < 2*Cv; ci++) {
        float v = hb[(size_t)ci*Pv];
        #pragma unroll
        for (int co = 0; co < COG; co++) acc[co] += wm2f[(size_t)(co0+co)*(2*Cv) + ci] * v;
    }
    int isf = flag[0];
    #pragma unroll
    for (int co = 0; co < COG; co++) {
        size_t oi = ((size_t)bb*Cv + co0 + co)*Pv + p;
        float r = xbuf[oi] + acc[co] + bm2[co0+co];
        if (isf) ((float*)out)[oi] = r;
        else     ((bf16*)out)[oi] = f2b(r);
    }
}

// ---------------------------------------------------------------------------
extern "C" void kernel_launch(void* const* d_in, const int* in_sizes, int n_in,
                              void* d_out, int out_size, void* d_ws, size_t ws_size,
                              hipStream_t stream) {
    (void)in_sizes; (void)n_in; (void)out_size; (void)ws_size;

    char* w = (char*)d_ws;
    float* ftf   = (float*)(w + 0);              // 12,582,912
    float* fkvcl = (float*)(w + 12582912);       // 12,582,912
    float* flowf = (float*)(w + 25165824);       //    262,144
    float* cw1f  = (float*)(w + 25427968);       //  1,340,928
    float* cw2f  = (float*)(w + 26768896);       //    663,552
    float* cw3f  = (float*)(w + 27432448);       //    746,496
    float* wqT   = (float*)(w + 28178944);       //     36,864
    float* woT   = (float*)(w + 28215808);       //     36,864
    bf16*  wkTb  = (bf16*) (w + 28252672);       //     18,432
    bf16*  wvTb  = (bf16*) (w + 28271104);       //     18,432
    float* wm1f  = (float*)(w + 28289536);       //     73,728
    float* wm2f  = (float*)(w + 28363264);       //     73,728
    float* biasf = (float*)(w + 28436992);       //      5,856
    int*   flag  = (int*)  (w + 28442848);       //          4
    bf16*  cat   = (bf16*) (w + 28443136);       // 12,713,984 (dead after conv1)
    float* r1    = (float*)(w + 41157120);       // 25,165,824 (dead after conv2)
    // aliases (strictly sequential lifetimes, stream-ordered):
    float* r2     = (float*)(w + 28443136);      // 12,582,912 over cat
    bf16*  off3   = (bf16*) (w + 41157120);      // 14,155,776 over r1
    float* xbuf   = (float*)(w + 28443136);      // 12,582,912 over r2 (dead)
    float* hidden = (float*)(w + 41157120);      // 25,165,824 over off3 (dead)
    // peak: 66,322,944 bytes

    detect_dtype<<<1, 256, 0, stream>>>((const unsigned short*)d_in[0], flag);

    prep_all<<<12288, 256, 0, stream>>>(flag,
        d_in[0], d_in[1], d_in[2],
        d_in[3], d_in[4], d_in[5], d_in[6], d_in[7], d_in[8], d_in[9], d_in[10],
        d_in[11], d_in[12], d_in[13], d_in[14], d_in[15], d_in[16], d_in[17], d_in[18],
        d_in[19], d_in[20], d_in[21], d_in[22],
        ftf, fkvcl, flowf, cw1f, cw2f, cw3f, wqT, woT, wkTb, wvTb, wm1f, wm2f, biasf);

    build_cat<<<(Bv*194*Pv + 255)/256, 256, 0, stream>>>(flag, ftf, d_in[1], flowf, cat);

    conv3x3<bf16,  float, 194, 16, 1><<<dim3(Hv, 192/16, Bv), 128, 0, stream>>>(
        cat, cw1f, biasf + 0,   biasf + 192, r1, 192);
    conv3x3<float, float, 192, 16, 1><<<dim3(Hv,  96/16, Bv), 128, 0, stream>>>(
        r1,  cw2f, biasf + 384, biasf + 480, r2,  96);
    conv3x3<float, bf16,  96,  12, 2><<<dim3(Hv, 216/12, Bv), 128, 0, stream>>>(
        r2,  cw3f, biasf + 576, biasf + 576, off3, 216);

    attn_kernel<<<768, 192, 0, stream>>>(ftf, flowf, fkvcl, off3,
        wkTb, wvTb, wqT, woT,
        biasf + 792, biasf + 888, biasf + 984, biasf + 1080, xbuf);

    mlp1_kernel<<<dim3(Hv, 192/16, Bv), 128, 0, stream>>>(xbuf, wm1f, biasf + 1176, hidden);
    mlp2_kernel<<<dim3(Hv,  96/16, Bv), 128, 0, stream>>>(flag, hidden, xbuf, wm2f,
                                                          biasf + 1368, d_out);
}

// Round 3
// 845.446 us; speedup vs baseline: 2.3931x; 2.3931x over previous
//
#include <hip/hip_runtime.h>
#include <hip/hip_bf16.h>
#include <math.h>

typedef __hip_bfloat16 bf16;
typedef __attribute__((ext_vector_type(8))) short s16x8;
typedef __attribute__((ext_vector_type(4))) short s16x4;
typedef __attribute__((ext_vector_type(4))) float fx4;

#define Bv 2
#define Cv 96
#define Hv 128
#define Wv 128
#define Pv (Hv*Wv)          /* 16384 */
#define Gv 12
#define Kv 9

__device__ __forceinline__ float b2f(bf16 x) { return __bfloat162float(x); }
__device__ __forceinline__ bf16 f2b(float x) { return __float2bfloat16(x); }

// dual-dtype input load: isf=1 -> float32, isf=0 -> bf16
__device__ __forceinline__ float ldin(const void* p, size_t i, int isf) {
    return isf ? ((const float*)p)[i] : __bfloat162float(((const bf16*)p)[i]);
}

// ---------------------------------------------------------------------------
// dtype detection (f32 read as bf16 shows NaN/Inf bit patterns in low halves)
// ---------------------------------------------------------------------------
__global__ void detect_dtype(const unsigned short* __restrict__ x, int* __restrict__ flag)
{
    __shared__ int bad;
    if (threadIdx.x == 0) bad = 0;
    __syncthreads();
    int cnt = 0;
    for (int i = threadIdx.x; i < 32768; i += 256) {
        unsigned short u = x[i];
        if ((u & 0x7F80) == 0x7F80) cnt++;
    }
    atomicAdd(&bad, cnt);
    __syncthreads();
    if (threadIdx.x == 0) flag[0] = (bad > 0) ? 1 : 0;   // 1 = float32 inputs
}

// ---------------------------------------------------------------------------
// prep: convert inputs; build MFMA A-layout weight buffers (bf16).
// wA layout: [(t*NC + kc)*COTOT + co]*32 + kq*8 + j,  k-in-chunk = kq*8+j
// ---------------------------------------------------------------------------
__global__ void prep_all(const int* __restrict__ flag,
    const void* ft, const void* fkv, const void* flow,
    const void* cw1, const void* cb1, const void* a1,
    const void* cw2, const void* cb2, const void* a2,
    const void* cw3, const void* cb3,
    const void* wq, const void* bq, const void* wk, const void* bk,
    const void* wv, const void* bv, const void* wo, const void* bo,
    const void* wm1, const void* bm1, const void* wm2, const void* bm2,
    float* __restrict__ ftf, float* __restrict__ fkvcl, float* __restrict__ flowf,
    float* __restrict__ wqT, float* __restrict__ woT,
    bf16* __restrict__ wkTb, bf16* __restrict__ wvTb,
    bf16* __restrict__ wA1, bf16* __restrict__ wA2, bf16* __restrict__ wA3,
    bf16* __restrict__ wAm1, bf16* __restrict__ wAm2,
    float* __restrict__ biasf)
{
    int isf = flag[0];
    size_t i = (size_t)blockIdx.x * 256 + threadIdx.x;
    if (i < (size_t)Bv*Cv*Pv) {
        ftf[i] = ldin(ft, i, isf);
        int c = (int)(i % 96);
        size_t rest = i / 96;
        int p = (int)(rest & (Pv-1));
        int b = (int)(rest >> 14);
        fkvcl[i] = ldin(fkv, ((size_t)(b*96 + c))*Pv + p, isf);
    }
    if (i < (size_t)Bv*2*Pv) flowf[i] = ldin(flow, i, isf);

    // conv1 weights: [192][194][9] -> wA1[t<9][kc<7][co<192][32]
    if (i < 9*7*192*32) {
        int q = (int)(i & 31);
        int rest = (int)(i >> 5);
        int co = rest % 192; rest /= 192;
        int kc = rest % 7;   int t = rest / 7;
        int ci = kc*32 + q;
        float v = (ci < 194) ? ldin(cw1, (size_t)co*194*9 + (size_t)ci*9 + t, isf) : 0.f;
        wA1[i] = f2b(v);
    }
    // conv2: [96][192][9] -> wA2[t<9][kc<6][co<96][32]
    if (i < 9*6*96*32) {
        int q = (int)(i & 31);
        int rest = (int)(i >> 5);
        int co = rest % 96; rest /= 96;
        int kc = rest % 6;  int t = rest / 6;
        int ci = kc*32 + q;
        wA2[i] = f2b(ldin(cw2, (size_t)co*192*9 + (size_t)ci*9 + t, isf));
    }
    // conv3: [216][96][9] -> wA3[t<9][kc<3][co<224][32], co>=216 zero
    if (i < 9*3*224*32) {
        int q = (int)(i & 31);
        int rest = (int)(i >> 5);
        int co = rest % 224; rest /= 224;
        int kc = rest % 3;   int t = rest / 3;
        int ci = kc*32 + q;
        float v = (co < 216) ? ldin(cw3, (size_t)co*96*9 + (size_t)ci*9 + t, isf) : 0.f;
        wA3[i] = f2b(v);
    }
    // mlp1: [192][96] -> wAm1[kc<3][co<192][32]
    if (i < 3*192*32) {
        int q = (int)(i & 31);
        int rest = (int)(i >> 5);
        int co = rest % 192;
        int kc = rest / 192;
        wAm1[i] = f2b(ldin(wm1, (size_t)co*96 + kc*32 + q, isf));
    }
    // mlp2: [96][192] -> wAm2[kc<6][co<96][32]
    if (i < 6*96*32) {
        int q = (int)(i & 31);
        int rest = (int)(i >> 5);
        int co = rest % 96;
        int kc = rest / 96;
        wAm2[i] = f2b(ldin(wm2, (size_t)co*192 + kc*32 + q, isf));
    }
    if (i < 96*96) {
        int co = (int)(i % 96), ci = (int)(i / 96);
        size_t j = (size_t)co*96 + ci;          // src [out][in] -> dst [in][out]
        wqT[i]  = ldin(wq, j, isf);
        woT[i]  = ldin(wo, j, isf);
        wkTb[i] = f2b(ldin(wk, j, isf));
        wvTb[i] = f2b(ldin(wv, j, isf));
    }
    if (i < 192) biasf[i]       = ldin(cb1, i, isf);
    if (i < 192) biasf[192+i]   = ldin(a1, i, isf);
    if (i < 96)  biasf[384+i]   = ldin(cb2, i, isf);
    if (i < 96)  biasf[480+i]   = ldin(a2, i, isf);
    if (i < 216) biasf[576+i]   = ldin(cb3, i, isf);
    if (i < 96) {
        biasf[792+i]  = ldin(bq, i, isf);
        biasf[888+i]  = ldin(bk, i, isf);
        biasf[984+i]  = ldin(bv, i, isf);
        biasf[1080+i] = ldin(bo, i, isf);
        biasf[1368+i] = ldin(bm2, i, isf);
    }
    if (i < 192) biasf[1176+i] = ldin(bm1, i, isf);
}

// ---------------------------------------------------------------------------
// cat[gp][224] bf16 pixel-major: ci 0..95 feat_t, 96..191 warped kv, 192/193 flow, rest 0
// ---------------------------------------------------------------------------
__global__ void build_cat(const float* __restrict__ ftf, const float* __restrict__ fkvcl,
                          const float* __restrict__ flowf, bf16* __restrict__ cat)
{
    size_t idx = (size_t)blockIdx.x * 256 + threadIdx.x;
    if (idx >= (size_t)Bv*Pv*224) return;
    int ch = (int)(idx % 224);
    int gp = (int)(idx / 224);
    int p  = gp & (Pv-1);
    int bb = gp >> 14;
    float v = 0.f;
    if (ch < 96) {
        v = ftf[((size_t)bb*Cv + ch)*Pv + p];
    } else if (ch < 192) {
        int cc = ch - 96;
        int py = p >> 7, px = p & (Wv-1);
        float xs = (float)px + flowf[((size_t)bb*2 + 0)*Pv + p];
        float ys = (float)py + flowf[((size_t)bb*2 + 1)*Pv + p];
        float x0f = floorf(xs), y0f = floorf(ys);
        float wx = xs - x0f, wy = ys - y0f;
        int x0 = (int)x0f, y0 = (int)y0f;
        #pragma unroll
        for (int tt = 0; tt < 4; tt++) {
            int xi = x0 + (tt & 1), yi = y0 + (tt >> 1);
            float wt = ((tt & 1) ? wx : 1.f - wx) * ((tt >> 1) ? wy : 1.f - wy);
            if (xi >= 0 && xi < Wv && yi >= 0 && yi < Hv)
                v += wt * fkvcl[((size_t)bb*Pv + yi*Wv + xi)*96 + cc];
        }
    } else if (ch < 194) {
        v = flowf[((size_t)bb*2 + (ch-192))*Pv + p];
    }
    cat[idx] = f2b(v);
}

// ---------------------------------------------------------------------------
// MFMA implicit-GEMM conv/1x1. Block 256 = 4 waves; tile 128 px x (COF*16) co.
// TAPS=9: 3x3 (stages 3 halo rows x 130 px per 32-ci chunk); TAPS=1: 1x1.
// MODE 0: PReLU -> bf16 pixel-major      MODE 1: none -> bf16 pixel-major (guard co<216)
// MODE 2: GELU -> bf16 pixel-major       MODE 3: +bias +resid(f32 ch-major) -> d_out
// LDS px stride 40 shorts (80 B): 2-way bank aliasing only (free), 16 B aligned.
// ---------------------------------------------------------------------------
template<int CIN_PAD, int COTOT, int COF, int TAPS, int MODE, int OCS>
__launch_bounds__(256)
__global__ void conv_mfma(const bf16* __restrict__ in, const bf16* __restrict__ wA,
                          const float* __restrict__ bias, const float* __restrict__ alpha,
                          const float* __restrict__ resid, const int* __restrict__ flag,
                          void* __restrict__ outp)
{
    constexpr int NC = CIN_PAD / 32;
    constexpr int LDS_PX = (TAPS == 9) ? 3*130 : 128;
    __shared__ short sbuf[LDS_PX * 40];

    int tid = threadIdx.x;
    int wave = tid >> 6, lane = tid & 63;
    int n = lane & 15, kq = lane >> 4;
    int y = blockIdx.x, cob = blockIdx.y * (COF*16), bb = blockIdx.z;

    fx4 acc[COF][2];
    #pragma unroll
    for (int f = 0; f < COF; f++)
        #pragma unroll
        for (int j = 0; j < 2; j++)
            acc[f][j] = (fx4){0.f, 0.f, 0.f, 0.f};

    for (int kc = 0; kc < NC; kc++) {
        __syncthreads();
        if (TAPS == 9) {
            for (int i = tid; i < 3*130*4; i += 256) {
                int part = i & 3; int pxr = i >> 2;
                int r = pxr / 130; int px = pxr - r*130;
                int yy = y + r - 1, xx = px - 1;
                uint4 val = {0u, 0u, 0u, 0u};
                if (yy >= 0 && yy < Hv && xx >= 0 && xx < Wv)
                    val = *(const uint4*)(in + ((size_t)(bb*Pv + yy*Wv + xx)*CIN_PAD + kc*32 + part*8));
                *(uint4*)&sbuf[(r*130 + px)*40 + part*8] = val;
            }
        } else {
            for (int i = tid; i < 128*4; i += 256) {
                int part = i & 3, px = i >> 2;
                uint4 val = *(const uint4*)(in + ((size_t)(bb*Pv + y*Wv + px)*CIN_PAD + kc*32 + part*8));
                *(uint4*)&sbuf[px*40 + part*8] = val;
            }
        }
        __syncthreads();
        #pragma unroll
        for (int t = 0; t < TAPS; t++) {
            const bf16* wbase = wA + ((size_t)(t*NC + kc)*COTOT + cob + n)*32 + kq*8;
            s16x8 af[COF];
            #pragma unroll
            for (int f = 0; f < COF; f++)
                af[f] = *(const s16x8*)(wbase + (size_t)f*16*32);
            #pragma unroll
            for (int j = 0; j < 2; j++) {
                int pxs;
                if (TAPS == 9) {
                    int r = t / 3, dx = t % 3;          // dx-1 shift + 1 halo offset = dx
                    pxs = r*130 + wave*32 + j*16 + n + dx;
                } else {
                    pxs = wave*32 + j*16 + n;
                }
                s16x8 bfr = *(const s16x8*)&sbuf[pxs*40 + kq*8];
                #pragma unroll
                for (int f = 0; f < COF; f++)
                    acc[f][j] = __builtin_amdgcn_mfma_f32_16x16x32_bf16(af[f], bfr, acc[f][j], 0, 0, 0);
            }
        }
    }

    // epilogue: D col=lane&15 (pixel), row=(lane>>4)*4+reg (co)
    int pxbase = wave*32;
    #pragma unroll
    for (int f = 0; f < COF; f++) {
        int co0 = cob + f*16 + kq*4;
        if (MODE == 1 && co0 >= 216) continue;
        #pragma unroll
        for (int j = 0; j < 2; j++) {
            int px = pxbase + j*16 + n;
            size_t gp = (size_t)bb*Pv + (size_t)y*Wv + px;
            fx4 fr = acc[f][j];
            if (MODE == 3) {
                int isf = flag[0];
                #pragma unroll
                for (int rg = 0; rg < 4; rg++) {
                    int co = co0 + rg;
                    size_t oi = ((size_t)bb*COTOT + co)*Pv + (size_t)y*Wv + px;
                    float v = fr[rg] + bias[co] + resid[oi];
                    if (isf) ((float*)outp)[oi] = v;
                    else     ((bf16*)outp)[oi] = f2b(v);
                }
            } else {
                s16x4 st;
                #pragma unroll
                for (int rg = 0; rg < 4; rg++) {
                    float v = fr[rg] + bias[co0 + rg];
                    if (MODE == 0) { float a = alpha[co0 + rg]; v = (v >= 0.f) ? v : a*v; }
                    if (MODE == 2) { v = 0.5f*v*(1.f + tanhf(0.7978845608028654f*(v + 0.044715f*v*v*v))); }
                    bf16 bv = f2b(v);
                    st[rg] = *(short*)&bv;
                }
                *(s16x4*)((bf16*)outp + gp*OCS + co0) = st;
            }
        }
    }
}

// ---------------------------------------------------------------------------
// Fused deformable sampling + attention + output projection + residual.
// Block = 192 threads = 2 pixels x 96 channel-lanes. (unchanged from round 2,
// plus bf16 pixel-major x store for the MLP GEMM input)
// ---------------------------------------------------------------------------
__launch_bounds__(192)
__global__ void attn_kernel(const float* __restrict__ ftf, const float* __restrict__ flowf,
    const float* __restrict__ fkvcl, const bf16* __restrict__ off3,
    const bf16* __restrict__ wkTb, const bf16* __restrict__ wvTb,
    const float* __restrict__ wqT, const float* __restrict__ woT,
    const float* __restrict__ bqf, const float* __restrict__ bkf,
    const float* __restrict__ bvf, const float* __restrict__ bof,
    float* __restrict__ xbuf, bf16* __restrict__ xb_bf)
{
    __shared__ bf16 wk_s[96*96];
    __shared__ bf16 wv_s[96*96];
    __shared__ float s_s[2][96][12];
    __shared__ float ft_s[2][96];
    __shared__ float o_s[2][96];

    int tid = threadIdx.x;
    for (int i = tid; i < 96*96; i += 192) { wk_s[i] = wkTb[i]; wv_s[i] = wvTb[i]; }
    int u = tid / 96;
    int c = tid - u*96;
    int g = c >> 3;
    float bqc = bqf[c], bkc = bkf[c], bvc = bvf[c], boc = bof[c];
    __syncthreads();

    const int npair = (Bv*Pv) / 2;   // 16384
    for (int pair = blockIdx.x; pair < npair; pair += gridDim.x) {
        int gp = pair*2 + u;
        int bb = gp >> 14;
        int p  = gp & (Pv-1);
        int py = p >> 7, px = p & (Wv-1);
        float fx = flowf[((size_t)bb*2 + 0)*Pv + p];
        float fy = flowf[((size_t)bb*2 + 1)*Pv + p];
        const bf16* offp = off3 + (size_t)gp * 216 + g*18;
        const float* fkv = fkvcl + ((size_t)bb*Pv)*96 + c;

        #pragma unroll
        for (int k = 0; k < Kv; k++) {
            float dy = b2f(offp[2*k])   + fy;
            float dx = b2f(offp[2*k+1]) + fx;
            float sx = (float)(px + (k % 3) - 1) + dx;
            float sy = (float)(py + (k / 3) - 1) + dy;
            float x0f = floorf(sx), y0f = floorf(sy);
            float wx = sx - x0f, wy = sy - y0f;
            int x0 = (int)x0f, y0 = (int)y0f;
            float v = 0.f;
            #pragma unroll
            for (int t = 0; t < 4; t++) {
                int xi = x0 + (t & 1), yi = y0 + (t >> 1);
                float wt = ((t & 1) ? wx : 1.f - wx) * ((t >> 1) ? wy : 1.f - wy);
                if (xi >= 0 && xi < Wv && yi >= 0 && yi < Hv)
                    v += wt * fkv[(size_t)(yi*Wv + xi)*96];
            }
            s_s[u][c][k] = v;
        }
        float ftv = ftf[((size_t)bb*Cv + c)*Pv + p];
        ft_s[u][c] = ftv;
        __syncthreads();

        float kacc[9], vacc[9];
        #pragma unroll
        for (int k = 0; k < 9; k++) { kacc[k] = 0.f; vacc[k] = 0.f; }
        float qv = 0.f;
        for (int cp = 0; cp < 96; cp++) {
            const float4* sp = (const float4*)&s_s[u][cp][0];
            float4 s0 = sp[0], s1 = sp[1];
            float s8 = s_s[u][cp][8];
            float sv[9] = {s0.x, s0.y, s0.z, s0.w, s1.x, s1.y, s1.z, s1.w, s8};
            float wkv = b2f(wk_s[cp*96 + c]);
            float wvv = b2f(wv_s[cp*96 + c]);
            qv += wqT[cp*96 + c] * ft_s[u][cp];
            #pragma unroll
            for (int k = 0; k < 9; k++) {
                kacc[k] += wkv * sv[k];
                vacc[k] += wvv * sv[k];
            }
        }
        qv += bqc;

        float lg[9];
        #pragma unroll
        for (int k = 0; k < 9; k++) {
            float pr = qv * (kacc[k] + bkc);
            pr += __shfl_xor(pr, 1);
            pr += __shfl_xor(pr, 2);
            pr += __shfl_xor(pr, 4);
            lg[k] = pr * 0.35355339059327373f;   // 1/sqrt(8)
        }
        float m = lg[0];
        #pragma unroll
        for (int k = 1; k < 9; k++) m = fmaxf(m, lg[k]);
        float sum = 0.f;
        #pragma unroll
        for (int k = 0; k < 9; k++) { lg[k] = __expf(lg[k] - m); sum += lg[k]; }
        float inv = 1.f / sum;
        float ov = 0.f;
        #pragma unroll
        for (int k = 0; k < 9; k++) ov += (lg[k] * inv) * (vacc[k] + bvc);

        o_s[u][c] = ov;
        __syncthreads();

        float xv = ftv + boc;
        for (int cp = 0; cp < 96; cp++)
            xv += woT[cp*96 + c] * o_s[u][cp];
        xbuf[((size_t)bb*Cv + c)*Pv + p] = xv;
        xb_bf[(size_t)gp*96 + c] = f2b(xv);
        __syncthreads();
    }
}

// ---------------------------------------------------------------------------
extern "C" void kernel_launch(void* const* d_in, const int* in_sizes, int n_in,
                              void* d_out, int out_size, void* d_ws, size_t ws_size,
                              hipStream_t stream) {
    (void)in_sizes; (void)n_in; (void)out_size; (void)ws_size;

    char* w = (char*)d_ws;
    float* ftf   = (float*)(w + 0);              // 12,582,912
    float* fkvcl = (float*)(w + 12582912);       // 12,582,912
    float* flowf = (float*)(w + 25165824);       //    262,144
    float* wqT   = (float*)(w + 25427968);       //     36,864
    float* woT   = (float*)(w + 25464832);       //     36,864
    bf16*  wkTb  = (bf16*) (w + 25501696);       //     18,432
    bf16*  wvTb  = (bf16*) (w + 25520128);       //     18,432
    bf16*  wA1   = (bf16*) (w + 25538560);       //    774,144
    bf16*  wA2   = (bf16*) (w + 26312704);       //    331,776
    bf16*  wA3   = (bf16*) (w + 26644480);       //    387,072
    bf16*  wAm1  = (bf16*) (w + 27031552);       //     36,864
    bf16*  wAm2  = (bf16*) (w + 27068416);       //     36,864
    float* biasf = (float*)(w + 27105280);       //      8,192 (pad)
    int*   flag  = (int*)  (w + 27113472);       //        256
    // region A: cat -> r2b -> xbuf        (14,680,064)
    char*  regA  = w + 27113728;
    // region B: r1b -> off3 -> hb         (14,155,776)
    char*  regB  = w + 41793792;
    // region C: xb_bf                      (6,291,456)
    char*  regC  = w + 55949568;
    // total 62,241,024 bytes

    bf16*  cat   = (bf16*) regA;   // [gp][224]
    bf16*  r2b   = (bf16*) regA;   // [gp][96]
    float* xbuf  = (float*)regA;   // [b][96][P] f32
    bf16*  r1b   = (bf16*) regB;   // [gp][192]
    bf16*  off3  = (bf16*) regB;   // [gp][216]
    bf16*  hb    = (bf16*) regB;   // [gp][192]
    bf16*  xb_bf = (bf16*) regC;   // [gp][96]

    detect_dtype<<<1, 256, 0, stream>>>((const unsigned short*)d_in[0], flag);

    prep_all<<<12288, 256, 0, stream>>>(flag,
        d_in[0], d_in[1], d_in[2],
        d_in[3], d_in[4], d_in[5], d_in[6], d_in[7], d_in[8], d_in[9], d_in[10],
        d_in[11], d_in[12], d_in[13], d_in[14], d_in[15], d_in[16], d_in[17], d_in[18],
        d_in[19], d_in[20], d_in[21], d_in[22],
        ftf, fkvcl, flowf, wqT, woT, wkTb, wvTb, wA1, wA2, wA3, wAm1, wAm2, biasf);

    build_cat<<<((size_t)Bv*Pv*224 + 255)/256, 256, 0, stream>>>(ftf, fkvcl, flowf, cat);

    conv_mfma<224, 192, 6, 9, 0, 192><<<dim3(Hv, 2, Bv), 256, 0, stream>>>(
        cat, wA1, biasf + 0,   biasf + 192, nullptr, flag, r1b);
    conv_mfma<192,  96, 3, 9, 0,  96><<<dim3(Hv, 2, Bv), 256, 0, stream>>>(
        r1b, wA2, biasf + 384, biasf + 480, nullptr, flag, r2b);
    conv_mfma< 96, 224, 7, 9, 1, 216><<<dim3(Hv, 2, Bv), 256, 0, stream>>>(
        r2b, wA3, biasf + 576, nullptr,     nullptr, flag, off3);

    attn_kernel<<<768, 192, 0, stream>>>(ftf, flowf, fkvcl, off3,
        wkTb, wvTb, wqT, woT,
        biasf + 792, biasf + 888, biasf + 984, biasf + 1080, xbuf, xb_bf);

    conv_mfma< 96, 192, 6, 1, 2, 192><<<dim3(Hv, 2, Bv), 256, 0, stream>>>(
        xb_bf, wAm1, biasf + 1176, nullptr, nullptr, flag, hb);
    conv_mfma<192,  96, 3, 1, 3,  96><<<dim3(Hv, 2, Bv), 256, 0, stream>>>(
        hb,   wAm2, biasf + 1368, nullptr, xbuf,    flag, d_out);
}

// Round 4
// 678.880 us; speedup vs baseline: 2.9803x; 1.2454x over previous
//
#include <hip/hip_runtime.h>
#include <hip/hip_bf16.h>
#include <math.h>

typedef __hip_bfloat16 bf16;
typedef __attribute__((ext_vector_type(8))) short s16x8;
typedef __attribute__((ext_vector_type(4))) short s16x4;
typedef __attribute__((ext_vector_type(4))) float fx4;

#define Bv 2
#define Cv 96
#define Hv 128
#define Wv 128
#define Pv (Hv*Wv)          /* 16384 */
#define Gv 12
#define Kv 9

__device__ __forceinline__ float b2f(bf16 x) { return __bfloat162float(x); }
__device__ __forceinline__ bf16 f2b(float x) { return __float2bfloat16(x); }

// dual-dtype input load: isf=1 -> float32, isf=0 -> bf16
__device__ __forceinline__ float ldin(const void* p, size_t i, int isf) {
    return isf ? ((const float*)p)[i] : __bfloat162float(((const bf16*)p)[i]);
}

// ---------------------------------------------------------------------------
// dtype detection (f32 read as bf16 shows NaN/Inf bit patterns in low halves)
// ---------------------------------------------------------------------------
__global__ void detect_dtype(const unsigned short* __restrict__ x, int* __restrict__ flag)
{
    __shared__ int bad;
    if (threadIdx.x == 0) bad = 0;
    __syncthreads();
    int cnt = 0;
    for (int i = threadIdx.x; i < 32768; i += 256) {
        unsigned short u = x[i];
        if ((u & 0x7F80) == 0x7F80) cnt++;
    }
    atomicAdd(&bad, cnt);
    __syncthreads();
    if (threadIdx.x == 0) flag[0] = (bad > 0) ? 1 : 0;   // 1 = float32 inputs
}

// ---------------------------------------------------------------------------
// prep: convert inputs; build MFMA A-layout weight buffers (bf16).
// wA layout: [(t*NC + kc)*COTOT + co]*32 + kq*8 + j,  k-in-chunk = kq*8+j
// ---------------------------------------------------------------------------
__global__ void prep_all(const int* __restrict__ flag,
    const void* ft, const void* fkv, const void* flow,
    const void* cw1, const void* cb1, const void* a1,
    const void* cw2, const void* cb2, const void* a2,
    const void* cw3, const void* cb3,
    const void* wq, const void* bq, const void* wk, const void* bk,
    const void* wv, const void* bv, const void* wo, const void* bo,
    const void* wm1, const void* bm1, const void* wm2, const void* bm2,
    float* __restrict__ ftf, bf16* __restrict__ fkvclb, float* __restrict__ flowf,
    bf16* __restrict__ wAq, bf16* __restrict__ wAo,
    bf16* __restrict__ wkTb, bf16* __restrict__ wvTb,
    bf16* __restrict__ wA1, bf16* __restrict__ wA2, bf16* __restrict__ wA3,
    bf16* __restrict__ wAm1, bf16* __restrict__ wAm2,
    float* __restrict__ biasf)
{
    int isf = flag[0];
    size_t i = (size_t)blockIdx.x * 256 + threadIdx.x;
    if (i < (size_t)Bv*Cv*Pv) {
        ftf[i] = ldin(ft, i, isf);
        int c = (int)(i % 96);
        size_t rest = i / 96;
        int p = (int)(rest & (Pv-1));
        int b = (int)(rest >> 14);
        fkvclb[i] = f2b(ldin(fkv, ((size_t)(b*96 + c))*Pv + p, isf));
    }
    if (i < (size_t)Bv*2*Pv) flowf[i] = ldin(flow, i, isf);

    // conv1 weights: [192][194][9] -> wA1[t<9][kc<7][co<192][32]
    if (i < 9*7*192*32) {
        int q = (int)(i & 31);
        int rest = (int)(i >> 5);
        int co = rest % 192; rest /= 192;
        int kc = rest % 7;   int t = rest / 7;
        int ci = kc*32 + q;
        float v = (ci < 194) ? ldin(cw1, (size_t)co*194*9 + (size_t)ci*9 + t, isf) : 0.f;
        wA1[i] = f2b(v);
    }
    // conv2: [96][192][9] -> wA2[t<9][kc<6][co<96][32]
    if (i < 9*6*96*32) {
        int q = (int)(i & 31);
        int rest = (int)(i >> 5);
        int co = rest % 96; rest /= 96;
        int kc = rest % 6;  int t = rest / 6;
        int ci = kc*32 + q;
        wA2[i] = f2b(ldin(cw2, (size_t)co*192*9 + (size_t)ci*9 + t, isf));
    }
    // conv3: [216][96][9] -> wA3[t<9][kc<3][co<224][32], co>=216 zero
    if (i < 9*3*224*32) {
        int q = (int)(i & 31);
        int rest = (int)(i >> 5);
        int co = rest % 224; rest /= 224;
        int kc = rest % 3;   int t = rest / 3;
        int ci = kc*32 + q;
        float v = (co < 216) ? ldin(cw3, (size_t)co*96*9 + (size_t)ci*9 + t, isf) : 0.f;
        wA3[i] = f2b(v);
    }
    // mlp1: [192][96] -> wAm1[kc<3][co<192][32]
    if (i < 3*192*32) {
        int q = (int)(i & 31);
        int rest = (int)(i >> 5);
        int co = rest % 192;
        int kc = rest / 192;
        wAm1[i] = f2b(ldin(wm1, (size_t)co*96 + kc*32 + q, isf));
    }
    // mlp2: [96][192] -> wAm2[kc<6][co<96][32]
    if (i < 6*96*32) {
        int q = (int)(i & 31);
        int rest = (int)(i >> 5);
        int co = rest % 96;
        int kc = rest / 96;
        wAm2[i] = f2b(ldin(wm2, (size_t)co*192 + kc*32 + q, isf));
    }
    // wq / wo: [96][96] -> A-layout [kc<3][co<96][32]
    if (i < 3*96*32) {
        int q = (int)(i & 31);
        int rest = (int)(i >> 5);
        int co = rest % 96;
        int kc = rest / 96;
        wAq[i] = f2b(ldin(wq, (size_t)co*96 + kc*32 + q, isf));
        wAo[i] = f2b(ldin(wo, (size_t)co*96 + kc*32 + q, isf));
    }
    // wk / wv: transpose to [ci][co] bf16 (streamed from L2 in attn)
    if (i < 96*96) {
        int co = (int)(i % 96), ci = (int)(i / 96);
        size_t j = (size_t)co*96 + ci;
        wkTb[i] = f2b(ldin(wk, j, isf));
        wvTb[i] = f2b(ldin(wv, j, isf));
    }
    if (i < 192) biasf[i]       = ldin(cb1, i, isf);
    if (i < 192) biasf[192+i]   = ldin(a1, i, isf);
    if (i < 96)  biasf[384+i]   = ldin(cb2, i, isf);
    if (i < 96)  biasf[480+i]   = ldin(a2, i, isf);
    if (i < 216) biasf[576+i]   = ldin(cb3, i, isf);
    if (i < 96) {
        biasf[792+i]  = ldin(bq, i, isf);
        biasf[888+i]  = ldin(bk, i, isf);
        biasf[984+i]  = ldin(bv, i, isf);
        biasf[1080+i] = ldin(bo, i, isf);
        biasf[1368+i] = ldin(bm2, i, isf);
    }
    if (i < 192) biasf[1176+i] = ldin(bm1, i, isf);
}

// ---------------------------------------------------------------------------
// cat[gp][224] bf16 pixel-major: ci 0..95 feat_t, 96..191 warped kv, 192/193 flow, rest 0
// ---------------------------------------------------------------------------
__global__ void build_cat(const float* __restrict__ ftf, const bf16* __restrict__ fkvclb,
                          const float* __restrict__ flowf, bf16* __restrict__ cat)
{
    size_t idx = (size_t)blockIdx.x * 256 + threadIdx.x;
    if (idx >= (size_t)Bv*Pv*224) return;
    int ch = (int)(idx % 224);
    int gp = (int)(idx / 224);
    int p  = gp & (Pv-1);
    int bb = gp >> 14;
    float v = 0.f;
    if (ch < 96) {
        v = ftf[((size_t)bb*Cv + ch)*Pv + p];
    } else if (ch < 192) {
        int cc = ch - 96;
        int py = p >> 7, px = p & (Wv-1);
        float xs = (float)px + flowf[((size_t)bb*2 + 0)*Pv + p];
        float ys = (float)py + flowf[((size_t)bb*2 + 1)*Pv + p];
        float x0f = floorf(xs), y0f = floorf(ys);
        float wx = xs - x0f, wy = ys - y0f;
        int x0 = (int)x0f, y0 = (int)y0f;
        #pragma unroll
        for (int tt = 0; tt < 4; tt++) {
            int xi = x0 + (tt & 1), yi = y0 + (tt >> 1);
            float wt = ((tt & 1) ? wx : 1.f - wx) * ((tt >> 1) ? wy : 1.f - wy);
            if (xi >= 0 && xi < Wv && yi >= 0 && yi < Hv)
                v += wt * b2f(fkvclb[((size_t)bb*Pv + yi*Wv + xi)*96 + cc]);
        }
    } else if (ch < 194) {
        v = flowf[((size_t)bb*2 + (ch-192))*Pv + p];
    }
    cat[idx] = f2b(v);
}

// ---------------------------------------------------------------------------
// MFMA implicit-GEMM conv/1x1. Block 256 = 4 waves; tile 128 px x (COF*16) co.
// CSTR = input pixel stride (elements); CIN_PAD = K extent (mult of 32).
// MODE 0: PReLU -> bf16 px-major    MODE 1: plain -> bf16 px-major (guard co<216)
// MODE 2: GELU  -> bf16 px-major    MODE 3: +bias +resid(f32 ch-major) -> d_out
// MODE 4: +bias +resid(f32 ch-major) -> outp f32 ch-major AND out2 bf16 px-major
// ---------------------------------------------------------------------------
template<int CSTR, int CIN_PAD, int COTOT, int COF, int TAPS, int MODE, int OCS>
__launch_bounds__(256)
__global__ void conv_mfma(const bf16* __restrict__ in, const bf16* __restrict__ wA,
                          const float* __restrict__ bias, const float* __restrict__ alpha,
                          const float* __restrict__ resid, const int* __restrict__ flag,
                          void* __restrict__ outp, void* __restrict__ out2)
{
    constexpr int NC = CIN_PAD / 32;
    constexpr int LDS_PX = (TAPS == 9) ? 3*130 : 128;
    __shared__ short sbuf[LDS_PX * 40];

    int tid = threadIdx.x;
    int wave = tid >> 6, lane = tid & 63;
    int n = lane & 15, kq = lane >> 4;
    int y = blockIdx.x, cob = blockIdx.y * (COF*16), bb = blockIdx.z;

    fx4 acc[COF][2];
    #pragma unroll
    for (int f = 0; f < COF; f++)
        #pragma unroll
        for (int j = 0; j < 2; j++)
            acc[f][j] = (fx4){0.f, 0.f, 0.f, 0.f};

    for (int kc = 0; kc < NC; kc++) {
        __syncthreads();
        if (TAPS == 9) {
            for (int i = tid; i < 3*130*4; i += 256) {
                int part = i & 3; int pxr = i >> 2;
                int r = pxr / 130; int px = pxr - r*130;
                int yy = y + r - 1, xx = px - 1;
                uint4 val = {0u, 0u, 0u, 0u};
                if (yy >= 0 && yy < Hv && xx >= 0 && xx < Wv)
                    val = *(const uint4*)(in + ((size_t)(bb*Pv + yy*Wv + xx)*CSTR + kc*32 + part*8));
                *(uint4*)&sbuf[(r*130 + px)*40 + part*8] = val;
            }
        } else {
            for (int i = tid; i < 128*4; i += 256) {
                int part = i & 3, px = i >> 2;
                uint4 val = *(const uint4*)(in + ((size_t)(bb*Pv + y*Wv + px)*CSTR + kc*32 + part*8));
                *(uint4*)&sbuf[px*40 + part*8] = val;
            }
        }
        __syncthreads();
        #pragma unroll
        for (int t = 0; t < TAPS; t++) {
            const bf16* wbase = wA + ((size_t)(t*NC + kc)*COTOT + cob + n)*32 + kq*8;
            s16x8 af[COF];
            #pragma unroll
            for (int f = 0; f < COF; f++)
                af[f] = *(const s16x8*)(wbase + (size_t)f*16*32);
            #pragma unroll
            for (int j = 0; j < 2; j++) {
                int pxs;
                if (TAPS == 9) {
                    int r = t / 3, dx = t % 3;
                    pxs = r*130 + wave*32 + j*16 + n + dx;
                } else {
                    pxs = wave*32 + j*16 + n;
                }
                s16x8 bfr = *(const s16x8*)&sbuf[pxs*40 + kq*8];
                #pragma unroll
                for (int f = 0; f < COF; f++)
                    acc[f][j] = __builtin_amdgcn_mfma_f32_16x16x32_bf16(af[f], bfr, acc[f][j], 0, 0, 0);
            }
        }
    }

    // epilogue: D col=lane&15 (pixel), row=(lane>>4)*4+reg (co)
    int pxbase = wave*32;
    #pragma unroll
    for (int f = 0; f < COF; f++) {
        int co0 = cob + f*16 + kq*4;
        if (MODE == 1 && co0 >= 216) continue;
        #pragma unroll
        for (int j = 0; j < 2; j++) {
            int px = pxbase + j*16 + n;
            size_t gp = (size_t)bb*Pv + (size_t)y*Wv + px;
            fx4 fr = acc[f][j];
            if (MODE == 3) {
                int isf = flag[0];
                #pragma unroll
                for (int rg = 0; rg < 4; rg++) {
                    int co = co0 + rg;
                    size_t oi = ((size_t)bb*COTOT + co)*Pv + (size_t)y*Wv + px;
                    float v = fr[rg] + bias[co] + resid[oi];
                    if (isf) ((float*)outp)[oi] = v;
                    else     ((bf16*)outp)[oi] = f2b(v);
                }
            } else if (MODE == 4) {
                s16x4 st;
                #pragma unroll
                for (int rg = 0; rg < 4; rg++) {
                    int co = co0 + rg;
                    size_t oi = ((size_t)bb*COTOT + co)*Pv + (size_t)y*Wv + px;
                    float v = fr[rg] + bias[co] + resid[oi];
                    ((float*)outp)[oi] = v;
                    bf16 bvv = f2b(v);
                    st[rg] = *(short*)&bvv;
                }
                *(s16x4*)((bf16*)out2 + gp*OCS + co0) = st;
            } else {
                s16x4 st;
                #pragma unroll
                for (int rg = 0; rg < 4; rg++) {
                    float v = fr[rg] + bias[co0 + rg];
                    if (MODE == 0) { float a = alpha[co0 + rg]; v = (v >= 0.f) ? v : a*v; }
                    if (MODE == 2) { v = 0.5f*v*(1.f + tanhf(0.7978845608028654f*(v + 0.044715f*v*v*v))); }
                    bf16 bvv = f2b(v);
                    st[rg] = *(short*)&bvv;
                }
                *(s16x4*)((bf16*)outp + gp*OCS + co0) = st;
            }
        }
    }
}

// ---------------------------------------------------------------------------
// Fused deformable sampling + k/v projection + softmax + weighted sum.
// Block = 192 threads = 2 pixels x 96 channel-lanes. Only s_s in LDS (~9.4 KB)
// -> occupancy is VGPR-limited, not LDS-limited. Wk/Wv stream from L2.
// q is precomputed (GEMM); o is written px-major for the o-projection GEMM.
// ---------------------------------------------------------------------------
__launch_bounds__(192)
__global__ void attn_kernel(const float* __restrict__ flowf, const bf16* __restrict__ fkvclb,
    const bf16* __restrict__ off3, const bf16* __restrict__ q_bf,
    const bf16* __restrict__ wkTb, const bf16* __restrict__ wvTb,
    const float* __restrict__ bkf, const float* __restrict__ bvf,
    bf16* __restrict__ o_bf)
{
    __shared__ float s_s[2][96][12];

    int tid = threadIdx.x;
    int u = tid / 96;
    int c = tid - u*96;
    int g = c >> 3;
    float bkc = bkf[c], bvc = bvf[c];

    const int npair = (Bv*Pv) / 2;   // 16384
    for (int pair = blockIdx.x; pair < npair; pair += gridDim.x) {
        int gp = pair*2 + u;
        int bb = gp >> 14;
        int p  = gp & (Pv-1);
        int py = p >> 7, px = p & (Wv-1);
        float fx = flowf[((size_t)bb*2 + 0)*Pv + p];
        float fy = flowf[((size_t)bb*2 + 1)*Pv + p];
        const bf16* offp = off3 + (size_t)gp * 216 + g*18;
        const bf16* fkv = fkvclb + ((size_t)bb*Pv)*96 + c;

        // --- deformable 3x3 sampling for this (pixel, channel) ---
        #pragma unroll
        for (int k = 0; k < Kv; k++) {
            float dy = b2f(offp[2*k])   + fy;
            float dx = b2f(offp[2*k+1]) + fx;
            float sx = (float)(px + (k % 3) - 1) + dx;
            float sy = (float)(py + (k / 3) - 1) + dy;
            float x0f = floorf(sx), y0f = floorf(sy);
            float wx = sx - x0f, wy = sy - y0f;
            int x0 = (int)x0f, y0 = (int)y0f;
            float v = 0.f;
            #pragma unroll
            for (int t = 0; t < 4; t++) {
                int xi = x0 + (t & 1), yi = y0 + (t >> 1);
                float wt = ((t & 1) ? wx : 1.f - wx) * ((t >> 1) ? wy : 1.f - wy);
                if (xi >= 0 && xi < Wv && yi >= 0 && yi < Hv)
                    v += wt * b2f(fkv[(size_t)(yi*Wv + xi)*96]);
            }
            s_s[u][c][k] = v;
        }
        __syncthreads();

        // --- k / v projections (Wk/Wv streamed from L2) ---
        float kacc[9], vacc[9];
        #pragma unroll
        for (int k = 0; k < 9; k++) { kacc[k] = 0.f; vacc[k] = 0.f; }
        for (int cp = 0; cp < 96; cp++) {
            const float4* sp = (const float4*)&s_s[u][cp][0];
            float4 s0 = sp[0], s1 = sp[1];
            float s8 = s_s[u][cp][8];
            float sv[9] = {s0.x, s0.y, s0.z, s0.w, s1.x, s1.y, s1.z, s1.w, s8};
            float wkv = b2f(wkTb[cp*96 + c]);
            float wvv = b2f(wvTb[cp*96 + c]);
            #pragma unroll
            for (int k = 0; k < 9; k++) {
                kacc[k] += wkv * sv[k];
                vacc[k] += wvv * sv[k];
            }
        }
        float qv = b2f(q_bf[(size_t)gp*96 + c]);

        // --- logits: reduce q.k over the 8 channels of this head (lane-aligned) ---
        float lg[9];
        #pragma unroll
        for (int k = 0; k < 9; k++) {
            float pr = qv * (kacc[k] + bkc);
            pr += __shfl_xor(pr, 1);
            pr += __shfl_xor(pr, 2);
            pr += __shfl_xor(pr, 4);
            lg[k] = pr * 0.35355339059327373f;   // 1/sqrt(8)
        }
        float m = lg[0];
        #pragma unroll
        for (int k = 1; k < 9; k++) m = fmaxf(m, lg[k]);
        float sum = 0.f;
        #pragma unroll
        for (int k = 0; k < 9; k++) { lg[k] = __expf(lg[k] - m); sum += lg[k]; }
        float inv = 1.f / sum;
        float ov = 0.f;
        #pragma unroll
        for (int k = 0; k < 9; k++) ov += (lg[k] * inv) * (vacc[k] + bvc);

        o_bf[(size_t)gp*96 + c] = f2b(ov);
        __syncthreads();   // WAR: s_s reused next iteration
    }
}

// ---------------------------------------------------------------------------
extern "C" void kernel_launch(void* const* d_in, const int* in_sizes, int n_in,
                              void* d_out, int out_size, void* d_ws, size_t ws_size,
                              hipStream_t stream) {
    (void)in_sizes; (void)n_in; (void)out_size; (void)ws_size;

    char* w = (char*)d_ws;
    float* ftf    = (float*)(w + 0);             // 12,582,912
    bf16*  fkvclb = (bf16*) (w + 12582912);      //  6,291,456
    float* flowf  = (float*)(w + 18874368);      //    262,144
    bf16*  wkTb   = (bf16*) (w + 19136512);      //     18,432
    bf16*  wvTb   = (bf16*) (w + 19154944);      //     18,432
    bf16*  wAq    = (bf16*) (w + 19173376);      //     18,432
    bf16*  wAo    = (bf16*) (w + 19191808);      //     18,432
    bf16*  wA1    = (bf16*) (w + 19210240);      //    774,144
    bf16*  wA2    = (bf16*) (w + 19984384);      //    331,776
    bf16*  wA3    = (bf16*) (w + 20316160);      //    387,072
    bf16*  wAm1   = (bf16*) (w + 20703232);      //     36,864
    bf16*  wAm2   = (bf16*) (w + 20740096);      //     36,864
    float* biasf  = (float*)(w + 20776960);      //      8,192
    int*   flag   = (int*)  (w + 20785152);      //        256
    // region A (14,680,064): cat[gp][224] (build->conv1,q_gemm) then xbuf f32 (o_gemm->mlp2)
    char*  regA   = w + 20785408;
    // region B (14,155,776): r1b (conv1->conv2) / off3 (conv3->attn) / hb (mlp1->mlp2)
    char*  regB   = w + 35465472;
    // region C (6,291,456): r2b (conv2->conv3) / q_bf (q_gemm->attn) / xb_bf (o_gemm->mlp1)
    char*  regC   = w + 49621248;
    // region D (6,291,456): o_bf (attn->o_gemm)
    char*  regD   = w + 55912704;
    // total 62,204,160 bytes

    bf16*  cat   = (bf16*) regA;
    float* xbuf  = (float*)regA;
    bf16*  r1b   = (bf16*) regB;
    bf16*  off3  = (bf16*) regB;
    bf16*  hb    = (bf16*) regB;
    bf16*  r2b   = (bf16*) regC;
    bf16*  q_bf  = (bf16*) regC;
    bf16*  xb_bf = (bf16*) regC;
    bf16*  o_bf  = (bf16*) regD;

    detect_dtype<<<1, 256, 0, stream>>>((const unsigned short*)d_in[0], flag);

    prep_all<<<12288, 256, 0, stream>>>(flag,
        d_in[0], d_in[1], d_in[2],
        d_in[3], d_in[4], d_in[5], d_in[6], d_in[7], d_in[8], d_in[9], d_in[10],
        d_in[11], d_in[12], d_in[13], d_in[14], d_in[15], d_in[16], d_in[17], d_in[18],
        d_in[19], d_in[20], d_in[21], d_in[22],
        ftf, fkvclb, flowf, wAq, wAo, wkTb, wvTb, wA1, wA2, wA3, wAm1, wAm2, biasf);

    build_cat<<<((size_t)Bv*Pv*224 + 255)/256, 256, 0, stream>>>(ftf, fkvclb, flowf, cat);

    conv_mfma<224, 224, 192, 6, 9, 0, 192><<<dim3(Hv, 2, Bv), 256, 0, stream>>>(
        cat, wA1, biasf + 0,   biasf + 192, nullptr, flag, r1b, nullptr);
    conv_mfma<192, 192,  96, 3, 9, 0,  96><<<dim3(Hv, 2, Bv), 256, 0, stream>>>(
        r1b, wA2, biasf + 384, biasf + 480, nullptr, flag, r2b, nullptr);
    conv_mfma< 96,  96, 224, 7, 9, 1, 216><<<dim3(Hv, 2, Bv), 256, 0, stream>>>(
        r2b, wA3, biasf + 576, nullptr,     nullptr, flag, off3, nullptr);

    // q = Wq @ feat_t + bq  (reads feat_t channels from cat, stride 224)
    conv_mfma<224,  96,  96, 3, 1, 1,  96><<<dim3(Hv, 2, Bv), 256, 0, stream>>>(
        cat, wAq, biasf + 792, nullptr,     nullptr, flag, q_bf, nullptr);

    attn_kernel<<<2048, 192, 0, stream>>>(flowf, fkvclb, off3, q_bf,
        wkTb, wvTb, biasf + 888, biasf + 984, o_bf);

    // x = feat_t + Wo @ o + bo  -> xbuf (f32 ch-major) + xb_bf (bf16 px-major)
    conv_mfma< 96,  96,  96, 3, 1, 4,  96><<<dim3(Hv, 2, Bv), 256, 0, stream>>>(
        o_bf, wAo, biasf + 1080, nullptr,   ftf,    flag, xbuf, xb_bf);

    conv_mfma< 96,  96, 192, 6, 1, 2, 192><<<dim3(Hv, 2, Bv), 256, 0, stream>>>(
        xb_bf, wAm1, biasf + 1176, nullptr, nullptr, flag, hb, nullptr);
    conv_mfma<192, 192,  96, 3, 1, 3,  96><<<dim3(Hv, 2, Bv), 256, 0, stream>>>(
        hb,   wAm2, biasf + 1368, nullptr,  xbuf,   flag, d_out, nullptr);
}

// Round 5
// 565.778 us; speedup vs baseline: 3.5761x; 1.1999x over previous
//
#include <hip/hip_runtime.h>
#include <hip/hip_bf16.h>
#include <math.h>

typedef __hip_bfloat16 bf16;
typedef __attribute__((ext_vector_type(8))) short s16x8;
typedef __attribute__((ext_vector_type(4))) short s16x4;
typedef __attribute__((ext_vector_type(4))) float fx4;

#define Bv 2
#define Cv 96
#define Hv 128
#define Wv 128
#define Pv (Hv*Wv)          /* 16384 */
#define NPIX (Bv*Pv)        /* 32768 */
#define Gv 12
#define Kv 9
#define PPB 7               /* pixels per dka block */
#define NPT 64              /* 63 points + 1 pad    */

__device__ __forceinline__ float b2f(bf16 x) { return __bfloat162float(x); }
__device__ __forceinline__ bf16 f2b(float x) { return __float2bfloat16(x); }

// dual-dtype input load: isf=1 -> float32, isf=0 -> bf16
__device__ __forceinline__ float ldin(const void* p, size_t i, int isf) {
    return isf ? ((const float*)p)[i] : __bfloat162float(((const bf16*)p)[i]);
}

// ---------------------------------------------------------------------------
// dtype detection (f32 read as bf16 shows NaN/Inf bit patterns in low halves)
// ---------------------------------------------------------------------------
__global__ void detect_dtype(const unsigned short* __restrict__ x, int* __restrict__ flag)
{
    __shared__ int bad;
    if (threadIdx.x == 0) bad = 0;
    __syncthreads();
    int cnt = 0;
    for (int i = threadIdx.x; i < 32768; i += 256) {
        unsigned short u = x[i];
        if ((u & 0x7F80) == 0x7F80) cnt++;
    }
    atomicAdd(&bad, cnt);
    __syncthreads();
    if (threadIdx.x == 0) flag[0] = (bad > 0) ? 1 : 0;   // 1 = float32 inputs
}

// ---------------------------------------------------------------------------
// prep: convert inputs; build MFMA A-layout weight buffers (bf16).
// wA layout: [(t*NC + kc)*COTOT + co]*32 + kq*8 + j,  k-in-chunk = kq*8+j
// ---------------------------------------------------------------------------
__global__ void prep_all(const int* __restrict__ flag,
    const void* ft, const void* fkv, const void* flow,
    const void* cw1, const void* cb1, const void* a1,
    const void* cw2, const void* cb2, const void* a2,
    const void* cw3, const void* cb3,
    const void* wq, const void* bq, const void* wk, const void* bk,
    const void* wv, const void* bv, const void* wo, const void* bo,
    const void* wm1, const void* bm1, const void* wm2, const void* bm2,
    float* __restrict__ ftf, bf16* __restrict__ fkvclb, float* __restrict__ flowf,
    bf16* __restrict__ wAq, bf16* __restrict__ wAo, bf16* __restrict__ wAkv,
    bf16* __restrict__ wA1, bf16* __restrict__ wA2, bf16* __restrict__ wA3,
    bf16* __restrict__ wAm1, bf16* __restrict__ wAm2,
    float* __restrict__ biasf)
{
    int isf = flag[0];
    size_t i = (size_t)blockIdx.x * 256 + threadIdx.x;
    if (i < (size_t)Bv*Cv*Pv) {
        ftf[i] = ldin(ft, i, isf);
        int c = (int)(i % 96);
        size_t rest = i / 96;
        int p = (int)(rest & (Pv-1));
        int b = (int)(rest >> 14);
        fkvclb[i] = f2b(ldin(fkv, ((size_t)(b*96 + c))*Pv + p, isf));
    }
    if (i < (size_t)Bv*2*Pv) flowf[i] = ldin(flow, i, isf);

    // conv1 weights: [192][194][9] -> wA1[t<9][kc<7][co<192][32]
    if (i < 9*7*192*32) {
        int q = (int)(i & 31);
        int rest = (int)(i >> 5);
        int co = rest % 192; rest /= 192;
        int kc = rest % 7;   int t = rest / 7;
        int ci = kc*32 + q;
        float v = (ci < 194) ? ldin(cw1, (size_t)co*194*9 + (size_t)ci*9 + t, isf) : 0.f;
        wA1[i] = f2b(v);
    }
    // conv2: [96][192][9] -> wA2[t<9][kc<6][co<96][32]
    if (i < 9*6*96*32) {
        int q = (int)(i & 31);
        int rest = (int)(i >> 5);
        int co = rest % 96; rest /= 96;
        int kc = rest % 6;  int t = rest / 6;
        int ci = kc*32 + q;
        wA2[i] = f2b(ldin(cw2, (size_t)co*192*9 + (size_t)ci*9 + t, isf));
    }
    // conv3: [216][96][9] -> wA3[t<9][kc<3][co<224][32], co>=216 zero
    if (i < 9*3*224*32) {
        int q = (int)(i & 31);
        int rest = (int)(i >> 5);
        int co = rest % 224; rest /= 224;
        int kc = rest % 3;   int t = rest / 3;
        int ci = kc*32 + q;
        float v = (co < 216) ? ldin(cw3, (size_t)co*96*9 + (size_t)ci*9 + t, isf) : 0.f;
        wA3[i] = f2b(v);
    }
    // mlp1: [192][96] -> wAm1[kc<3][co<192][32]
    if (i < 3*192*32) {
        int q = (int)(i & 31);
        int rest = (int)(i >> 5);
        int co = rest % 192;
        int kc = rest / 192;
        wAm1[i] = f2b(ldin(wm1, (size_t)co*96 + kc*32 + q, isf));
    }
    // mlp2: [96][192] -> wAm2[kc<6][co<96][32]
    if (i < 6*96*32) {
        int q = (int)(i & 31);
        int rest = (int)(i >> 5);
        int co = rest % 96;
        int kc = rest / 96;
        wAm2[i] = f2b(ldin(wm2, (size_t)co*192 + kc*32 + q, isf));
    }
    // wq / wo: [96][96] -> A-layout [kc<3][co<96][32]
    if (i < 3*96*32) {
        int q = (int)(i & 31);
        int rest = (int)(i >> 5);
        int co = rest % 96;
        int kc = rest / 96;
        wAq[i] = f2b(ldin(wq, (size_t)co*96 + kc*32 + q, isf));
        wAo[i] = f2b(ldin(wo, (size_t)co*96 + kc*32 + q, isf));
    }
    // wk/wv fused A-layout: wAkv[kc<3][co<192][32]; co<96 -> wk[co], co>=96 -> wv[co-96]
    if (i < 3*192*32) {
        int q = (int)(i & 31);
        int rest = (int)(i >> 5);
        int co = rest % 192;
        int kc = rest / 192;
        int ci = kc*32 + q;
        float v = (co < 96) ? ldin(wk, (size_t)co*96 + ci, isf)
                            : ldin(wv, (size_t)(co-96)*96 + ci, isf);
        wAkv[i] = f2b(v);
    }
    if (i < 192) biasf[i]       = ldin(cb1, i, isf);
    if (i < 192) biasf[192+i]   = ldin(a1, i, isf);
    if (i < 96)  biasf[384+i]   = ldin(cb2, i, isf);
    if (i < 96)  biasf[480+i]   = ldin(a2, i, isf);
    if (i < 216) biasf[576+i]   = ldin(cb3, i, isf);
    if (i < 96) {
        biasf[792+i]  = ldin(bq, i, isf);
        biasf[888+i]  = ldin(bk, i, isf);
        biasf[984+i]  = ldin(bv, i, isf);
        biasf[1080+i] = ldin(bo, i, isf);
        biasf[1368+i] = ldin(bm2, i, isf);
    }
    if (i < 192) biasf[1176+i] = ldin(bm1, i, isf);
}

// ---------------------------------------------------------------------------
// cat[gp][224] bf16 pixel-major: ci 0..95 feat_t, 96..191 warped kv, 192/193 flow, rest 0
// ---------------------------------------------------------------------------
__global__ void build_cat(const float* __restrict__ ftf, const bf16* __restrict__ fkvclb,
                          const float* __restrict__ flowf, bf16* __restrict__ cat)
{
    size_t idx = (size_t)blockIdx.x * 256 + threadIdx.x;
    if (idx >= (size_t)Bv*Pv*224) return;
    int ch = (int)(idx % 224);
    int gp = (int)(idx / 224);
    int p  = gp & (Pv-1);
    int bb = gp >> 14;
    float v = 0.f;
    if (ch < 96) {
        v = ftf[((size_t)bb*Cv + ch)*Pv + p];
    } else if (ch < 192) {
        int cc = ch - 96;
        int py = p >> 7, px = p & (Wv-1);
        float xs = (float)px + flowf[((size_t)bb*2 + 0)*Pv + p];
        float ys = (float)py + flowf[((size_t)bb*2 + 1)*Pv + p];
        float x0f = floorf(xs), y0f = floorf(ys);
        float wx = xs - x0f, wy = ys - y0f;
        int x0 = (int)x0f, y0 = (int)y0f;
        #pragma unroll
        for (int tt = 0; tt < 4; tt++) {
            int xi = x0 + (tt & 1), yi = y0 + (tt >> 1);
            float wt = ((tt & 1) ? wx : 1.f - wx) * ((tt >> 1) ? wy : 1.f - wy);
            if (xi >= 0 && xi < Wv && yi >= 0 && yi < Hv)
                v += wt * b2f(fkvclb[((size_t)bb*Pv + yi*Wv + xi)*96 + cc]);
        }
    } else if (ch < 194) {
        v = flowf[((size_t)bb*2 + (ch-192))*Pv + p];
    }
    cat[idx] = f2b(v);
}

// ---------------------------------------------------------------------------
// MFMA implicit-GEMM conv/1x1. Block 256 = 4 waves; tile 128 px x (COF*16) co.
// MODE 0: PReLU -> bf16 px-major    MODE 1: plain -> bf16 px-major (guard co<216)
// MODE 2: GELU  -> bf16 px-major    MODE 3: +bias +resid(f32 ch-major) -> d_out
// MODE 4: +bias +resid(f32 ch-major) -> outp f32 ch-major AND out2 bf16 px-major
// ---------------------------------------------------------------------------
template<int CSTR, int CIN_PAD, int COTOT, int COF, int TAPS, int MODE, int OCS>
__launch_bounds__(256)
__global__ void conv_mfma(const bf16* __restrict__ in, const bf16* __restrict__ wA,
                          const float* __restrict__ bias, const float* __restrict__ alpha,
                          const float* __restrict__ resid, const int* __restrict__ flag,
                          void* __restrict__ outp, void* __restrict__ out2)
{
    constexpr int NC = CIN_PAD / 32;
    constexpr int LDS_PX = (TAPS == 9) ? 3*130 : 128;
    __shared__ short sbuf[LDS_PX * 40];

    int tid = threadIdx.x;
    int wave = tid >> 6, lane = tid & 63;
    int n = lane & 15, kq = lane >> 4;
    int y = blockIdx.x, cob = blockIdx.y * (COF*16), bb = blockIdx.z;

    fx4 acc[COF][2];
    #pragma unroll
    for (int f = 0; f < COF; f++)
        #pragma unroll
        for (int j = 0; j < 2; j++)
            acc[f][j] = (fx4){0.f, 0.f, 0.f, 0.f};

    for (int kc = 0; kc < NC; kc++) {
        __syncthreads();
        if (TAPS == 9) {
            for (int i = tid; i < 3*130*4; i += 256) {
                int part = i & 3; int pxr = i >> 2;
                int r = pxr / 130; int px = pxr - r*130;
                int yy = y + r - 1, xx = px - 1;
                uint4 val = {0u, 0u, 0u, 0u};
                if (yy >= 0 && yy < Hv && xx >= 0 && xx < Wv)
                    val = *(const uint4*)(in + ((size_t)(bb*Pv + yy*Wv + xx)*CSTR + kc*32 + part*8));
                *(uint4*)&sbuf[(r*130 + px)*40 + part*8] = val;
            }
        } else {
            for (int i = tid; i < 128*4; i += 256) {
                int part = i & 3, px = i >> 2;
                uint4 val = *(const uint4*)(in + ((size_t)(bb*Pv + y*Wv + px)*CSTR + kc*32 + part*8));
                *(uint4*)&sbuf[px*40 + part*8] = val;
            }
        }
        __syncthreads();
        #pragma unroll
        for (int t = 0; t < TAPS; t++) {
            const bf16* wbase = wA + ((size_t)(t*NC + kc)*COTOT + cob + n)*32 + kq*8;
            s16x8 af[COF];
            #pragma unroll
            for (int f = 0; f < COF; f++)
                af[f] = *(const s16x8*)(wbase + (size_t)f*16*32);
            #pragma unroll
            for (int j = 0; j < 2; j++) {
                int pxs;
                if (TAPS == 9) {
                    int r = t / 3, dx = t % 3;
                    pxs = r*130 + wave*32 + j*16 + n + dx;
                } else {
                    pxs = wave*32 + j*16 + n;
                }
                s16x8 bfr = *(const s16x8*)&sbuf[pxs*40 + kq*8];
                #pragma unroll
                for (int f = 0; f < COF; f++)
                    acc[f][j] = __builtin_amdgcn_mfma_f32_16x16x32_bf16(af[f], bfr, acc[f][j], 0, 0, 0);
            }
        }
    }

    // epilogue: D col=lane&15 (pixel), row=(lane>>4)*4+reg (co)
    int pxbase = wave*32;
    #pragma unroll
    for (int f = 0; f < COF; f++) {
        int co0 = cob + f*16 + kq*4;
        if (MODE == 1 && co0 >= 216) continue;
        #pragma unroll
        for (int j = 0; j < 2; j++) {
            int px = pxbase + j*16 + n;
            size_t gp = (size_t)bb*Pv + (size_t)y*Wv + px;
            fx4 fr = acc[f][j];
            if (MODE == 3) {
                int isf = flag[0];
                #pragma unroll
                for (int rg = 0; rg < 4; rg++) {
                    int co = co0 + rg;
                    size_t oi = ((size_t)bb*COTOT + co)*Pv + (size_t)y*Wv + px;
                    float v = fr[rg] + bias[co] + resid[oi];
                    if (isf) ((float*)outp)[oi] = v;
                    else     ((bf16*)outp)[oi] = f2b(v);
                }
            } else if (MODE == 4) {
                s16x4 st;
                #pragma unroll
                for (int rg = 0; rg < 4; rg++) {
                    int co = co0 + rg;
                    size_t oi = ((size_t)bb*COTOT + co)*Pv + (size_t)y*Wv + px;
                    float v = fr[rg] + bias[co] + resid[oi];
                    ((float*)outp)[oi] = v;
                    bf16 bvv = f2b(v);
                    st[rg] = *(short*)&bvv;
                }
                *(s16x4*)((bf16*)out2 + gp*OCS + co0) = st;
            } else {
                s16x4 st;
                #pragma unroll
                for (int rg = 0; rg < 4; rg++) {
                    float v = fr[rg] + bias[co0 + rg];
                    if (MODE == 0) { float a = alpha[co0 + rg]; v = (v >= 0.f) ? v : a*v; }
                    if (MODE == 2) { v = 0.5f*v*(1.f + tanhf(0.7978845608028654f*(v + 0.044715f*v*v*v))); }
                    bf16 bvv = f2b(v);
                    st[rg] = *(short*)&bvv;
                }
                *(s16x4*)((bf16*)outp + gp*OCS + co0) = st;
            }
        }
    }
}

// ---------------------------------------------------------------------------
// Fused deformable attention: sample -> kv MFMA GEMM -> softmax -> o.
// Block 256 = 4 waves, 7 pixels = 63 points (+1 pad) per block.
// LDS: cbuf (coords, 6.1 KB) + s_s (64x104 bf16, 13 KB) + kv_s (64x200 bf16, 25.6 KB).
// GEMM: M=192 (k||v co, waves split M by 48), N=64 points, K=96.
// Epilogue: proven 8-lane shfl_xor softmax (8 | 96 and 8 | 256 keep groups aligned).
// ---------------------------------------------------------------------------
__launch_bounds__(256)
__global__ void dka_kernel(const float* __restrict__ flowf, const bf16* __restrict__ fkvclb,
    const bf16* __restrict__ off3, const bf16* __restrict__ q_bf,
    const bf16* __restrict__ wAkv, const float* __restrict__ bkf, const float* __restrict__ bvf,
    bf16* __restrict__ o_bf)
{
    __shared__ float cbuf[NPT*12*2];    // (sx, sy) per (point, group)
    __shared__ short s_s[NPT*104];      // sampled values, [pt][c], stride 104
    __shared__ short kv_s[NPT*200];     // k (co 0..95) || v (96..191), [pt][co]

    int tid = threadIdx.x;
    int pb0 = blockIdx.x * PPB;

    // --- phase 1a: sampling coordinates per (point, deform-group) ---
    for (int it = tid; it < NPT*12; it += 256) {
        int pt = it / 12, g = it - (it/12)*12;
        int pxl = pt / 9, k = pt - pxl*9;
        int gp = pb0 + pxl;
        float sx = -10.f, sy = -10.f;
        if (pt < 63 && gp < NPIX) {
            int bb = gp >> 14, p = gp & (Pv-1);
            int py = p >> 7, px = p & (Wv-1);
            float fx = flowf[((size_t)bb*2 + 0)*Pv + p];
            float fy = flowf[((size_t)bb*2 + 1)*Pv + p];
            float dy = b2f(off3[(size_t)gp*216 + (g*9 + k)*2    ]) + fy;
            float dx = b2f(off3[(size_t)gp*216 + (g*9 + k)*2 + 1]) + fx;
            sx = (float)(px + (k % 3) - 1) + dx;
            sy = (float)(py + (k / 3) - 1) + dy;
        }
        cbuf[it*2] = sx; cbuf[it*2+1] = sy;
    }
    __syncthreads();

    // --- phase 1b: bilinear gather into s_s[pt][c] ---
    for (int it = tid; it < NPT*96; it += 256) {
        int pt = it / 96, c = it - (it/96)*96;
        int g = c >> 3;
        int gp = pb0 + pt/9;
        float v = 0.f;
        if (pt < 63 && gp < NPIX) {
            int bb = gp >> 14;
            float sx = cbuf[(pt*12+g)*2], sy = cbuf[(pt*12+g)*2+1];
            float x0f = floorf(sx), y0f = floorf(sy);
            float wx = sx - x0f, wy = sy - y0f;
            int x0 = (int)x0f, y0 = (int)y0f;
            const bf16* base = fkvclb + ((size_t)bb*Pv)*96 + c;
            #pragma unroll
            for (int t = 0; t < 4; t++) {
                int xi = x0 + (t & 1), yi = y0 + (t >> 1);
                float wt = ((t & 1) ? wx : 1.f - wx) * ((t >> 1) ? wy : 1.f - wy);
                if (xi >= 0 && xi < Wv && yi >= 0 && yi < Hv)
                    v += wt * b2f(base[(size_t)(yi*Wv + xi)*96]);
            }
        }
        bf16 bv = f2b(v);
        s_s[pt*104 + c] = *(short*)&bv;
    }
    __syncthreads();

    // --- phase 2: kv = wAkv @ s  (M=192 split over waves, N=64, K=96) ---
    {
        int wave = tid >> 6, lane = tid & 63;
        int n = lane & 15, kq = lane >> 4;
        fx4 acc[3][4];
        #pragma unroll
        for (int mi = 0; mi < 3; mi++)
            #pragma unroll
            for (int nf = 0; nf < 4; nf++)
                acc[mi][nf] = (fx4){0.f, 0.f, 0.f, 0.f};
        #pragma unroll
        for (int kc = 0; kc < 3; kc++) {
            s16x8 b[4];
            #pragma unroll
            for (int nf = 0; nf < 4; nf++)
                b[nf] = *(const s16x8*)&s_s[(nf*16 + n)*104 + kc*32 + kq*8];
            #pragma unroll
            for (int mi = 0; mi < 3; mi++) {
                s16x8 a = *(const s16x8*)(wAkv + ((size_t)(kc*192 + (wave*3 + mi)*16 + n))*32 + kq*8);
                #pragma unroll
                for (int nf = 0; nf < 4; nf++)
                    acc[mi][nf] = __builtin_amdgcn_mfma_f32_16x16x32_bf16(a, b[nf], acc[mi][nf], 0, 0, 0);
            }
        }
        // phase 3: stage kv to LDS. D: col=point(lane&15), row=co((lane>>4)*4+rg)
        #pragma unroll
        for (int mi = 0; mi < 3; mi++)
            #pragma unroll
            for (int nf = 0; nf < 4; nf++) {
                s16x4 st;
                #pragma unroll
                for (int rg = 0; rg < 4; rg++) {
                    bf16 bv = f2b(acc[mi][nf][rg]);
                    st[rg] = *(short*)&bv;
                }
                *(s16x4*)&kv_s[(size_t)(nf*16 + n)*200 + (wave*3 + mi)*16 + kq*4] = st;
            }
    }
    __syncthreads();

    // --- phase 4: logits, softmax over 9 points, weighted v-sum, write o ---
    #pragma unroll
    for (int r = 0; r < 3; r++) {
        int idx = r*256 + tid;
        int pxl = idx / 96, c = idx - (idx/96)*96;
        int gp = pb0 + pxl;
        bool act = (pxl < PPB) && (gp < NPIX);   // uniform per 8-lane group
        float q = 0.f, bkc = 0.f, bvc = 0.f;
        if (act) { q = b2f(q_bf[(size_t)gp*96 + c]); bkc = bkf[c]; bvc = bvf[c]; }
        float lg[9];
        #pragma unroll
        for (int k = 0; k < 9; k++) {
            float kk = 0.f;
            if (act) kk = b2f(*(bf16*)&kv_s[(pxl*9 + k)*200 + c]) + bkc;
            float pr = q * kk;
            pr += __shfl_xor(pr, 1);
            pr += __shfl_xor(pr, 2);
            pr += __shfl_xor(pr, 4);
            lg[k] = pr * 0.35355339059327373f;   // 1/sqrt(8)
        }
        float m = lg[0];
        #pragma unroll
        for (int k = 1; k < 9; k++) m = fmaxf(m, lg[k]);
        float sum = 0.f;
        #pragma unroll
        for (int k = 0; k < 9; k++) { lg[k] = __expf(lg[k] - m); sum += lg[k]; }
        float inv = 1.f / sum;
        float ov = 0.f;
        #pragma unroll
        for (int k = 0; k < 9; k++) {
            float vv = 0.f;
            if (act) vv = b2f(*(bf16*)&kv_s[(pxl*9 + k)*200 + 96 + c]) + bvc;
            ov += (lg[k] * inv) * vv;
        }
        if (act) o_bf[(size_t)gp*96 + c] = f2b(ov);
    }
}

// ---------------------------------------------------------------------------
extern "C" void kernel_launch(void* const* d_in, const int* in_sizes, int n_in,
                              void* d_out, int out_size, void* d_ws, size_t ws_size,
                              hipStream_t stream) {
    (void)in_sizes; (void)n_in; (void)out_size; (void)ws_size;

    char* w = (char*)d_ws;
    float* ftf    = (float*)(w + 0);             // 12,582,912
    bf16*  fkvclb = (bf16*) (w + 12582912);      //  6,291,456
    float* flowf  = (float*)(w + 18874368);      //    262,144
    bf16*  wAkv   = (bf16*) (w + 19136512);      //     36,864
    bf16*  wAq    = (bf16*) (w + 19173376);      //     18,432
    bf16*  wAo    = (bf16*) (w + 19191808);      //     18,432
    bf16*  wA1    = (bf16*) (w + 19210240);      //    774,144
    bf16*  wA2    = (bf16*) (w + 19984384);      //    331,776
    bf16*  wA3    = (bf16*) (w + 20316160);      //    387,072
    bf16*  wAm1   = (bf16*) (w + 20703232);      //     36,864
    bf16*  wAm2   = (bf16*) (w + 20740096);      //     36,864
    float* biasf  = (float*)(w + 20776960);      //      8,192
    int*   flag   = (int*)  (w + 20785152);      //        256
    // region A (14,680,064): cat[gp][224] (build->conv1,q_gemm) then xbuf f32 (o_gemm->mlp2)
    char*  regA   = w + 20785408;
    // region B (14,155,776): r1b (conv1->conv2) / off3 (conv3->dka) / hb (mlp1->mlp2)
    char*  regB   = w + 35465472;
    // region C (6,291,456): r2b (conv2->conv3) / q_bf (q_gemm->dka) / xb_bf (o_gemm->mlp1)
    char*  regC   = w + 49621248;
    // region D (6,291,456): o_bf (dka->o_gemm)
    char*  regD   = w + 55912704;
    // total 62,204,160 bytes

    bf16*  cat   = (bf16*) regA;
    float* xbuf  = (float*)regA;
    bf16*  r1b   = (bf16*) regB;
    bf16*  off3  = (bf16*) regB;
    bf16*  hb    = (bf16*) regB;
    bf16*  r2b   = (bf16*) regC;
    bf16*  q_bf  = (bf16*) regC;
    bf16*  xb_bf = (bf16*) regC;
    bf16*  o_bf  = (bf16*) regD;

    detect_dtype<<<1, 256, 0, stream>>>((const unsigned short*)d_in[0], flag);

    prep_all<<<12288, 256, 0, stream>>>(flag,
        d_in[0], d_in[1], d_in[2],
        d_in[3], d_in[4], d_in[5], d_in[6], d_in[7], d_in[8], d_in[9], d_in[10],
        d_in[11], d_in[12], d_in[13], d_in[14], d_in[15], d_in[16], d_in[17], d_in[18],
        d_in[19], d_in[20], d_in[21], d_in[22],
        ftf, fkvclb, flowf, wAq, wAo, wAkv, wA1, wA2, wA3, wAm1, wAm2, biasf);

    build_cat<<<((size_t)Bv*Pv*224 + 255)/256, 256, 0, stream>>>(ftf, fkvclb, flowf, cat);

    conv_mfma<224, 224, 192, 6, 9, 0, 192><<<dim3(Hv, 2, Bv), 256, 0, stream>>>(
        cat, wA1, biasf + 0,   biasf + 192, nullptr, flag, r1b, nullptr);
    conv_mfma<192, 192,  96, 3, 9, 0,  96><<<dim3(Hv, 2, Bv), 256, 0, stream>>>(
        r1b, wA2, biasf + 384, biasf + 480, nullptr, flag, r2b, nullptr);
    conv_mfma< 96,  96, 224, 7, 9, 1, 216><<<dim3(Hv, 2, Bv), 256, 0, stream>>>(
        r2b, wA3, biasf + 576, nullptr,     nullptr, flag, off3, nullptr);

    // q = Wq @ feat_t + bq  (reads feat_t channels from cat, stride 224)
    conv_mfma<224,  96,  96, 3, 1, 1,  96><<<dim3(Hv, 2, Bv), 256, 0, stream>>>(
        cat, wAq, biasf + 792, nullptr,     nullptr, flag, q_bf, nullptr);

    // fused deformable attention (sample + kv GEMM + softmax + o)
    dka_kernel<<<(NPIX + PPB - 1)/PPB, 256, 0, stream>>>(
        flowf, fkvclb, off3, q_bf, wAkv, biasf + 888, biasf + 984, o_bf);

    // x = feat_t + Wo @ o + bo  -> xbuf (f32 ch-major) + xb_bf (bf16 px-major)
    conv_mfma< 96,  96,  96, 3, 1, 4,  96><<<dim3(Hv, 2, Bv), 256, 0, stream>>>(
        o_bf, wAo, biasf + 1080, nullptr,   ftf,    flag, xbuf, xb_bf);

    conv_mfma< 96,  96, 192, 6, 1, 2, 192><<<dim3(Hv, 2, Bv), 256, 0, stream>>>(
        xb_bf, wAm1, biasf + 1176, nullptr, nullptr, flag, hb, nullptr);
    conv_mfma<192, 192,  96, 3, 1, 3,  96><<<dim3(Hv, 2, Bv), 256, 0, stream>>>(
        hb,   wAm2, biasf + 1368, nullptr,  xbuf,   flag, d_out, nullptr);
}

// Round 6
// 418.750 us; speedup vs baseline: 4.8316x; 1.3511x over previous
//
#include <hip/hip_runtime.h>
#include <hip/hip_bf16.h>
#include <math.h>

typedef __hip_bfloat16 bf16;
typedef __attribute__((ext_vector_type(8))) short s16x8;
typedef __attribute__((ext_vector_type(4))) short s16x4;
typedef __attribute__((ext_vector_type(4))) float fx4;

#define Bv 2
#define Cv 96
#define Hv 128
#define Wv 128
#define Pv (Hv*Wv)          /* 16384 */
#define NPIX (Bv*Pv)        /* 32768 */
#define Gv 12
#define Kv 9
#define PPB 7               /* pixels per dka block */
#define NPT 64              /* 63 points + 1 pad    */

__device__ __forceinline__ float b2f(bf16 x) { return __bfloat162float(x); }
__device__ __forceinline__ bf16 f2b(float x) { return __float2bfloat16(x); }

// dual-dtype input load: isf=1 -> float32, isf=0 -> bf16
__device__ __forceinline__ float ldin(const void* p, size_t i, int isf) {
    return isf ? ((const float*)p)[i] : __bfloat162float(((const bf16*)p)[i]);
}

// ---------------------------------------------------------------------------
// dtype detection (f32 read as bf16 shows NaN/Inf bit patterns in low halves)
// ---------------------------------------------------------------------------
__global__ void detect_dtype(const unsigned short* __restrict__ x, int* __restrict__ flag)
{
    __shared__ int bad;
    if (threadIdx.x == 0) bad = 0;
    __syncthreads();
    int cnt = 0;
    for (int i = threadIdx.x; i < 32768; i += 256) {
        unsigned short u = x[i];
        if ((u & 0x7F80) == 0x7F80) cnt++;
    }
    atomicAdd(&bad, cnt);
    __syncthreads();
    if (threadIdx.x == 0) flag[0] = (bad > 0) ? 1 : 0;   // 1 = float32 inputs
}

// ---------------------------------------------------------------------------
// prep: convert inputs; build MFMA A-layout weight buffers (bf16).
// wA layout: [(t*NC + kc)*COTOT + co]*32 + kq*8 + j,  k-in-chunk = kq*8+j
// ---------------------------------------------------------------------------
__global__ void prep_all(const int* __restrict__ flag,
    const void* ft, const void* fkv, const void* flow,
    const void* cw1, const void* cb1, const void* a1,
    const void* cw2, const void* cb2, const void* a2,
    const void* cw3, const void* cb3,
    const void* wq, const void* bq, const void* wk, const void* bk,
    const void* wv, const void* bv, const void* wo, const void* bo,
    const void* wm1, const void* bm1, const void* wm2, const void* bm2,
    float* __restrict__ ftf, bf16* __restrict__ fkvclb, float* __restrict__ flowf,
    bf16* __restrict__ wAq, bf16* __restrict__ wAo, bf16* __restrict__ wAkv,
    bf16* __restrict__ wA1, bf16* __restrict__ wA2, bf16* __restrict__ wA3,
    bf16* __restrict__ wAm1, bf16* __restrict__ wAm2,
    float* __restrict__ biasf)
{
    int isf = flag[0];
    size_t i = (size_t)blockIdx.x * 256 + threadIdx.x;
    if (i < (size_t)Bv*Cv*Pv) {
        ftf[i] = ldin(ft, i, isf);
        int c = (int)(i % 96);
        size_t rest = i / 96;
        int p = (int)(rest & (Pv-1));
        int b = (int)(rest >> 14);
        fkvclb[i] = f2b(ldin(fkv, ((size_t)(b*96 + c))*Pv + p, isf));
    }
    if (i < (size_t)Bv*2*Pv) flowf[i] = ldin(flow, i, isf);

    // conv1 weights: [192][194][9] -> wA1[t<9][kc<7][co<192][32]
    if (i < 9*7*192*32) {
        int q = (int)(i & 31);
        int rest = (int)(i >> 5);
        int co = rest % 192; rest /= 192;
        int kc = rest % 7;   int t = rest / 7;
        int ci = kc*32 + q;
        float v = (ci < 194) ? ldin(cw1, (size_t)co*194*9 + (size_t)ci*9 + t, isf) : 0.f;
        wA1[i] = f2b(v);
    }
    // conv2: [96][192][9] -> wA2[t<9][kc<6][co<96][32]
    if (i < 9*6*96*32) {
        int q = (int)(i & 31);
        int rest = (int)(i >> 5);
        int co = rest % 96; rest /= 96;
        int kc = rest % 6;  int t = rest / 6;
        int ci = kc*32 + q;
        wA2[i] = f2b(ldin(cw2, (size_t)co*192*9 + (size_t)ci*9 + t, isf));
    }
    // conv3: [216][96][9] -> wA3[t<9][kc<3][co<224][32], co>=216 zero
    if (i < 9*3*224*32) {
        int q = (int)(i & 31);
        int rest = (int)(i >> 5);
        int co = rest % 224; rest /= 224;
        int kc = rest % 3;   int t = rest / 3;
        int ci = kc*32 + q;
        float v = (co < 216) ? ldin(cw3, (size_t)co*96*9 + (size_t)ci*9 + t, isf) : 0.f;
        wA3[i] = f2b(v);
    }
    // mlp1: [192][96] -> wAm1[kc<3][co<192][32]
    if (i < 3*192*32) {
        int q = (int)(i & 31);
        int rest = (int)(i >> 5);
        int co = rest % 192;
        int kc = rest / 192;
        wAm1[i] = f2b(ldin(wm1, (size_t)co*96 + kc*32 + q, isf));
    }
    // mlp2: [96][192] -> wAm2[kc<6][co<96][32]
    if (i < 6*96*32) {
        int q = (int)(i & 31);
        int rest = (int)(i >> 5);
        int co = rest % 96;
        int kc = rest / 96;
        wAm2[i] = f2b(ldin(wm2, (size_t)co*192 + kc*32 + q, isf));
    }
    // wq / wo: [96][96] -> A-layout [kc<3][co<96][32]
    if (i < 3*96*32) {
        int q = (int)(i & 31);
        int rest = (int)(i >> 5);
        int co = rest % 96;
        int kc = rest / 96;
        wAq[i] = f2b(ldin(wq, (size_t)co*96 + kc*32 + q, isf));
        wAo[i] = f2b(ldin(wo, (size_t)co*96 + kc*32 + q, isf));
    }
    // wk/wv fused A-layout: wAkv[kc<3][co<192][32]; co<96 -> wk[co], co>=96 -> wv[co-96]
    if (i < 3*192*32) {
        int q = (int)(i & 31);
        int rest = (int)(i >> 5);
        int co = rest % 192;
        int kc = rest / 192;
        int ci = kc*32 + q;
        float v = (co < 96) ? ldin(wk, (size_t)co*96 + ci, isf)
                            : ldin(wv, (size_t)(co-96)*96 + ci, isf);
        wAkv[i] = f2b(v);
    }
    if (i < 192) biasf[i]       = ldin(cb1, i, isf);
    if (i < 192) biasf[192+i]   = ldin(a1, i, isf);
    if (i < 96)  biasf[384+i]   = ldin(cb2, i, isf);
    if (i < 96)  biasf[480+i]   = ldin(a2, i, isf);
    if (i < 216) biasf[576+i]   = ldin(cb3, i, isf);
    if (i < 96) {
        biasf[792+i]  = ldin(bq, i, isf);
        biasf[888+i]  = ldin(bk, i, isf);
        biasf[984+i]  = ldin(bv, i, isf);
        biasf[1080+i] = ldin(bo, i, isf);
        biasf[1368+i] = ldin(bm2, i, isf);
    }
    if (i < 192) biasf[1176+i] = ldin(bm1, i, isf);
}

// ---------------------------------------------------------------------------
// cat[gp][224] bf16 pixel-major: ci 0..95 feat_t, 96..191 warped kv, 192/193 flow, rest 0
// ---------------------------------------------------------------------------
__global__ void build_cat(const float* __restrict__ ftf, const bf16* __restrict__ fkvclb,
                          const float* __restrict__ flowf, bf16* __restrict__ cat)
{
    size_t idx = (size_t)blockIdx.x * 256 + threadIdx.x;
    if (idx >= (size_t)Bv*Pv*224) return;
    int ch = (int)(idx % 224);
    int gp = (int)(idx / 224);
    int p  = gp & (Pv-1);
    int bb = gp >> 14;
    float v = 0.f;
    if (ch < 96) {
        v = ftf[((size_t)bb*Cv + ch)*Pv + p];
    } else if (ch < 192) {
        int cc = ch - 96;
        int py = p >> 7, px = p & (Wv-1);
        float xs = (float)px + flowf[((size_t)bb*2 + 0)*Pv + p];
        float ys = (float)py + flowf[((size_t)bb*2 + 1)*Pv + p];
        float x0f = floorf(xs), y0f = floorf(ys);
        float wx = xs - x0f, wy = ys - y0f;
        int x0 = (int)x0f, y0 = (int)y0f;
        #pragma unroll
        for (int tt = 0; tt < 4; tt++) {
            int xi = x0 + (tt & 1), yi = y0 + (tt >> 1);
            float wt = ((tt & 1) ? wx : 1.f - wx) * ((tt >> 1) ? wy : 1.f - wy);
            if (xi >= 0 && xi < Wv && yi >= 0 && yi < Hv)
                v += wt * b2f(fkvclb[((size_t)bb*Pv + yi*Wv + xi)*96 + cc]);
        }
    } else if (ch < 194) {
        v = flowf[((size_t)bb*2 + (ch-192))*Pv + p];
    }
    cat[idx] = f2b(v);
}

// ---------------------------------------------------------------------------
// MFMA implicit-GEMM conv/1x1. Block 256 = 4 waves; tile 128 px x (COF*16) co.
// MODE 0: PReLU -> bf16 px-major    MODE 1: plain -> bf16 px-major (guard co<216)
// MODE 2: GELU  -> bf16 px-major    MODE 3: +bias +resid(f32 ch-major) -> d_out
// MODE 4: +bias +resid(f32 ch-major) -> outp f32 ch-major AND out2 bf16 px-major
// ---------------------------------------------------------------------------
template<int CSTR, int CIN_PAD, int COTOT, int COF, int TAPS, int MODE, int OCS>
__launch_bounds__(256)
__global__ void conv_mfma(const bf16* __restrict__ in, const bf16* __restrict__ wA,
                          const float* __restrict__ bias, const float* __restrict__ alpha,
                          const float* __restrict__ resid, const int* __restrict__ flag,
                          void* __restrict__ outp, void* __restrict__ out2)
{
    constexpr int NC = CIN_PAD / 32;
    constexpr int LDS_PX = (TAPS == 9) ? 3*130 : 128;
    __shared__ short sbuf[LDS_PX * 40];

    int tid = threadIdx.x;
    int wave = tid >> 6, lane = tid & 63;
    int n = lane & 15, kq = lane >> 4;
    int y = blockIdx.x, cob = blockIdx.y * (COF*16), bb = blockIdx.z;

    fx4 acc[COF][2];
    #pragma unroll
    for (int f = 0; f < COF; f++)
        #pragma unroll
        for (int j = 0; j < 2; j++)
            acc[f][j] = (fx4){0.f, 0.f, 0.f, 0.f};

    for (int kc = 0; kc < NC; kc++) {
        __syncthreads();
        if (TAPS == 9) {
            for (int i = tid; i < 3*130*4; i += 256) {
                int part = i & 3; int pxr = i >> 2;
                int r = pxr / 130; int px = pxr - r*130;
                int yy = y + r - 1, xx = px - 1;
                uint4 val = {0u, 0u, 0u, 0u};
                if (yy >= 0 && yy < Hv && xx >= 0 && xx < Wv)
                    val = *(const uint4*)(in + ((size_t)(bb*Pv + yy*Wv + xx)*CSTR + kc*32 + part*8));
                *(uint4*)&sbuf[(r*130 + px)*40 + part*8] = val;
            }
        } else {
            for (int i = tid; i < 128*4; i += 256) {
                int part = i & 3, px = i >> 2;
                uint4 val = *(const uint4*)(in + ((size_t)(bb*Pv + y*Wv + px)*CSTR + kc*32 + part*8));
                *(uint4*)&sbuf[px*40 + part*8] = val;
            }
        }
        __syncthreads();
        #pragma unroll
        for (int t = 0; t < TAPS; t++) {
            const bf16* wbase = wA + ((size_t)(t*NC + kc)*COTOT + cob + n)*32 + kq*8;
            s16x8 af[COF];
            #pragma unroll
            for (int f = 0; f < COF; f++)
                af[f] = *(const s16x8*)(wbase + (size_t)f*16*32);
            #pragma unroll
            for (int j = 0; j < 2; j++) {
                int pxs;
                if (TAPS == 9) {
                    int r = t / 3, dx = t % 3;
                    pxs = r*130 + wave*32 + j*16 + n + dx;
                } else {
                    pxs = wave*32 + j*16 + n;
                }
                s16x8 bfr = *(const s16x8*)&sbuf[pxs*40 + kq*8];
                #pragma unroll
                for (int f = 0; f < COF; f++)
                    acc[f][j] = __builtin_amdgcn_mfma_f32_16x16x32_bf16(af[f], bfr, acc[f][j], 0, 0, 0);
            }
        }
    }

    // epilogue: D col=lane&15 (pixel), row=(lane>>4)*4+reg (co)
    int pxbase = wave*32;
    #pragma unroll
    for (int f = 0; f < COF; f++) {
        int co0 = cob + f*16 + kq*4;
        if (MODE == 1 && co0 >= 216) continue;
        #pragma unroll
        for (int j = 0; j < 2; j++) {
            int px = pxbase + j*16 + n;
            size_t gp = (size_t)bb*Pv + (size_t)y*Wv + px;
            fx4 fr = acc[f][j];
            if (MODE == 3) {
                int isf = flag[0];
                #pragma unroll
                for (int rg = 0; rg < 4; rg++) {
                    int co = co0 + rg;
                    size_t oi = ((size_t)bb*COTOT + co)*Pv + (size_t)y*Wv + px;
                    float v = fr[rg] + bias[co] + resid[oi];
                    if (isf) ((float*)outp)[oi] = v;
                    else     ((bf16*)outp)[oi] = f2b(v);
                }
            } else if (MODE == 4) {
                s16x4 st;
                #pragma unroll
                for (int rg = 0; rg < 4; rg++) {
                    int co = co0 + rg;
                    size_t oi = ((size_t)bb*COTOT + co)*Pv + (size_t)y*Wv + px;
                    float v = fr[rg] + bias[co] + resid[oi];
                    ((float*)outp)[oi] = v;
                    bf16 bvv = f2b(v);
                    st[rg] = *(short*)&bvv;
                }
                *(s16x4*)((bf16*)out2 + gp*OCS + co0) = st;
            } else {
                s16x4 st;
                #pragma unroll
                for (int rg = 0; rg < 4; rg++) {
                    float v = fr[rg] + bias[co0 + rg];
                    if (MODE == 0) { float a = alpha[co0 + rg]; v = (v >= 0.f) ? v : a*v; }
                    if (MODE == 2) { v = 0.5f*v*(1.f + tanhf(0.7978845608028654f*(v + 0.044715f*v*v*v))); }
                    bf16 bvv = f2b(v);
                    st[rg] = *(short*)&bvv;
                }
                *(s16x4*)((bf16*)outp + gp*OCS + co0) = st;
            }
        }
    }
}

// ---------------------------------------------------------------------------
// Fused deformable attention: sample -> kv MFMA GEMM -> softmax -> o.
// Block 256 = 4 waves, 7 pixels = 63 points (+1 pad) per block.
// Phase 1: item = (point, group): coords inline, 4 UNCONDITIONAL clamped
// uint4 gathers (8 ch / load), OOB handled by zeroing tap weight. 12 vector
// loads per thread total (was 96 scalar). No cbuf -> LDS 38.9 KB, 4 blocks/CU.
// GEMM: M=192 (k||v co, waves split M by 48), N=64 points, K=96.
// ---------------------------------------------------------------------------
__launch_bounds__(256)
__global__ void dka_kernel(const float* __restrict__ flowf, const bf16* __restrict__ fkvclb,
    const bf16* __restrict__ off3, const bf16* __restrict__ q_bf,
    const bf16* __restrict__ wAkv, const float* __restrict__ bkf, const float* __restrict__ bvf,
    bf16* __restrict__ o_bf)
{
    __shared__ short s_s[NPT*104];      // sampled values, [pt][c], stride 104
    __shared__ short kv_s[NPT*200];     // k (co 0..95) || v (96..191), [pt][co]

    int tid = threadIdx.x;
    int pb0 = blockIdx.x * PPB;

    // --- phase 1: sample 8 channels per item = (point, deform-group) ---
    #pragma unroll
    for (int r = 0; r < 3; r++) {
        int it = r*256 + tid;           // 768 items = 64 pts x 12 groups
        int pt = it / 12, g = it - (it/12)*12;
        int pxl = pt / 9, k = pt - pxl*9;
        int gp0 = pb0 + pxl;
        bool act = (pt < 63) && (gp0 < NPIX);
        int gp = act ? gp0 : (NPIX-1);
        int bb = gp >> 14, p = gp & (Pv-1);
        int py = p >> 7, px = p & (Wv-1);
        float fx = flowf[((size_t)bb*2 + 0)*Pv + p];
        float fy = flowf[((size_t)bb*2 + 1)*Pv + p];
        float dy = b2f(off3[(size_t)gp*216 + (g*9 + k)*2    ]) + fy;
        float dx = b2f(off3[(size_t)gp*216 + (g*9 + k)*2 + 1]) + fx;
        float sx = (float)(px + (k % 3) - 1) + dx;
        float sy = (float)(py + (k / 3) - 1) + dy;
        float x0f = floorf(sx), y0f = floorf(sy);
        float wx = sx - x0f, wy = sy - y0f;
        int x0 = (int)x0f, y0 = (int)y0f;
        const bf16* base = fkvclb + ((size_t)bb*Pv)*96 + g*8;

        float w[4]; uint4 t4[4];
        #pragma unroll
        for (int t = 0; t < 4; t++) {
            int xi = x0 + (t & 1), yi = y0 + (t >> 1);
            float wt = ((t & 1) ? wx : 1.f - wx) * ((t >> 1) ? wy : 1.f - wy);
            bool vld = (xi >= 0) & (xi < Wv) & (yi >= 0) & (yi < Hv);
            int xc = min(max(xi, 0), Wv-1), yc = min(max(yi, 0), Hv-1);
            w[t] = (act && vld) ? wt : 0.f;
            t4[t] = *(const uint4*)(base + (size_t)(yc*Wv + xc)*96);
        }
        float v[8];
        #pragma unroll
        for (int j = 0; j < 8; j++) v[j] = 0.f;
        #pragma unroll
        for (int t = 0; t < 4; t++) {
            const bf16* pp = (const bf16*)&t4[t];
            #pragma unroll
            for (int j = 0; j < 8; j++) v[j] += w[t] * b2f(pp[j]);
        }
        s16x8 st;
        #pragma unroll
        for (int j = 0; j < 8; j++) { bf16 bv = f2b(v[j]); st[j] = *(short*)&bv; }
        *(s16x8*)&s_s[pt*104 + g*8] = st;
    }
    __syncthreads();

    // --- phase 2: kv = wAkv @ s  (M=192 split over waves, N=64, K=96) ---
    {
        int wave = tid >> 6, lane = tid & 63;
        int n = lane & 15, kq = lane >> 4;
        fx4 acc[3][4];
        #pragma unroll
        for (int mi = 0; mi < 3; mi++)
            #pragma unroll
            for (int nf = 0; nf < 4; nf++)
                acc[mi][nf] = (fx4){0.f, 0.f, 0.f, 0.f};
        #pragma unroll
        for (int kc = 0; kc < 3; kc++) {
            s16x8 b[4];
            #pragma unroll
            for (int nf = 0; nf < 4; nf++)
                b[nf] = *(const s16x8*)&s_s[(nf*16 + n)*104 + kc*32 + kq*8];
            #pragma unroll
            for (int mi = 0; mi < 3; mi++) {
                s16x8 a = *(const s16x8*)(wAkv + ((size_t)(kc*192 + (wave*3 + mi)*16 + n))*32 + kq*8);
                #pragma unroll
                for (int nf = 0; nf < 4; nf++)
                    acc[mi][nf] = __builtin_amdgcn_mfma_f32_16x16x32_bf16(a, b[nf], acc[mi][nf], 0, 0, 0);
            }
        }
        // phase 3: stage kv to LDS. D: col=point(lane&15), row=co((lane>>4)*4+rg)
        #pragma unroll
        for (int mi = 0; mi < 3; mi++)
            #pragma unroll
            for (int nf = 0; nf < 4; nf++) {
                s16x4 st;
                #pragma unroll
                for (int rg = 0; rg < 4; rg++) {
                    bf16 bv = f2b(acc[mi][nf][rg]);
                    st[rg] = *(short*)&bv;
                }
                *(s16x4*)&kv_s[(size_t)(nf*16 + n)*200 + (wave*3 + mi)*16 + kq*4] = st;
            }
    }
    __syncthreads();

    // --- phase 4: logits, softmax over 9 points, weighted v-sum, write o ---
    #pragma unroll
    for (int r = 0; r < 3; r++) {
        int idx = r*256 + tid;
        int pxl = idx / 96, c = idx - (idx/96)*96;
        int gp = pb0 + pxl;
        bool act = (pxl < PPB) && (gp < NPIX);   // uniform per 8-lane group
        float q = 0.f, bkc = 0.f, bvc = 0.f;
        if (act) { q = b2f(q_bf[(size_t)gp*96 + c]); bkc = bkf[c]; bvc = bvf[c]; }
        float lg[9];
        #pragma unroll
        for (int k = 0; k < 9; k++) {
            float kk = 0.f;
            if (act) kk = b2f(*(bf16*)&kv_s[(pxl*9 + k)*200 + c]) + bkc;
            float pr = q * kk;
            pr += __shfl_xor(pr, 1);
            pr += __shfl_xor(pr, 2);
            pr += __shfl_xor(pr, 4);
            lg[k] = pr * 0.35355339059327373f;   // 1/sqrt(8)
        }
        float m = lg[0];
        #pragma unroll
        for (int k = 1; k < 9; k++) m = fmaxf(m, lg[k]);
        float sum = 0.f;
        #pragma unroll
        for (int k = 0; k < 9; k++) { lg[k] = __expf(lg[k] - m); sum += lg[k]; }
        float inv = 1.f / sum;
        float ov = 0.f;
        #pragma unroll
        for (int k = 0; k < 9; k++) {
            float vv = 0.f;
            if (act) vv = b2f(*(bf16*)&kv_s[(pxl*9 + k)*200 + 96 + c]) + bvc;
            ov += (lg[k] * inv) * vv;
        }
        if (act) o_bf[(size_t)gp*96 + c] = f2b(ov);
    }
}

// ---------------------------------------------------------------------------
extern "C" void kernel_launch(void* const* d_in, const int* in_sizes, int n_in,
                              void* d_out, int out_size, void* d_ws, size_t ws_size,
                              hipStream_t stream) {
    (void)in_sizes; (void)n_in; (void)out_size; (void)ws_size;

    char* w = (char*)d_ws;
    float* ftf    = (float*)(w + 0);             // 12,582,912
    bf16*  fkvclb = (bf16*) (w + 12582912);      //  6,291,456
    float* flowf  = (float*)(w + 18874368);      //    262,144
    bf16*  wAkv   = (bf16*) (w + 19136512);      //     36,864
    bf16*  wAq    = (bf16*) (w + 19173376);      //     18,432
    bf16*  wAo    = (bf16*) (w + 19191808);      //     18,432
    bf16*  wA1    = (bf16*) (w + 19210240);      //    774,144
    bf16*  wA2    = (bf16*) (w + 19984384);      //    331,776
    bf16*  wA3    = (bf16*) (w + 20316160);      //    387,072
    bf16*  wAm1   = (bf16*) (w + 20703232);      //     36,864
    bf16*  wAm2   = (bf16*) (w + 20740096);      //     36,864
    float* biasf  = (float*)(w + 20776960);      //      8,192
    int*   flag   = (int*)  (w + 20785152);      //        256
    // region A (14,680,064): cat[gp][224] (build->conv1,q_gemm) then xbuf f32 (o_gemm->mlp2)
    char*  regA   = w + 20785408;
    // region B (14,155,776): r1b (conv1->conv2) / off3 (conv3->dka) / hb (mlp1->mlp2)
    char*  regB   = w + 35465472;
    // region C (6,291,456): r2b (conv2->conv3) / q_bf (q_gemm->dka) / xb_bf (o_gemm->mlp1)
    char*  regC   = w + 49621248;
    // region D (6,291,456): o_bf (dka->o_gemm)
    char*  regD   = w + 55912704;
    // total 62,204,160 bytes

    bf16*  cat   = (bf16*) regA;
    float* xbuf  = (float*)regA;
    bf16*  r1b   = (bf16*) regB;
    bf16*  off3  = (bf16*) regB;
    bf16*  hb    = (bf16*) regB;
    bf16*  r2b   = (bf16*) regC;
    bf16*  q_bf  = (bf16*) regC;
    bf16*  xb_bf = (bf16*) regC;
    bf16*  o_bf  = (bf16*) regD;

    detect_dtype<<<1, 256, 0, stream>>>((const unsigned short*)d_in[0], flag);

    prep_all<<<12288, 256, 0, stream>>>(flag,
        d_in[0], d_in[1], d_in[2],
        d_in[3], d_in[4], d_in[5], d_in[6], d_in[7], d_in[8], d_in[9], d_in[10],
        d_in[11], d_in[12], d_in[13], d_in[14], d_in[15], d_in[16], d_in[17], d_in[18],
        d_in[19], d_in[20], d_in[21], d_in[22],
        ftf, fkvclb, flowf, wAq, wAo, wAkv, wA1, wA2, wA3, wAm1, wAm2, biasf);

    build_cat<<<((size_t)Bv*Pv*224 + 255)/256, 256, 0, stream>>>(ftf, fkvclb, flowf, cat);

    conv_mfma<224, 224, 192, 6, 9, 0, 192><<<dim3(Hv, 2, Bv), 256, 0, stream>>>(
        cat, wA1, biasf + 0,   biasf + 192, nullptr, flag, r1b, nullptr);
    conv_mfma<192, 192,  96, 3, 9, 0,  96><<<dim3(Hv, 2, Bv), 256, 0, stream>>>(
        r1b, wA2, biasf + 384, biasf + 480, nullptr, flag, r2b, nullptr);
    conv_mfma< 96,  96, 224, 7, 9, 1, 216><<<dim3(Hv, 2, Bv), 256, 0, stream>>>(
        r2b, wA3, biasf + 576, nullptr,     nullptr, flag, off3, nullptr);

    // q = Wq @ feat_t + bq  (reads feat_t channels from cat, stride 224)
    conv_mfma<224,  96,  96, 3, 1, 1,  96><<<dim3(Hv, 2, Bv), 256, 0, stream>>>(
        cat, wAq, biasf + 792, nullptr,     nullptr, flag, q_bf, nullptr);

    // fused deformable attention (sample + kv GEMM + softmax + o)
    dka_kernel<<<(NPIX + PPB - 1)/PPB, 256, 0, stream>>>(
        flowf, fkvclb, off3, q_bf, wAkv, biasf + 888, biasf + 984, o_bf);

    // x = feat_t + Wo @ o + bo  -> xbuf (f32 ch-major) + xb_bf (bf16 px-major)
    conv_mfma< 96,  96,  96, 3, 1, 4,  96><<<dim3(Hv, 2, Bv), 256, 0, stream>>>(
        o_bf, wAo, biasf + 1080, nullptr,   ftf,    flag, xbuf, xb_bf);

    conv_mfma< 96,  96, 192, 6, 1, 2, 192><<<dim3(Hv, 2, Bv), 256, 0, stream>>>(
        xb_bf, wAm1, biasf + 1176, nullptr, nullptr, flag, hb, nullptr);
    conv_mfma<192, 192,  96, 3, 1, 3,  96><<<dim3(Hv, 2, Bv), 256, 0, stream>>>(
        hb,   wAm2, biasf + 1368, nullptr,  xbuf,   flag, d_out, nullptr);
}

// Round 7
// 386.373 us; speedup vs baseline: 5.2365x; 1.0838x over previous
//
#include <hip/hip_runtime.h>
#include <hip/hip_bf16.h>
#include <math.h>

typedef __hip_bfloat16 bf16;
typedef __attribute__((ext_vector_type(8))) short s16x8;
typedef __attribute__((ext_vector_type(4))) short s16x4;
typedef __attribute__((ext_vector_type(4))) float fx4;

#define Bv 2
#define Cv 96
#define Hv 128
#define Wv 128
#define Pv (Hv*Wv)          /* 16384 */
#define NPIX (Bv*Pv)        /* 32768 */
#define Gv 12
#define Kv 9
#define PPB 7               /* pixels per dka block */
#define NPT 64              /* 63 points + 1 pad    */

__device__ __forceinline__ float b2f(bf16 x) { return __bfloat162float(x); }
__device__ __forceinline__ bf16 f2b(float x) { return __float2bfloat16(x); }

// dual-dtype input load: isf=1 -> float32, isf=0 -> bf16
__device__ __forceinline__ float ldin(const void* p, size_t i, int isf) {
    return isf ? ((const float*)p)[i] : __bfloat162float(((const bf16*)p)[i]);
}

// ---------------------------------------------------------------------------
// dtype detection (f32 read as bf16 shows NaN/Inf bit patterns in low halves)
// ---------------------------------------------------------------------------
__global__ void detect_dtype(const unsigned short* __restrict__ x, int* __restrict__ flag)
{
    __shared__ int bad;
    if (threadIdx.x == 0) bad = 0;
    __syncthreads();
    int cnt = 0;
    for (int i = threadIdx.x; i < 32768; i += 256) {
        unsigned short u = x[i];
        if ((u & 0x7F80) == 0x7F80) cnt++;
    }
    atomicAdd(&bad, cnt);
    __syncthreads();
    if (threadIdx.x == 0) flag[0] = (bad > 0) ? 1 : 0;   // 1 = float32 inputs
}

// ---------------------------------------------------------------------------
// prep: convert inputs; build MFMA A-layout weight buffers (bf16).
// wA layout: [(t*NC + kc)*COTOT + co]*32 + kq*8 + j,  k-in-chunk = kq*8+j
// ---------------------------------------------------------------------------
__global__ void prep_all(const int* __restrict__ flag,
    const void* ft, const void* fkv, const void* flow,
    const void* cw1, const void* cb1, const void* a1,
    const void* cw2, const void* cb2, const void* a2,
    const void* cw3, const void* cb3,
    const void* wq, const void* bq, const void* wk, const void* bk,
    const void* wv, const void* bv, const void* wo, const void* bo,
    const void* wm1, const void* bm1, const void* wm2, const void* bm2,
    float* __restrict__ ftf, bf16* __restrict__ fkvclb, float* __restrict__ flowf,
    bf16* __restrict__ wAq, bf16* __restrict__ wAo, bf16* __restrict__ wAkv,
    bf16* __restrict__ wA1, bf16* __restrict__ wA2, bf16* __restrict__ wA3,
    bf16* __restrict__ wAm1, bf16* __restrict__ wAm2,
    float* __restrict__ biasf)
{
    int isf = flag[0];
    size_t i = (size_t)blockIdx.x * 256 + threadIdx.x;
    if (i < (size_t)Bv*Cv*Pv) {
        ftf[i] = ldin(ft, i, isf);
        int c = (int)(i % 96);
        size_t rest = i / 96;
        int p = (int)(rest & (Pv-1));
        int b = (int)(rest >> 14);
        fkvclb[i] = f2b(ldin(fkv, ((size_t)(b*96 + c))*Pv + p, isf));
    }
    if (i < (size_t)Bv*2*Pv) flowf[i] = ldin(flow, i, isf);

    // conv1 weights: [192][194][9] -> wA1[t<9][kc<7][co<192][32]
    if (i < 9*7*192*32) {
        int q = (int)(i & 31);
        int rest = (int)(i >> 5);
        int co = rest % 192; rest /= 192;
        int kc = rest % 7;   int t = rest / 7;
        int ci = kc*32 + q;
        float v = (ci < 194) ? ldin(cw1, (size_t)co*194*9 + (size_t)ci*9 + t, isf) : 0.f;
        wA1[i] = f2b(v);
    }
    // conv2: [96][192][9] -> wA2[t<9][kc<6][co<96][32]
    if (i < 9*6*96*32) {
        int q = (int)(i & 31);
        int rest = (int)(i >> 5);
        int co = rest % 96; rest /= 96;
        int kc = rest % 6;  int t = rest / 6;
        int ci = kc*32 + q;
        wA2[i] = f2b(ldin(cw2, (size_t)co*192*9 + (size_t)ci*9 + t, isf));
    }
    // conv3: [216][96][9] -> wA3[t<9][kc<3][co<224][32], co>=216 zero
    if (i < 9*3*224*32) {
        int q = (int)(i & 31);
        int rest = (int)(i >> 5);
        int co = rest % 224; rest /= 224;
        int kc = rest % 3;   int t = rest / 3;
        int ci = kc*32 + q;
        float v = (co < 216) ? ldin(cw3, (size_t)co*96*9 + (size_t)ci*9 + t, isf) : 0.f;
        wA3[i] = f2b(v);
    }
    // mlp1: [192][96] -> wAm1[kc<3][co<192][32]
    if (i < 3*192*32) {
        int q = (int)(i & 31);
        int rest = (int)(i >> 5);
        int co = rest % 192;
        int kc = rest / 192;
        wAm1[i] = f2b(ldin(wm1, (size_t)co*96 + kc*32 + q, isf));
    }
    // mlp2: [96][192] -> wAm2[kc<6][co<96][32]
    if (i < 6*96*32) {
        int q = (int)(i & 31);
        int rest = (int)(i >> 5);
        int co = rest % 96;
        int kc = rest / 96;
        wAm2[i] = f2b(ldin(wm2, (size_t)co*192 + kc*32 + q, isf));
    }
    // wq / wo: [96][96] -> A-layout [kc<3][co<96][32]
    if (i < 3*96*32) {
        int q = (int)(i & 31);
        int rest = (int)(i >> 5);
        int co = rest % 96;
        int kc = rest / 96;
        wAq[i] = f2b(ldin(wq, (size_t)co*96 + kc*32 + q, isf));
        wAo[i] = f2b(ldin(wo, (size_t)co*96 + kc*32 + q, isf));
    }
    // wk/wv fused A-layout: wAkv[kc<3][co<192][32]; co<96 -> wk[co], co>=96 -> wv[co-96]
    if (i < 3*192*32) {
        int q = (int)(i & 31);
        int rest = (int)(i >> 5);
        int co = rest % 192;
        int kc = rest / 192;
        int ci = kc*32 + q;
        float v = (co < 96) ? ldin(wk, (size_t)co*96 + ci, isf)
                            : ldin(wv, (size_t)(co-96)*96 + ci, isf);
        wAkv[i] = f2b(v);
    }
    if (i < 192) biasf[i]       = ldin(cb1, i, isf);
    if (i < 192) biasf[192+i]   = ldin(a1, i, isf);
    if (i < 96)  biasf[384+i]   = ldin(cb2, i, isf);
    if (i < 96)  biasf[480+i]   = ldin(a2, i, isf);
    if (i < 216) biasf[576+i]   = ldin(cb3, i, isf);
    if (i < 96) {
        biasf[792+i]  = ldin(bq, i, isf);
        biasf[888+i]  = ldin(bk, i, isf);
        biasf[984+i]  = ldin(bv, i, isf);
        biasf[1080+i] = ldin(bo, i, isf);
        biasf[1368+i] = ldin(bm2, i, isf);
    }
    if (i < 192) biasf[1176+i] = ldin(bm1, i, isf);
}

// ---------------------------------------------------------------------------
// cat[gp][224] bf16 pixel-major: ci 0..95 feat_t, 96..191 warped kv, 192/193 flow, rest 0
// ---------------------------------------------------------------------------
__global__ void build_cat(const float* __restrict__ ftf, const bf16* __restrict__ fkvclb,
                          const float* __restrict__ flowf, bf16* __restrict__ cat)
{
    size_t idx = (size_t)blockIdx.x * 256 + threadIdx.x;
    if (idx >= (size_t)Bv*Pv*224) return;
    int ch = (int)(idx % 224);
    int gp = (int)(idx / 224);
    int p  = gp & (Pv-1);
    int bb = gp >> 14;
    float v = 0.f;
    if (ch < 96) {
        v = ftf[((size_t)bb*Cv + ch)*Pv + p];
    } else if (ch < 192) {
        int cc = ch - 96;
        int py = p >> 7, px = p & (Wv-1);
        float xs = (float)px + flowf[((size_t)bb*2 + 0)*Pv + p];
        float ys = (float)py + flowf[((size_t)bb*2 + 1)*Pv + p];
        float x0f = floorf(xs), y0f = floorf(ys);
        float wx = xs - x0f, wy = ys - y0f;
        int x0 = (int)x0f, y0 = (int)y0f;
        #pragma unroll
        for (int tt = 0; tt < 4; tt++) {
            int xi = x0 + (tt & 1), yi = y0 + (tt >> 1);
            float wt = ((tt & 1) ? wx : 1.f - wx) * ((tt >> 1) ? wy : 1.f - wy);
            if (xi >= 0 && xi < Wv && yi >= 0 && yi < Hv)
                v += wt * b2f(fkvclb[((size_t)bb*Pv + yi*Wv + xi)*96 + cc]);
        }
    } else if (ch < 194) {
        v = flowf[((size_t)bb*2 + (ch-192))*Pv + p];
    }
    cat[idx] = f2b(v);
}

// ---------------------------------------------------------------------------
// MFMA implicit-GEMM conv/1x1. 1-D grid of 128*GY*Bv blocks, XCD-aware decode:
// bid&7 = XCD owns 16 consecutive rows for all (co,b) -> halos hit L2.
// Software pipeline: chunk kc+1 prefetched to VGPRs while MFMAs run on kc.
// MODE 0: PReLU -> bf16 px-major    MODE 1: plain -> bf16 px-major (guard co<216)
// MODE 2: GELU  -> bf16 px-major    MODE 3: +bias +resid(f32 ch-major) -> d_out
// MODE 4: +bias +resid(f32 ch-major) -> outp f32 ch-major AND out2 bf16 px-major
// ---------------------------------------------------------------------------
template<int CSTR, int CIN_PAD, int COTOT, int COF, int TAPS, int MODE, int OCS, int GY>
__launch_bounds__(256)
__global__ void conv_mfma(const bf16* __restrict__ in, const bf16* __restrict__ wA,
                          const float* __restrict__ bias, const float* __restrict__ alpha,
                          const float* __restrict__ resid, const int* __restrict__ flag,
                          void* __restrict__ outp, void* __restrict__ out2)
{
    constexpr int NC = CIN_PAD / 32;
    constexpr int LDS_PX = (TAPS == 9) ? 3*130 : 128;
    constexpr int NITEMS = LDS_PX * 4;
    constexpr int NSTG = (NITEMS + 255) / 256;
    __shared__ short sbuf[LDS_PX * 40];

    int tid = threadIdx.x;
    int wave = tid >> 6, lane = tid & 63;
    int n = lane & 15, kq = lane >> 4;

    int bid = blockIdx.x;
    int xcd = bid & 7, idx = bid >> 3;
    int y   = xcd * 16 + (idx & 15);
    int cob = ((idx >> 4) % GY) * (COF*16);
    int bb  = idx / (16*GY);

    uint4 pre[NSTG];
    auto ldst = [&](int kc) {
        #pragma unroll
        for (int s = 0; s < NSTG; s++) {
            int i = s*256 + tid;
            int ii = (i < NITEMS) ? i : (NITEMS-1);
            int part = ii & 3; int pxr = ii >> 2;
            const bf16* ap;
            if (TAPS == 9) {
                int r = pxr / 130; int px = pxr - r*130;
                int yy = y + r - 1, xx = px - 1;
                int yc = min(max(yy, 0), Hv-1), xc = min(max(xx, 0), Wv-1);
                ap = in + ((size_t)(bb*Pv + yc*Wv + xc)*CSTR + kc*32 + part*8);
            } else {
                ap = in + ((size_t)(bb*Pv + y*Wv + pxr)*CSTR + kc*32 + part*8);
            }
            pre[s] = *(const uint4*)ap;
        }
    };
    auto wrst = [&]() {
        #pragma unroll
        for (int s = 0; s < NSTG; s++) {
            int i = s*256 + tid;
            if (i < NITEMS) {
                int part = i & 3; int pxr = i >> 2;
                uint4 val = pre[s];
                if (TAPS == 9) {
                    int r = pxr / 130; int px = pxr - r*130;
                    int yy = y + r - 1, xx = px - 1;
                    if (!(yy >= 0 && yy < Hv && xx >= 0 && xx < Wv)) val = (uint4){0u,0u,0u,0u};
                    *(uint4*)&sbuf[(r*130 + px)*40 + part*8] = val;
                } else {
                    *(uint4*)&sbuf[pxr*40 + part*8] = val;
                }
            }
        }
    };

    fx4 acc[COF][2];
    #pragma unroll
    for (int f = 0; f < COF; f++)
        #pragma unroll
        for (int j = 0; j < 2; j++)
            acc[f][j] = (fx4){0.f, 0.f, 0.f, 0.f};

    ldst(0);
    for (int kc = 0; kc < NC; kc++) {
        wrst();
        __syncthreads();
        if (kc + 1 < NC) ldst(kc + 1);   // prefetch overlaps MFMA below
        #pragma unroll
        for (int t = 0; t < TAPS; t++) {
            const bf16* wbase = wA + ((size_t)(t*NC + kc)*COTOT + cob + n)*32 + kq*8;
            s16x8 af[COF];
            #pragma unroll
            for (int f = 0; f < COF; f++)
                af[f] = *(const s16x8*)(wbase + (size_t)f*16*32);
            #pragma unroll
            for (int j = 0; j < 2; j++) {
                int pxs;
                if (TAPS == 9) {
                    int r = t / 3, dx = t % 3;
                    pxs = r*130 + wave*32 + j*16 + n + dx;
                } else {
                    pxs = wave*32 + j*16 + n;
                }
                s16x8 bfr = *(const s16x8*)&sbuf[pxs*40 + kq*8];
                #pragma unroll
                for (int f = 0; f < COF; f++)
                    acc[f][j] = __builtin_amdgcn_mfma_f32_16x16x32_bf16(af[f], bfr, acc[f][j], 0, 0, 0);
            }
        }
        __syncthreads();   // WAR: all reads done before next wrst
    }

    // epilogue: D col=lane&15 (pixel), row=(lane>>4)*4+reg (co)
    int pxbase = wave*32;
    #pragma unroll
    for (int f = 0; f < COF; f++) {
        int co0 = cob + f*16 + kq*4;
        if (MODE == 1 && co0 >= 216) continue;
        #pragma unroll
        for (int j = 0; j < 2; j++) {
            int px = pxbase + j*16 + n;
            size_t gp = (size_t)bb*Pv + (size_t)y*Wv + px;
            fx4 fr = acc[f][j];
            if (MODE == 3) {
                int isf = flag[0];
                #pragma unroll
                for (int rg = 0; rg < 4; rg++) {
                    int co = co0 + rg;
                    size_t oi = ((size_t)bb*COTOT + co)*Pv + (size_t)y*Wv + px;
                    float v = fr[rg] + bias[co] + resid[oi];
                    if (isf) ((float*)outp)[oi] = v;
                    else     ((bf16*)outp)[oi] = f2b(v);
                }
            } else if (MODE == 4) {
                s16x4 st;
                #pragma unroll
                for (int rg = 0; rg < 4; rg++) {
                    int co = co0 + rg;
                    size_t oi = ((size_t)bb*COTOT + co)*Pv + (size_t)y*Wv + px;
                    float v = fr[rg] + bias[co] + resid[oi];
                    ((float*)outp)[oi] = v;
                    bf16 bvv = f2b(v);
                    st[rg] = *(short*)&bvv;
                }
                *(s16x4*)((bf16*)out2 + gp*OCS + co0) = st;
            } else {
                s16x4 st;
                #pragma unroll
                for (int rg = 0; rg < 4; rg++) {
                    float v = fr[rg] + bias[co0 + rg];
                    if (MODE == 0) { float a = alpha[co0 + rg]; v = (v >= 0.f) ? v : a*v; }
                    if (MODE == 2) {
                        float t2 = __expf(1.5957691216057308f*(v + 0.044715f*v*v*v));
                        v = v * t2 / (t2 + 1.f);   // fast tanh-GELU
                    }
                    bf16 bvv = f2b(v);
                    st[rg] = *(short*)&bvv;
                }
                *(s16x4*)((bf16*)outp + gp*OCS + co0) = st;
            }
        }
    }
}

// ---------------------------------------------------------------------------
// Fused deformable attention: sample -> kv MFMA GEMM -> softmax -> o.
// Block 256 = 4 waves, 7 pixels = 63 points (+1 pad) per block.
// ---------------------------------------------------------------------------
__launch_bounds__(256)
__global__ void dka_kernel(const float* __restrict__ flowf, const bf16* __restrict__ fkvclb,
    const bf16* __restrict__ off3, const bf16* __restrict__ q_bf,
    const bf16* __restrict__ wAkv, const float* __restrict__ bkf, const float* __restrict__ bvf,
    bf16* __restrict__ o_bf)
{
    __shared__ short s_s[NPT*104];      // sampled values, [pt][c], stride 104
    __shared__ short kv_s[NPT*200];     // k (co 0..95) || v (96..191), [pt][co]

    int tid = threadIdx.x;
    int pb0 = blockIdx.x * PPB;

    // --- phase 1: sample 8 channels per item = (point, deform-group) ---
    #pragma unroll
    for (int r = 0; r < 3; r++) {
        int it = r*256 + tid;           // 768 items = 64 pts x 12 groups
        int pt = it / 12, g = it - (it/12)*12;
        int pxl = pt / 9, k = pt - pxl*9;
        int gp0 = pb0 + pxl;
        bool act = (pt < 63) && (gp0 < NPIX);
        int gp = act ? gp0 : (NPIX-1);
        int bb = gp >> 14, p = gp & (Pv-1);
        int py = p >> 7, px = p & (Wv-1);
        float fx = flowf[((size_t)bb*2 + 0)*Pv + p];
        float fy = flowf[((size_t)bb*2 + 1)*Pv + p];
        float dy = b2f(off3[(size_t)gp*216 + (g*9 + k)*2    ]) + fy;
        float dx = b2f(off3[(size_t)gp*216 + (g*9 + k)*2 + 1]) + fx;
        float sx = (float)(px + (k % 3) - 1) + dx;
        float sy = (float)(py + (k / 3) - 1) + dy;
        float x0f = floorf(sx), y0f = floorf(sy);
        float wx = sx - x0f, wy = sy - y0f;
        int x0 = (int)x0f, y0 = (int)y0f;
        const bf16* base = fkvclb + ((size_t)bb*Pv)*96 + g*8;

        float w[4]; uint4 t4[4];
        #pragma unroll
        for (int t = 0; t < 4; t++) {
            int xi = x0 + (t & 1), yi = y0 + (t >> 1);
            float wt = ((t & 1) ? wx : 1.f - wx) * ((t >> 1) ? wy : 1.f - wy);
            bool vld = (xi >= 0) & (xi < Wv) & (yi >= 0) & (yi < Hv);
            int xc = min(max(xi, 0), Wv-1), yc = min(max(yi, 0), Hv-1);
            w[t] = (act && vld) ? wt : 0.f;
            t4[t] = *(const uint4*)(base + (size_t)(yc*Wv + xc)*96);
        }
        float v[8];
        #pragma unroll
        for (int j = 0; j < 8; j++) v[j] = 0.f;
        #pragma unroll
        for (int t = 0; t < 4; t++) {
            const bf16* pp = (const bf16*)&t4[t];
            #pragma unroll
            for (int j = 0; j < 8; j++) v[j] += w[t] * b2f(pp[j]);
        }
        s16x8 st;
        #pragma unroll
        for (int j = 0; j < 8; j++) { bf16 bv = f2b(v[j]); st[j] = *(short*)&bv; }
        *(s16x8*)&s_s[pt*104 + g*8] = st;
    }
    __syncthreads();

    // --- phase 2: kv = wAkv @ s  (M=192 split over waves, N=64, K=96) ---
    {
        int wave = tid >> 6, lane = tid & 63;
        int n = lane & 15, kq = lane >> 4;
        fx4 acc[3][4];
        #pragma unroll
        for (int mi = 0; mi < 3; mi++)
            #pragma unroll
            for (int nf = 0; nf < 4; nf++)
                acc[mi][nf] = (fx4){0.f, 0.f, 0.f, 0.f};
        #pragma unroll
        for (int kc = 0; kc < 3; kc++) {
            s16x8 b[4];
            #pragma unroll
            for (int nf = 0; nf < 4; nf++)
                b[nf] = *(const s16x8*)&s_s[(nf*16 + n)*104 + kc*32 + kq*8];
            #pragma unroll
            for (int mi = 0; mi < 3; mi++) {
                s16x8 a = *(const s16x8*)(wAkv + ((size_t)(kc*192 + (wave*3 + mi)*16 + n))*32 + kq*8);
                #pragma unroll
                for (int nf = 0; nf < 4; nf++)
                    acc[mi][nf] = __builtin_amdgcn_mfma_f32_16x16x32_bf16(a, b[nf], acc[mi][nf], 0, 0, 0);
            }
        }
        // phase 3: stage kv to LDS. D: col=point(lane&15), row=co((lane>>4)*4+rg)
        #pragma unroll
        for (int mi = 0; mi < 3; mi++)
            #pragma unroll
            for (int nf = 0; nf < 4; nf++) {
                s16x4 st;
                #pragma unroll
                for (int rg = 0; rg < 4; rg++) {
                    bf16 bv = f2b(acc[mi][nf][rg]);
                    st[rg] = *(short*)&bv;
                }
                *(s16x4*)&kv_s[(size_t)(nf*16 + n)*200 + (wave*3 + mi)*16 + kq*4] = st;
            }
    }
    __syncthreads();

    // --- phase 4: logits, softmax over 9 points, weighted v-sum, write o ---
    #pragma unroll
    for (int r = 0; r < 3; r++) {
        int idx = r*256 + tid;
        int pxl = idx / 96, c = idx - (idx/96)*96;
        int gp = pb0 + pxl;
        bool act = (pxl < PPB) && (gp < NPIX);   // uniform per 8-lane group
        float q = 0.f, bkc = 0.f, bvc = 0.f;
        if (act) { q = b2f(q_bf[(size_t)gp*96 + c]); bkc = bkf[c]; bvc = bvf[c]; }
        float lg[9];
        #pragma unroll
        for (int k = 0; k < 9; k++) {
            float kk = 0.f;
            if (act) kk = b2f(*(bf16*)&kv_s[(pxl*9 + k)*200 + c]) + bkc;
            float pr = q * kk;
            pr += __shfl_xor(pr, 1);
            pr += __shfl_xor(pr, 2);
            pr += __shfl_xor(pr, 4);
            lg[k] = pr * 0.35355339059327373f;   // 1/sqrt(8)
        }
        float m = lg[0];
        #pragma unroll
        for (int k = 1; k < 9; k++) m = fmaxf(m, lg[k]);
        float sum = 0.f;
        #pragma unroll
        for (int k = 0; k < 9; k++) { lg[k] = __expf(lg[k] - m); sum += lg[k]; }
        float inv = 1.f / sum;
        float ov = 0.f;
        #pragma unroll
        for (int k = 0; k < 9; k++) {
            float vv = 0.f;
            if (act) vv = b2f(*(bf16*)&kv_s[(pxl*9 + k)*200 + 96 + c]) + bvc;
            ov += (lg[k] * inv) * vv;
        }
        if (act) o_bf[(size_t)gp*96 + c] = f2b(ov);
    }
}

// ---------------------------------------------------------------------------
extern "C" void kernel_launch(void* const* d_in, const int* in_sizes, int n_in,
                              void* d_out, int out_size, void* d_ws, size_t ws_size,
                              hipStream_t stream) {
    (void)in_sizes; (void)n_in; (void)out_size; (void)ws_size;

    char* w = (char*)d_ws;
    float* ftf    = (float*)(w + 0);             // 12,582,912
    bf16*  fkvclb = (bf16*) (w + 12582912);      //  6,291,456
    float* flowf  = (float*)(w + 18874368);      //    262,144
    bf16*  wAkv   = (bf16*) (w + 19136512);      //     36,864
    bf16*  wAq    = (bf16*) (w + 19173376);      //     18,432
    bf16*  wAo    = (bf16*) (w + 19191808);      //     18,432
    bf16*  wA1    = (bf16*) (w + 19210240);      //    774,144
    bf16*  wA2    = (bf16*) (w + 19984384);      //    331,776
    bf16*  wA3    = (bf16*) (w + 20316160);      //    387,072
    bf16*  wAm1   = (bf16*) (w + 20703232);      //     36,864
    bf16*  wAm2   = (bf16*) (w + 20740096);      //     36,864
    float* biasf  = (float*)(w + 20776960);      //      8,192
    int*   flag   = (int*)  (w + 20785152);      //        256
    // region A (14,680,064): cat[gp][224] (build->conv1,q_gemm) then xbuf f32 (o_gemm->mlp2)
    char*  regA   = w + 20785408;
    // region B (14,155,776): r1b (conv1->conv2) / off3 (conv3->dka) / hb (mlp1->mlp2)
    char*  regB   = w + 35465472;
    // region C (6,291,456): r2b (conv2->conv3) / q_bf (q_gemm->dka) / xb_bf (o_gemm->mlp1)
    char*  regC   = w + 49621248;
    // region D (6,291,456): o_bf (dka->o_gemm)
    char*  regD   = w + 55912704;
    // total 62,204,160 bytes

    bf16*  cat   = (bf16*) regA;
    float* xbuf  = (float*)regA;
    bf16*  r1b   = (bf16*) regB;
    bf16*  off3  = (bf16*) regB;
    bf16*  hb    = (bf16*) regB;
    bf16*  r2b   = (bf16*) regC;
    bf16*  q_bf  = (bf16*) regC;
    bf16*  xb_bf = (bf16*) regC;
    bf16*  o_bf  = (bf16*) regD;

    detect_dtype<<<1, 256, 0, stream>>>((const unsigned short*)d_in[0], flag);

    prep_all<<<12288, 256, 0, stream>>>(flag,
        d_in[0], d_in[1], d_in[2],
        d_in[3], d_in[4], d_in[5], d_in[6], d_in[7], d_in[8], d_in[9], d_in[10],
        d_in[11], d_in[12], d_in[13], d_in[14], d_in[15], d_in[16], d_in[17], d_in[18],
        d_in[19], d_in[20], d_in[21], d_in[22],
        ftf, fkvclb, flowf, wAq, wAo, wAkv, wA1, wA2, wA3, wAm1, wAm2, biasf);

    build_cat<<<((size_t)Bv*Pv*224 + 255)/256, 256, 0, stream>>>(ftf, fkvclb, flowf, cat);

    // conv1: GY=4, COF=3 -> 1024 blocks (4/CU)
    conv_mfma<224, 224, 192, 3, 9, 0, 192, 4><<<1024, 256, 0, stream>>>(
        cat, wA1, biasf + 0,   biasf + 192, nullptr, flag, r1b, nullptr);
    // conv2: GY=3, COF=2 -> 768 blocks (3/CU)
    conv_mfma<192, 192,  96, 2, 9, 0,  96, 3><<<768, 256, 0, stream>>>(
        r1b, wA2, biasf + 384, biasf + 480, nullptr, flag, r2b, nullptr);
    // conv3: GY=2, COF=7 -> 512 blocks
    conv_mfma< 96,  96, 224, 7, 9, 1, 216, 2><<<512, 256, 0, stream>>>(
        r2b, wA3, biasf + 576, nullptr,     nullptr, flag, off3, nullptr);

    // q = Wq @ feat_t + bq  (reads feat_t channels from cat, stride 224)
    conv_mfma<224,  96,  96, 2, 1, 1,  96, 3><<<768, 256, 0, stream>>>(
        cat, wAq, biasf + 792, nullptr,     nullptr, flag, q_bf, nullptr);

    // fused deformable attention (sample + kv GEMM + softmax + o)
    dka_kernel<<<(NPIX + PPB - 1)/PPB, 256, 0, stream>>>(
        flowf, fkvclb, off3, q_bf, wAkv, biasf + 888, biasf + 984, o_bf);

    // x = feat_t + Wo @ o + bo  -> xbuf (f32 ch-major) + xb_bf (bf16 px-major)
    conv_mfma< 96,  96,  96, 2, 1, 4,  96, 3><<<768, 256, 0, stream>>>(
        o_bf, wAo, biasf + 1080, nullptr,   ftf,    flag, xbuf, xb_bf);

    conv_mfma< 96,  96, 192, 3, 1, 2, 192, 4><<<1024, 256, 0, stream>>>(
        xb_bf, wAm1, biasf + 1176, nullptr, nullptr, flag, hb, nullptr);
    conv_mfma<192, 192,  96, 2, 1, 3,  96, 3><<<768, 256, 0, stream>>>(
        hb,   wAm2, biasf + 1368, nullptr,  xbuf,   flag, d_out, nullptr);
}

// Round 8
// 375.422 us; speedup vs baseline: 5.3893x; 1.0292x over previous
//
#include <hip/hip_runtime.h>
#include <hip/hip_bf16.h>
#include <math.h>

typedef __hip_bfloat16 bf16;
typedef __attribute__((ext_vector_type(8))) short s16x8;
typedef __attribute__((ext_vector_type(4))) short s16x4;
typedef __attribute__((ext_vector_type(4))) float fx4;

#define Bv 2
#define Cv 96
#define Hv 128
#define Wv 128
#define Pv (Hv*Wv)          /* 16384 */
#define NPIX (Bv*Pv)        /* 32768 */
#define Gv 12
#define Kv 9
#define PPB 7               /* pixels per dka block */
#define NPT 64              /* 63 points + 1 pad    */

__device__ __forceinline__ float b2f(bf16 x) { return __bfloat162float(x); }
__device__ __forceinline__ bf16 f2b(float x) { return __float2bfloat16(x); }

// dual-dtype input load: isf=1 -> float32, isf=0 -> bf16
__device__ __forceinline__ float ldin(const void* p, size_t i, int isf) {
    return isf ? ((const float*)p)[i] : __bfloat162float(((const bf16*)p)[i]);
}

// ---------------------------------------------------------------------------
// dtype detection (f32 read as bf16 shows NaN/Inf bit patterns in low halves)
// ---------------------------------------------------------------------------
__global__ void detect_dtype(const unsigned short* __restrict__ x, int* __restrict__ flag)
{
    __shared__ int bad;
    if (threadIdx.x == 0) bad = 0;
    __syncthreads();
    int cnt = 0;
    for (int i = threadIdx.x; i < 32768; i += 256) {
        unsigned short u = x[i];
        if ((u & 0x7F80) == 0x7F80) cnt++;
    }
    atomicAdd(&bad, cnt);
    __syncthreads();
    if (threadIdx.x == 0) flag[0] = (bad > 0) ? 1 : 0;   // 1 = float32 inputs
}

// ---------------------------------------------------------------------------
// prep: convert inputs; build MFMA A-layout weight buffers (bf16).
// wA layout: [(t*NC + kc)*COTOT + co]*32 + kq*8 + j,  k-in-chunk = kq*8+j
// fkvclb: coalesced READ of fkv, scattered write (L2 merges partial lines).
// ---------------------------------------------------------------------------
__global__ void prep_all(const int* __restrict__ flag,
    const void* ft, const void* fkv, const void* flow,
    const void* cw1, const void* cb1, const void* a1,
    const void* cw2, const void* cb2, const void* a2,
    const void* cw3, const void* cb3,
    const void* wq, const void* bq, const void* wk, const void* bk,
    const void* wv, const void* bv, const void* wo, const void* bo,
    const void* wm1, const void* bm1, const void* wm2, const void* bm2,
    float* __restrict__ ftf, bf16* __restrict__ fkvclb, float* __restrict__ flowf,
    bf16* __restrict__ wAq, bf16* __restrict__ wAo, bf16* __restrict__ wAkv,
    bf16* __restrict__ wA1, bf16* __restrict__ wA2, bf16* __restrict__ wA3,
    bf16* __restrict__ wAm1, bf16* __restrict__ wAm2,
    float* __restrict__ biasf)
{
    int isf = flag[0];
    size_t i = (size_t)blockIdx.x * 256 + threadIdx.x;
    if (i < (size_t)Bv*Cv*Pv) {
        ftf[i] = ldin(ft, i, isf);
        int b = (i >= (size_t)Cv*Pv) ? 1 : 0;
        int rem = (int)(i - (size_t)b*Cv*Pv);
        int c = rem >> 14;            // rem / Pv
        int p = rem & (Pv-1);
        fkvclb[((size_t)(b*Pv + p))*96 + c] = f2b(ldin(fkv, i, isf));
    }
    if (i < (size_t)Bv*2*Pv) flowf[i] = ldin(flow, i, isf);

    // conv1 weights: [192][194][9] -> wA1[t<9][kc<7][co<192][32]
    if (i < 9*7*192*32) {
        int q = (int)(i & 31);
        int rest = (int)(i >> 5);
        int co = rest % 192; rest /= 192;
        int kc = rest % 7;   int t = rest / 7;
        int ci = kc*32 + q;
        float v = (ci < 194) ? ldin(cw1, (size_t)co*194*9 + (size_t)ci*9 + t, isf) : 0.f;
        wA1[i] = f2b(v);
    }
    // conv2: [96][192][9] -> wA2[t<9][kc<6][co<96][32]
    if (i < 9*6*96*32) {
        int q = (int)(i & 31);
        int rest = (int)(i >> 5);
        int co = rest % 96; rest /= 96;
        int kc = rest % 6;  int t = rest / 6;
        int ci = kc*32 + q;
        wA2[i] = f2b(ldin(cw2, (size_t)co*192*9 + (size_t)ci*9 + t, isf));
    }
    // conv3: [216][96][9] -> wA3[t<9][kc<3][co<256][32], co>=216 zero
    if (i < 9*3*256*32) {
        int q = (int)(i & 31);
        int rest = (int)(i >> 5);
        int co = rest % 256; rest /= 256;
        int kc = rest % 3;   int t = rest / 3;
        int ci = kc*32 + q;
        float v = (co < 216) ? ldin(cw3, (size_t)co*96*9 + (size_t)ci*9 + t, isf) : 0.f;
        wA3[i] = f2b(v);
    }
    // mlp1: [192][96] -> wAm1[kc<3][co<192][32]
    if (i < 3*192*32) {
        int q = (int)(i & 31);
        int rest = (int)(i >> 5);
        int co = rest % 192;
        int kc = rest / 192;
        wAm1[i] = f2b(ldin(wm1, (size_t)co*96 + kc*32 + q, isf));
    }
    // mlp2: [96][192] -> wAm2[kc<6][co<96][32]
    if (i < 6*96*32) {
        int q = (int)(i & 31);
        int rest = (int)(i >> 5);
        int co = rest % 96;
        int kc = rest / 96;
        wAm2[i] = f2b(ldin(wm2, (size_t)co*192 + kc*32 + q, isf));
    }
    // wq / wo: [96][96] -> A-layout [kc<3][co<96][32]
    if (i < 3*96*32) {
        int q = (int)(i & 31);
        int rest = (int)(i >> 5);
        int co = rest % 96;
        int kc = rest / 96;
        wAq[i] = f2b(ldin(wq, (size_t)co*96 + kc*32 + q, isf));
        wAo[i] = f2b(ldin(wo, (size_t)co*96 + kc*32 + q, isf));
    }
    // wk/wv fused A-layout: wAkv[kc<3][co<192][32]; co<96 -> wk[co], co>=96 -> wv[co-96]
    if (i < 3*192*32) {
        int q = (int)(i & 31);
        int rest = (int)(i >> 5);
        int co = rest % 192;
        int kc = rest / 192;
        int ci = kc*32 + q;
        float v = (co < 96) ? ldin(wk, (size_t)co*96 + ci, isf)
                            : ldin(wv, (size_t)(co-96)*96 + ci, isf);
        wAkv[i] = f2b(v);
    }
    if (i < 192) biasf[i]       = ldin(cb1, i, isf);
    if (i < 192) biasf[192+i]   = ldin(a1, i, isf);
    if (i < 96)  biasf[384+i]   = ldin(cb2, i, isf);
    if (i < 96)  biasf[480+i]   = ldin(a2, i, isf);
    if (i < 216) biasf[576+i]   = ldin(cb3, i, isf);
    if (i < 96) {
        biasf[792+i]  = ldin(bq, i, isf);
        biasf[888+i]  = ldin(bk, i, isf);
        biasf[984+i]  = ldin(bv, i, isf);
        biasf[1080+i] = ldin(bo, i, isf);
        biasf[1368+i] = ldin(bm2, i, isf);
    }
    if (i < 192) biasf[1176+i] = ldin(bm1, i, isf);
}

// ---------------------------------------------------------------------------
// cat[gp][224] bf16 px-major. item = (pixel, 8-ch group): grp<12 = feat_t copy,
// 12..23 = flow-warped kv (4 x uint4 vectorized gather), 24 = flow+pad, 25..27 = 0.
// ---------------------------------------------------------------------------
__global__ void build_cat(const float* __restrict__ ftf, const bf16* __restrict__ fkvclb,
                          const float* __restrict__ flowf, bf16* __restrict__ cat)
{
    int idx = blockIdx.x * 256 + threadIdx.x;
    if (idx >= NPIX*28) return;
    int grp = idx % 28;
    int gp  = idx / 28;
    int p   = gp & (Pv-1);
    int bb  = gp >> 14;
    s16x8 st;
    if (grp < 12) {
        #pragma unroll
        for (int j = 0; j < 8; j++) {
            bf16 bv = f2b(ftf[((size_t)bb*Cv + grp*8 + j)*Pv + p]);
            st[j] = *(short*)&bv;
        }
    } else if (grp < 24) {
        int g = grp - 12;
        int py = p >> 7, px = p & (Wv-1);
        float xs = (float)px + flowf[((size_t)bb*2 + 0)*Pv + p];
        float ys = (float)py + flowf[((size_t)bb*2 + 1)*Pv + p];
        float x0f = floorf(xs), y0f = floorf(ys);
        float wx = xs - x0f, wy = ys - y0f;
        int x0 = (int)x0f, y0 = (int)y0f;
        const bf16* base = fkvclb + ((size_t)bb*Pv)*96 + g*8;
        float w[4]; uint4 t4[4];
        #pragma unroll
        for (int t = 0; t < 4; t++) {
            int xi = x0 + (t & 1), yi = y0 + (t >> 1);
            float wt = ((t & 1) ? wx : 1.f - wx) * ((t >> 1) ? wy : 1.f - wy);
            bool vld = (xi >= 0) & (xi < Wv) & (yi >= 0) & (yi < Hv);
            int xc = min(max(xi, 0), Wv-1), yc = min(max(yi, 0), Hv-1);
            w[t] = vld ? wt : 0.f;
            t4[t] = *(const uint4*)(base + (size_t)(yc*Wv + xc)*96);
        }
        float v[8];
        #pragma unroll
        for (int j = 0; j < 8; j++) v[j] = 0.f;
        #pragma unroll
        for (int t = 0; t < 4; t++) {
            const bf16* pp = (const bf16*)&t4[t];
            #pragma unroll
            for (int j = 0; j < 8; j++) v[j] += w[t] * b2f(pp[j]);
        }
        #pragma unroll
        for (int j = 0; j < 8; j++) { bf16 bv = f2b(v[j]); st[j] = *(short*)&bv; }
    } else if (grp == 24) {
        float fx = flowf[((size_t)bb*2 + 0)*Pv + p];
        float fy = flowf[((size_t)bb*2 + 1)*Pv + p];
        bf16 b0 = f2b(fx), b1 = f2b(fy);
        st[0] = *(short*)&b0; st[1] = *(short*)&b1;
        #pragma unroll
        for (int j = 2; j < 8; j++) st[j] = 0;
    } else {
        #pragma unroll
        for (int j = 0; j < 8; j++) st[j] = 0;
    }
    *(s16x8*)(cat + (size_t)gp*224 + grp*8) = st;
}

// ---------------------------------------------------------------------------
// MFMA implicit-GEMM conv/1x1. 1-D grid of 128*GY*Bv blocks, XCD-aware decode.
// Software pipeline: chunk kc+1 prefetched to VGPRs while MFMAs run on kc.
// MODE 0: PReLU -> bf16 px-major    MODE 1: plain -> bf16 px-major (guard co<216)
// MODE 2: GELU  -> bf16 px-major    MODE 3: +bias +resid(f32 ch-major) -> d_out
// MODE 4: +bias +resid(f32 ch-major) -> outp f32 ch-major AND out2 bf16 px-major
// ---------------------------------------------------------------------------
template<int CSTR, int CIN_PAD, int COTOT, int COF, int TAPS, int MODE, int OCS, int GY>
__launch_bounds__(256)
__global__ void conv_mfma(const bf16* __restrict__ in, const bf16* __restrict__ wA,
                          const float* __restrict__ bias, const float* __restrict__ alpha,
                          const float* __restrict__ resid, const int* __restrict__ flag,
                          void* __restrict__ outp, void* __restrict__ out2)
{
    constexpr int NC = CIN_PAD / 32;
    constexpr int LDS_PX = (TAPS == 9) ? 3*130 : 128;
    constexpr int NITEMS = LDS_PX * 4;
    constexpr int NSTG = (NITEMS + 255) / 256;
    __shared__ short sbuf[LDS_PX * 40];

    int tid = threadIdx.x;
    int wave = tid >> 6, lane = tid & 63;
    int n = lane & 15, kq = lane >> 4;

    int bid = blockIdx.x;
    int xcd = bid & 7, idx = bid >> 3;
    int y   = xcd * 16 + (idx & 15);
    int cob = ((idx >> 4) % GY) * (COF*16);
    int bb  = idx / (16*GY);

    uint4 pre[NSTG];
    auto ldst = [&](int kc) {
        #pragma unroll
        for (int s = 0; s < NSTG; s++) {
            int i = s*256 + tid;
            int ii = (i < NITEMS) ? i : (NITEMS-1);
            int part = ii & 3; int pxr = ii >> 2;
            const bf16* ap;
            if (TAPS == 9) {
                int r = pxr / 130; int px = pxr - r*130;
                int yy = y + r - 1, xx = px - 1;
                int yc = min(max(yy, 0), Hv-1), xc = min(max(xx, 0), Wv-1);
                ap = in + ((size_t)(bb*Pv + yc*Wv + xc)*CSTR + kc*32 + part*8);
            } else {
                ap = in + ((size_t)(bb*Pv + y*Wv + pxr)*CSTR + kc*32 + part*8);
            }
            pre[s] = *(const uint4*)ap;
        }
    };
    auto wrst = [&]() {
        #pragma unroll
        for (int s = 0; s < NSTG; s++) {
            int i = s*256 + tid;
            if (i < NITEMS) {
                int part = i & 3; int pxr = i >> 2;
                uint4 val = pre[s];
                if (TAPS == 9) {
                    int r = pxr / 130; int px = pxr - r*130;
                    int yy = y + r - 1, xx = px - 1;
                    if (!(yy >= 0 && yy < Hv && xx >= 0 && xx < Wv)) val = (uint4){0u,0u,0u,0u};
                    *(uint4*)&sbuf[(r*130 + px)*40 + part*8] = val;
                } else {
                    *(uint4*)&sbuf[pxr*40 + part*8] = val;
                }
            }
        }
    };

    fx4 acc[COF][2];
    #pragma unroll
    for (int f = 0; f < COF; f++)
        #pragma unroll
        for (int j = 0; j < 2; j++)
            acc[f][j] = (fx4){0.f, 0.f, 0.f, 0.f};

    ldst(0);
    for (int kc = 0; kc < NC; kc++) {
        wrst();
        __syncthreads();
        if (kc + 1 < NC) ldst(kc + 1);   // prefetch overlaps MFMA below
        #pragma unroll
        for (int t = 0; t < TAPS; t++) {
            const bf16* wbase = wA + ((size_t)(t*NC + kc)*COTOT + cob + n)*32 + kq*8;
            s16x8 af[COF];
            #pragma unroll
            for (int f = 0; f < COF; f++)
                af[f] = *(const s16x8*)(wbase + (size_t)f*16*32);
            #pragma unroll
            for (int j = 0; j < 2; j++) {
                int pxs;
                if (TAPS == 9) {
                    int r = t / 3, dx = t % 3;
                    pxs = r*130 + wave*32 + j*16 + n + dx;
                } else {
                    pxs = wave*32 + j*16 + n;
                }
                s16x8 bfr = *(const s16x8*)&sbuf[pxs*40 + kq*8];
                #pragma unroll
                for (int f = 0; f < COF; f++)
                    acc[f][j] = __builtin_amdgcn_mfma_f32_16x16x32_bf16(af[f], bfr, acc[f][j], 0, 0, 0);
            }
        }
        __syncthreads();   // WAR: all reads done before next wrst
    }

    // epilogue: D col=lane&15 (pixel), row=(lane>>4)*4+reg (co)
    int pxbase = wave*32;
    #pragma unroll
    for (int f = 0; f < COF; f++) {
        int co0 = cob + f*16 + kq*4;
        if (MODE == 1 && co0 >= 216) continue;
        #pragma unroll
        for (int j = 0; j < 2; j++) {
            int px = pxbase + j*16 + n;
            size_t gp = (size_t)bb*Pv + (size_t)y*Wv + px;
            fx4 fr = acc[f][j];
            if (MODE == 3) {
                int isf = flag[0];
                #pragma unroll
                for (int rg = 0; rg < 4; rg++) {
                    int co = co0 + rg;
                    size_t oi = ((size_t)bb*COTOT + co)*Pv + (size_t)y*Wv + px;
                    float v = fr[rg] + bias[co] + resid[oi];
                    if (isf) ((float*)outp)[oi] = v;
                    else     ((bf16*)outp)[oi] = f2b(v);
                }
            } else if (MODE == 4) {
                s16x4 st;
                #pragma unroll
                for (int rg = 0; rg < 4; rg++) {
                    int co = co0 + rg;
                    size_t oi = ((size_t)bb*COTOT + co)*Pv + (size_t)y*Wv + px;
                    float v = fr[rg] + bias[co] + resid[oi];
                    ((float*)outp)[oi] = v;
                    bf16 bvv = f2b(v);
                    st[rg] = *(short*)&bvv;
                }
                *(s16x4*)((bf16*)out2 + gp*OCS + co0) = st;
            } else {
                s16x4 st;
                #pragma unroll
                for (int rg = 0; rg < 4; rg++) {
                    float v = fr[rg] + bias[co0 + rg];
                    if (MODE == 0) { float a = alpha[co0 + rg]; v = (v >= 0.f) ? v : a*v; }
                    if (MODE == 2) {
                        float t2 = __expf(1.5957691216057308f*(v + 0.044715f*v*v*v));
                        v = v * t2 / (t2 + 1.f);   // fast tanh-GELU
                    }
                    bf16 bvv = f2b(v);
                    st[rg] = *(short*)&bvv;
                }
                *(s16x4*)((bf16*)outp + gp*OCS + co0) = st;
            }
        }
    }
}

// ---------------------------------------------------------------------------
// Fused deformable attention: sample -> kv MFMA GEMM -> softmax -> o.
// Block 256 = 4 waves, 7 pixels = 63 points (+1 pad) per block.
// Phase 1 is a 3-stage pipeline: (A) issue flow/offset loads for all 3 items,
// (B) compute coords + issue all 12 uint4 gathers, (C) accumulate + LDS store.
// ---------------------------------------------------------------------------
__launch_bounds__(256, 4)
__global__ void dka_kernel(const float* __restrict__ flowf, const bf16* __restrict__ fkvclb,
    const bf16* __restrict__ off3, const bf16* __restrict__ q_bf,
    const bf16* __restrict__ wAkv, const float* __restrict__ bkf, const float* __restrict__ bvf,
    bf16* __restrict__ o_bf)
{
    __shared__ short s_s[NPT*104];      // sampled values, [pt][c], stride 104
    __shared__ short kv_s[NPT*200];     // k (co 0..95) || v (96..191), [pt][co]

    int tid = threadIdx.x;
    int pb0 = blockIdx.x * PPB;

    // --- phase 1A: flow + offset loads for all 3 items ---
    float fxv[3], fyv[3]; unsigned owv[3];
    #pragma unroll
    for (int r = 0; r < 3; r++) {
        int it = r*256 + tid;           // 768 items = 64 pts x 12 groups
        int pt = it / 12, g = it - (it/12)*12;
        int pxl = pt / 9, k = pt - pxl*9;
        int gp0 = pb0 + pxl;
        bool act = (pt < 63) && (gp0 < NPIX);
        int gp = act ? gp0 : (NPIX-1);
        int bb = gp >> 14, p = gp & (Pv-1);
        fxv[r] = flowf[((size_t)bb*2 + 0)*Pv + p];
        fyv[r] = flowf[((size_t)bb*2 + 1)*Pv + p];
        owv[r] = *(const unsigned*)(off3 + (size_t)gp*216 + (g*9 + k)*2);  // (dy,dx)
    }
    // --- phase 1B: coords + all 12 gathers in flight ---
    float w[3][4]; uint4 t4[3][4];
    #pragma unroll
    for (int r = 0; r < 3; r++) {
        int it = r*256 + tid;
        int pt = it / 12, g = it - (it/12)*12;
        int pxl = pt / 9, k = pt - pxl*9;
        int gp0 = pb0 + pxl;
        bool act = (pt < 63) && (gp0 < NPIX);
        int gp = act ? gp0 : (NPIX-1);
        int bb = gp >> 14, p = gp & (Pv-1);
        int py = p >> 7, px = p & (Wv-1);
        unsigned ow = owv[r];
        bf16 dyb, dxb;
        unsigned short lo = (unsigned short)(ow & 0xFFFFu), hi = (unsigned short)(ow >> 16);
        dyb = *(bf16*)&lo; dxb = *(bf16*)&hi;
        float dy = b2f(dyb) + fyv[r];
        float dx = b2f(dxb) + fxv[r];
        float sx = (float)(px + (k % 3) - 1) + dx;
        float sy = (float)(py + (k / 3) - 1) + dy;
        float x0f = floorf(sx), y0f = floorf(sy);
        float wx = sx - x0f, wy = sy - y0f;
        int x0 = (int)x0f, y0 = (int)y0f;
        const bf16* base = fkvclb + ((size_t)bb*Pv)*96 + g*8;
        #pragma unroll
        for (int t = 0; t < 4; t++) {
            int xi = x0 + (t & 1), yi = y0 + (t >> 1);
            float wt = ((t & 1) ? wx : 1.f - wx) * ((t >> 1) ? wy : 1.f - wy);
            bool vld = (xi >= 0) & (xi < Wv) & (yi >= 0) & (yi < Hv);
            int xc = min(max(xi, 0), Wv-1), yc = min(max(yi, 0), Hv-1);
            w[r][t] = (act && vld) ? wt : 0.f;
            t4[r][t] = *(const uint4*)(base + (size_t)(yc*Wv + xc)*96);
        }
    }
    // --- phase 1C: accumulate + LDS store ---
    #pragma unroll
    for (int r = 0; r < 3; r++) {
        int it = r*256 + tid;
        int pt = it / 12, g = it - (it/12)*12;
        float v[8];
        #pragma unroll
        for (int j = 0; j < 8; j++) v[j] = 0.f;
        #pragma unroll
        for (int t = 0; t < 4; t++) {
            const bf16* pp = (const bf16*)&t4[r][t];
            #pragma unroll
            for (int j = 0; j < 8; j++) v[j] += w[r][t] * b2f(pp[j]);
        }
        s16x8 st;
        #pragma unroll
        for (int j = 0; j < 8; j++) { bf16 bv = f2b(v[j]); st[j] = *(short*)&bv; }
        *(s16x8*)&s_s[pt*104 + g*8] = st;
    }
    __syncthreads();

    // --- phase 2: kv = wAkv @ s  (M=192 split over waves, N=64, K=96) ---
    {
        int wave = tid >> 6, lane = tid & 63;
        int n = lane & 15, kq = lane >> 4;
        fx4 acc[3][4];
        #pragma unroll
        for (int mi = 0; mi < 3; mi++)
            #pragma unroll
            for (int nf = 0; nf < 4; nf++)
                acc[mi][nf] = (fx4){0.f, 0.f, 0.f, 0.f};
        #pragma unroll
        for (int kc = 0; kc < 3; kc++) {
            s16x8 b[4];
            #pragma unroll
            for (int nf = 0; nf < 4; nf++)
                b[nf] = *(const s16x8*)&s_s[(nf*16 + n)*104 + kc*32 + kq*8];
            #pragma unroll
            for (int mi = 0; mi < 3; mi++) {
                s16x8 a = *(const s16x8*)(wAkv + ((size_t)(kc*192 + (wave*3 + mi)*16 + n))*32 + kq*8);
                #pragma unroll
                for (int nf = 0; nf < 4; nf++)
                    acc[mi][nf] = __builtin_amdgcn_mfma_f32_16x16x32_bf16(a, b[nf], acc[mi][nf], 0, 0, 0);
            }
        }
        // phase 3: stage kv to LDS. D: col=point(lane&15), row=co((lane>>4)*4+rg)
        #pragma unroll
        for (int mi = 0; mi < 3; mi++)
            #pragma unroll
            for (int nf = 0; nf < 4; nf++) {
                s16x4 st;
                #pragma unroll
                for (int rg = 0; rg < 4; rg++) {
                    bf16 bv = f2b(acc[mi][nf][rg]);
                    st[rg] = *(short*)&bv;
                }
                *(s16x4*)&kv_s[(size_t)(nf*16 + n)*200 + (wave*3 + mi)*16 + kq*4] = st;
            }
    }
    __syncthreads();

    // --- phase 4: logits, softmax over 9 points, weighted v-sum, write o ---
    #pragma unroll
    for (int r = 0; r < 3; r++) {
        int idx = r*256 + tid;
        int pxl = idx / 96, c = idx - (idx/96)*96;
        int gp = pb0 + pxl;
        bool act = (pxl < PPB) && (gp < NPIX);   // uniform per 8-lane group
        float q = 0.f, bkc = 0.f, bvc = 0.f;
        if (act) { q = b2f(q_bf[(size_t)gp*96 + c]); bkc = bkf[c]; bvc = bvf[c]; }
        float lg[9];
        #pragma unroll
        for (int k = 0; k < 9; k++) {
            float kk = 0.f;
            if (act) kk = b2f(*(bf16*)&kv_s[(pxl*9 + k)*200 + c]) + bkc;
            float pr = q * kk;
            pr += __shfl_xor(pr, 1);
            pr += __shfl_xor(pr, 2);
            pr += __shfl_xor(pr, 4);
            lg[k] = pr * 0.35355339059327373f;   // 1/sqrt(8)
        }
        float m = lg[0];
        #pragma unroll
        for (int k = 1; k < 9; k++) m = fmaxf(m, lg[k]);
        float sum = 0.f;
        #pragma unroll
        for (int k = 0; k < 9; k++) { lg[k] = __expf(lg[k] - m); sum += lg[k]; }
        float inv = 1.f / sum;
        float ov = 0.f;
        #pragma unroll
        for (int k = 0; k < 9; k++) {
            float vv = 0.f;
            if (act) vv = b2f(*(bf16*)&kv_s[(pxl*9 + k)*200 + 96 + c]) + bvc;
            ov += (lg[k] * inv) * vv;
        }
        if (act) o_bf[(size_t)gp*96 + c] = f2b(ov);
    }
}

// ---------------------------------------------------------------------------
extern "C" void kernel_launch(void* const* d_in, const int* in_sizes, int n_in,
                              void* d_out, int out_size, void* d_ws, size_t ws_size,
                              hipStream_t stream) {
    (void)in_sizes; (void)n_in; (void)out_size; (void)ws_size;

    char* w = (char*)d_ws;
    float* ftf    = (float*)(w + 0);             // 12,582,912
    bf16*  fkvclb = (bf16*) (w + 12582912);      //  6,291,456
    float* flowf  = (float*)(w + 18874368);      //    262,144
    bf16*  wAkv   = (bf16*) (w + 19136512);      //     36,864
    bf16*  wAq    = (bf16*) (w + 19173376);      //     18,432
    bf16*  wAo    = (bf16*) (w + 19191808);      //     18,432
    bf16*  wA1    = (bf16*) (w + 19210240);      //    774,144
    bf16*  wA2    = (bf16*) (w + 19984384);      //    331,776
    bf16*  wA3    = (bf16*) (w + 20316160);      //    442,368 (padded to 256 co)
    bf16*  wAm1   = (bf16*) (w + 20758528);      //     36,864
    bf16*  wAm2   = (bf16*) (w + 20795392);      //     36,864
    float* biasf  = (float*)(w + 20832256);      //      8,192
    int*   flag   = (int*)  (w + 20840448);      //        256
    // region A (14,680,064): cat[gp][224] (build->conv1,q_gemm) then xbuf f32 (o_gemm->mlp2)
    char*  regA   = w + 20840704;
    // region B (14,155,776): r1b (conv1->conv2) / off3 (conv3->dka) / hb (mlp1->mlp2)
    char*  regB   = w + 35520768;
    // region C (6,291,456): r2b (conv2->conv3) / q_bf (q_gemm->dka) / xb_bf (o_gemm->mlp1)
    char*  regC   = w + 49676544;
    // region D (6,291,456): o_bf (dka->o_gemm)
    char*  regD   = w + 55968000;
    // total 62,259,456 bytes

    bf16*  cat   = (bf16*) regA;
    float* xbuf  = (float*)regA;
    bf16*  r1b   = (bf16*) regB;
    bf16*  off3  = (bf16*) regB;
    bf16*  hb    = (bf16*) regB;
    bf16*  r2b   = (bf16*) regC;
    bf16*  q_bf  = (bf16*) regC;
    bf16*  xb_bf = (bf16*) regC;
    bf16*  o_bf  = (bf16*) regD;

    detect_dtype<<<1, 256, 0, stream>>>((const unsigned short*)d_in[0], flag);

    prep_all<<<12288, 256, 0, stream>>>(flag,
        d_in[0], d_in[1], d_in[2],
        d_in[3], d_in[4], d_in[5], d_in[6], d_in[7], d_in[8], d_in[9], d_in[10],
        d_in[11], d_in[12], d_in[13], d_in[14], d_in[15], d_in[16], d_in[17], d_in[18],
        d_in[19], d_in[20], d_in[21], d_in[22],
        ftf, fkvclb, flowf, wAq, wAo, wAkv, wA1, wA2, wA3, wAm1, wAm2, biasf);

    build_cat<<<(NPIX*28 + 255)/256, 256, 0, stream>>>(ftf, fkvclb, flowf, cat);

    // conv1: GY=4, COF=3 -> 1024 blocks (4/CU)
    conv_mfma<224, 224, 192, 3, 9, 0, 192, 4><<<1024, 256, 0, stream>>>(
        cat, wA1, biasf + 0,   biasf + 192, nullptr, flag, r1b, nullptr);
    // conv2: GY=3, COF=2 -> 768 blocks (3/CU)
    conv_mfma<192, 192,  96, 2, 9, 0,  96, 3><<<768, 256, 0, stream>>>(
        r1b, wA2, biasf + 384, biasf + 480, nullptr, flag, r2b, nullptr);
    // conv3: GY=4, COF=4 (COTOT=256 padded) -> 1024 blocks (4/CU)
    conv_mfma< 96,  96, 256, 4, 9, 1, 216, 4><<<1024, 256, 0, stream>>>(
        r2b, wA3, biasf + 576, nullptr,     nullptr, flag, off3, nullptr);

    // q = Wq @ feat_t + bq  (reads feat_t channels from cat, stride 224)
    conv_mfma<224,  96,  96, 2, 1, 1,  96, 3><<<768, 256, 0, stream>>>(
        cat, wAq, biasf + 792, nullptr,     nullptr, flag, q_bf, nullptr);

    // fused deformable attention (sample + kv GEMM + softmax + o)
    dka_kernel<<<(NPIX + PPB - 1)/PPB, 256, 0, stream>>>(
        flowf, fkvclb, off3, q_bf, wAkv, biasf + 888, biasf + 984, o_bf);

    // x = feat_t + Wo @ o + bo  -> xbuf (f32 ch-major) + xb_bf (bf16 px-major)
    conv_mfma< 96,  96,  96, 2, 1, 4,  96, 3><<<768, 256, 0, stream>>>(
        o_bf, wAo, biasf + 1080, nullptr,   ftf,    flag, xbuf, xb_bf);

    conv_mfma< 96,  96, 192, 3, 1, 2, 192, 4><<<1024, 256, 0, stream>>>(
        xb_bf, wAm1, biasf + 1176, nullptr, nullptr, flag, hb, nullptr);
    conv_mfma<192, 192,  96, 2, 1, 3,  96, 3><<<768, 256, 0, stream>>>(
        hb,   wAm2, biasf + 1368, nullptr,  xbuf,   flag, d_out, nullptr);
}

// Round 9
// 374.404 us; speedup vs baseline: 5.4039x; 1.0027x over previous
//
#include <hip/hip_runtime.h>
#include <hip/hip_bf16.h>
#include <math.h>

typedef __hip_bfloat16 bf16;
typedef __attribute__((ext_vector_type(8))) short s16x8;
typedef __attribute__((ext_vector_type(4))) short s16x4;
typedef __attribute__((ext_vector_type(4))) float fx4;

#define Bv 2
#define Cv 96
#define Hv 128
#define Wv 128
#define Pv (Hv*Wv)          /* 16384 */
#define NPIX (Bv*Pv)        /* 32768 */
#define Gv 12
#define Kv 9
#define PPB 7               /* pixels per dka block */
#define NPT 64              /* 63 points + 1 pad    */

__device__ __forceinline__ float b2f(bf16 x) { return __bfloat162float(x); }
__device__ __forceinline__ bf16 f2b(float x) { return __float2bfloat16(x); }

// dual-dtype input load: isf=1 -> float32, isf=0 -> bf16
__device__ __forceinline__ float ldin(const void* p, size_t i, int isf) {
    return isf ? ((const float*)p)[i] : __bfloat162float(((const bf16*)p)[i]);
}

// ---------------------------------------------------------------------------
// dtype detection (f32 read as bf16 shows NaN/Inf bit patterns in low halves)
// ---------------------------------------------------------------------------
__global__ void detect_dtype(const unsigned short* __restrict__ x, int* __restrict__ flag)
{
    __shared__ int bad;
    if (threadIdx.x == 0) bad = 0;
    __syncthreads();
    int cnt = 0;
    for (int i = threadIdx.x; i < 32768; i += 256) {
        unsigned short u = x[i];
        if ((u & 0x7F80) == 0x7F80) cnt++;
    }
    atomicAdd(&bad, cnt);
    __syncthreads();
    if (threadIdx.x == 0) flag[0] = (bad > 0) ? 1 : 0;   // 1 = float32 inputs
}

// ---------------------------------------------------------------------------
// prep: convert inputs; build MFMA A-layout weight buffers (bf16).
// wA layout: [(t*NC + kc)*COTOT + co]*32 + kq*8 + j,  k-in-chunk = kq*8+j
// fkvclb: coalesced READ of fkv, scattered write (L2 merges partial lines).
// ---------------------------------------------------------------------------
__global__ void prep_all(const int* __restrict__ flag,
    const void* ft, const void* fkv, const void* flow,
    const void* cw1, const void* cb1, const void* a1,
    const void* cw2, const void* cb2, const void* a2,
    const void* cw3, const void* cb3,
    const void* wq, const void* bq, const void* wk, const void* bk,
    const void* wv, const void* bv, const void* wo, const void* bo,
    const void* wm1, const void* bm1, const void* wm2, const void* bm2,
    float* __restrict__ ftf, bf16* __restrict__ fkvclb, float* __restrict__ flowf,
    bf16* __restrict__ wAq, bf16* __restrict__ wAo, bf16* __restrict__ wAkv,
    bf16* __restrict__ wA1, bf16* __restrict__ wA2, bf16* __restrict__ wA3,
    bf16* __restrict__ wAm1, bf16* __restrict__ wAm2,
    float* __restrict__ biasf)
{
    int isf = flag[0];
    size_t i = (size_t)blockIdx.x * 256 + threadIdx.x;
    if (i < (size_t)Bv*Cv*Pv) {
        ftf[i] = ldin(ft, i, isf);
        int b = (i >= (size_t)Cv*Pv) ? 1 : 0;
        int rem = (int)(i - (size_t)b*Cv*Pv);
        int c = rem >> 14;            // rem / Pv
        int p = rem & (Pv-1);
        fkvclb[((size_t)(b*Pv + p))*96 + c] = f2b(ldin(fkv, i, isf));
    }
    if (i < (size_t)Bv*2*Pv) flowf[i] = ldin(flow, i, isf);

    // conv1 weights: [192][194][9] -> wA1[t<9][kc<7][co<192][32]
    if (i < 9*7*192*32) {
        int q = (int)(i & 31);
        int rest = (int)(i >> 5);
        int co = rest % 192; rest /= 192;
        int kc = rest % 7;   int t = rest / 7;
        int ci = kc*32 + q;
        float v = (ci < 194) ? ldin(cw1, (size_t)co*194*9 + (size_t)ci*9 + t, isf) : 0.f;
        wA1[i] = f2b(v);
    }
    // conv2: [96][192][9] -> wA2[t<9][kc<6][co<96][32]
    if (i < 9*6*96*32) {
        int q = (int)(i & 31);
        int rest = (int)(i >> 5);
        int co = rest % 96; rest /= 96;
        int kc = rest % 6;  int t = rest / 6;
        int ci = kc*32 + q;
        wA2[i] = f2b(ldin(cw2, (size_t)co*192*9 + (size_t)ci*9 + t, isf));
    }
    // conv3: [216][96][9] -> wA3[t<9][kc<3][co<256][32], co>=216 zero
    if (i < 9*3*256*32) {
        int q = (int)(i & 31);
        int rest = (int)(i >> 5);
        int co = rest % 256; rest /= 256;
        int kc = rest % 3;   int t = rest / 3;
        int ci = kc*32 + q;
        float v = (co < 216) ? ldin(cw3, (size_t)co*96*9 + (size_t)ci*9 + t, isf) : 0.f;
        wA3[i] = f2b(v);
    }
    // mlp1: [192][96] -> wAm1[kc<3][co<192][32]
    if (i < 3*192*32) {
        int q = (int)(i & 31);
        int rest = (int)(i >> 5);
        int co = rest % 192;
        int kc = rest / 192;
        wAm1[i] = f2b(ldin(wm1, (size_t)co*96 + kc*32 + q, isf));
    }
    // mlp2: [96][192] -> wAm2[kc<6][co<96][32]
    if (i < 6*96*32) {
        int q = (int)(i & 31);
        int rest = (int)(i >> 5);
        int co = rest % 96;
        int kc = rest / 96;
        wAm2[i] = f2b(ldin(wm2, (size_t)co*192 + kc*32 + q, isf));
    }
    // wq / wo: [96][96] -> A-layout [kc<3][co<96][32]
    if (i < 3*96*32) {
        int q = (int)(i & 31);
        int rest = (int)(i >> 5);
        int co = rest % 96;
        int kc = rest / 96;
        wAq[i] = f2b(ldin(wq, (size_t)co*96 + kc*32 + q, isf));
        wAo[i] = f2b(ldin(wo, (size_t)co*96 + kc*32 + q, isf));
    }
    // wk/wv fused A-layout: wAkv[kc<3][co<192][32]; co<96 -> wk[co], co>=96 -> wv[co-96]
    if (i < 3*192*32) {
        int q = (int)(i & 31);
        int rest = (int)(i >> 5);
        int co = rest % 192;
        int kc = rest / 192;
        int ci = kc*32 + q;
        float v = (co < 96) ? ldin(wk, (size_t)co*96 + ci, isf)
                            : ldin(wv, (size_t)(co-96)*96 + ci, isf);
        wAkv[i] = f2b(v);
    }
    if (i < 192) biasf[i]       = ldin(cb1, i, isf);
    if (i < 192) biasf[192+i]   = ldin(a1, i, isf);
    if (i < 96)  biasf[384+i]   = ldin(cb2, i, isf);
    if (i < 96)  biasf[480+i]   = ldin(a2, i, isf);
    if (i < 216) biasf[576+i]   = ldin(cb3, i, isf);
    if (i < 96) {
        biasf[792+i]  = ldin(bq, i, isf);
        biasf[888+i]  = ldin(bk, i, isf);
        biasf[984+i]  = ldin(bv, i, isf);
        biasf[1080+i] = ldin(bo, i, isf);
        biasf[1368+i] = ldin(bm2, i, isf);
    }
    if (i < 192) biasf[1176+i] = ldin(bm1, i, isf);
}

// ---------------------------------------------------------------------------
// cat[gp][224] bf16 px-major. item = (pixel, 8-ch group): grp<12 = feat_t copy,
// 12..23 = flow-warped kv (4 x uint4 vectorized gather), 24 = flow+pad, 25..27 = 0.
// ---------------------------------------------------------------------------
__global__ void build_cat(const float* __restrict__ ftf, const bf16* __restrict__ fkvclb,
                          const float* __restrict__ flowf, bf16* __restrict__ cat)
{
    int idx = blockIdx.x * 256 + threadIdx.x;
    if (idx >= NPIX*28) return;
    int grp = idx % 28;
    int gp  = idx / 28;
    int p   = gp & (Pv-1);
    int bb  = gp >> 14;
    s16x8 st;
    if (grp < 12) {
        #pragma unroll
        for (int j = 0; j < 8; j++) {
            bf16 bv = f2b(ftf[((size_t)bb*Cv + grp*8 + j)*Pv + p]);
            st[j] = *(short*)&bv;
        }
    } else if (grp < 24) {
        int g = grp - 12;
        int py = p >> 7, px = p & (Wv-1);
        float xs = (float)px + flowf[((size_t)bb*2 + 0)*Pv + p];
        float ys = (float)py + flowf[((size_t)bb*2 + 1)*Pv + p];
        float x0f = floorf(xs), y0f = floorf(ys);
        float wx = xs - x0f, wy = ys - y0f;
        int x0 = (int)x0f, y0 = (int)y0f;
        const bf16* base = fkvclb + ((size_t)bb*Pv)*96 + g*8;
        float w[4]; uint4 t4[4];
        #pragma unroll
        for (int t = 0; t < 4; t++) {
            int xi = x0 + (t & 1), yi = y0 + (t >> 1);
            float wt = ((t & 1) ? wx : 1.f - wx) * ((t >> 1) ? wy : 1.f - wy);
            bool vld = (xi >= 0) & (xi < Wv) & (yi >= 0) & (yi < Hv);
            int xc = min(max(xi, 0), Wv-1), yc = min(max(yi, 0), Hv-1);
            w[t] = vld ? wt : 0.f;
            t4[t] = *(const uint4*)(base + (size_t)(yc*Wv + xc)*96);
        }
        float v[8];
        #pragma unroll
        for (int j = 0; j < 8; j++) v[j] = 0.f;
        #pragma unroll
        for (int t = 0; t < 4; t++) {
            const bf16* pp = (const bf16*)&t4[t];
            #pragma unroll
            for (int j = 0; j < 8; j++) v[j] += w[t] * b2f(pp[j]);
        }
        #pragma unroll
        for (int j = 0; j < 8; j++) { bf16 bv = f2b(v[j]); st[j] = *(short*)&bv; }
    } else if (grp == 24) {
        float fx = flowf[((size_t)bb*2 + 0)*Pv + p];
        float fy = flowf[((size_t)bb*2 + 1)*Pv + p];
        bf16 b0 = f2b(fx), b1 = f2b(fy);
        st[0] = *(short*)&b0; st[1] = *(short*)&b1;
        #pragma unroll
        for (int j = 2; j < 8; j++) st[j] = 0;
    } else {
        #pragma unroll
        for (int j = 0; j < 8; j++) st[j] = 0;
    }
    *(s16x8*)(cat + (size_t)gp*224 + grp*8) = st;
}

// ---------------------------------------------------------------------------
// MFMA implicit-GEMM conv/1x1. 1-D grid of 128*GY*Bv blocks, XCD-aware decode.
// Software pipeline: chunk kc+1 prefetched to VGPRs while MFMAs run on kc.
// MODE 0: PReLU -> bf16 px-major    MODE 1: plain -> bf16 px-major (guard co<216)
// ---------------------------------------------------------------------------
template<int CSTR, int CIN_PAD, int COTOT, int COF, int TAPS, int MODE, int OCS, int GY>
__launch_bounds__(256)
__global__ void conv_mfma(const bf16* __restrict__ in, const bf16* __restrict__ wA,
                          const float* __restrict__ bias, const float* __restrict__ alpha,
                          const float* __restrict__ resid, const int* __restrict__ flag,
                          void* __restrict__ outp, void* __restrict__ out2)
{
    constexpr int NC = CIN_PAD / 32;
    constexpr int LDS_PX = (TAPS == 9) ? 3*130 : 128;
    constexpr int NITEMS = LDS_PX * 4;
    constexpr int NSTG = (NITEMS + 255) / 256;
    __shared__ short sbuf[LDS_PX * 40];

    int tid = threadIdx.x;
    int wave = tid >> 6, lane = tid & 63;
    int n = lane & 15, kq = lane >> 4;

    int bid = blockIdx.x;
    int xcd = bid & 7, idx = bid >> 3;
    int y   = xcd * 16 + (idx & 15);
    int cob = ((idx >> 4) % GY) * (COF*16);
    int bb  = idx / (16*GY);

    uint4 pre[NSTG];
    auto ldst = [&](int kc) {
        #pragma unroll
        for (int s = 0; s < NSTG; s++) {
            int i = s*256 + tid;
            int ii = (i < NITEMS) ? i : (NITEMS-1);
            int part = ii & 3; int pxr = ii >> 2;
            const bf16* ap;
            if (TAPS == 9) {
                int r = pxr / 130; int px = pxr - r*130;
                int yy = y + r - 1, xx = px - 1;
                int yc = min(max(yy, 0), Hv-1), xc = min(max(xx, 0), Wv-1);
                ap = in + ((size_t)(bb*Pv + yc*Wv + xc)*CSTR + kc*32 + part*8);
            } else {
                ap = in + ((size_t)(bb*Pv + y*Wv + pxr)*CSTR + kc*32 + part*8);
            }
            pre[s] = *(const uint4*)ap;
        }
    };
    auto wrst = [&]() {
        #pragma unroll
        for (int s = 0; s < NSTG; s++) {
            int i = s*256 + tid;
            if (i < NITEMS) {
                int part = i & 3; int pxr = i >> 2;
                uint4 val = pre[s];
                if (TAPS == 9) {
                    int r = pxr / 130; int px = pxr - r*130;
                    int yy = y + r - 1, xx = px - 1;
                    if (!(yy >= 0 && yy < Hv && xx >= 0 && xx < Wv)) val = (uint4){0u,0u,0u,0u};
                    *(uint4*)&sbuf[(r*130 + px)*40 + part*8] = val;
                } else {
                    *(uint4*)&sbuf[pxr*40 + part*8] = val;
                }
            }
        }
    };

    fx4 acc[COF][2];
    #pragma unroll
    for (int f = 0; f < COF; f++)
        #pragma unroll
        for (int j = 0; j < 2; j++)
            acc[f][j] = (fx4){0.f, 0.f, 0.f, 0.f};

    ldst(0);
    for (int kc = 0; kc < NC; kc++) {
        wrst();
        __syncthreads();
        if (kc + 1 < NC) ldst(kc + 1);   // prefetch overlaps MFMA below
        #pragma unroll
        for (int t = 0; t < TAPS; t++) {
            const bf16* wbase = wA + ((size_t)(t*NC + kc)*COTOT + cob + n)*32 + kq*8;
            s16x8 af[COF];
            #pragma unroll
            for (int f = 0; f < COF; f++)
                af[f] = *(const s16x8*)(wbase + (size_t)f*16*32);
            #pragma unroll
            for (int j = 0; j < 2; j++) {
                int pxs;
                if (TAPS == 9) {
                    int r = t / 3, dx = t % 3;
                    pxs = r*130 + wave*32 + j*16 + n + dx;
                } else {
                    pxs = wave*32 + j*16 + n;
                }
                s16x8 bfr = *(const s16x8*)&sbuf[pxs*40 + kq*8];
                #pragma unroll
                for (int f = 0; f < COF; f++)
                    acc[f][j] = __builtin_amdgcn_mfma_f32_16x16x32_bf16(af[f], bfr, acc[f][j], 0, 0, 0);
            }
        }
        __syncthreads();   // WAR: all reads done before next wrst
    }

    // epilogue: D col=lane&15 (pixel), row=(lane>>4)*4+reg (co)
    int pxbase = wave*32;
    #pragma unroll
    for (int f = 0; f < COF; f++) {
        int co0 = cob + f*16 + kq*4;
        if (MODE == 1 && co0 >= 216) continue;
        #pragma unroll
        for (int j = 0; j < 2; j++) {
            int px = pxbase + j*16 + n;
            size_t gp = (size_t)bb*Pv + (size_t)y*Wv + px;
            fx4 fr = acc[f][j];
            s16x4 st;
            #pragma unroll
            for (int rg = 0; rg < 4; rg++) {
                float v = fr[rg] + bias[co0 + rg];
                if (MODE == 0) { float a = alpha[co0 + rg]; v = (v >= 0.f) ? v : a*v; }
                bf16 bvv = f2b(v);
                st[rg] = *(short*)&bvv;
            }
            *(s16x4*)((bf16*)outp + gp*OCS + co0) = st;
        }
    }
    (void)resid; (void)flag; (void)out2;
}

// ---------------------------------------------------------------------------
// Fused deformable attention: sample -> kv MFMA GEMM -> softmax -> o.
// Block 256 = 4 waves, 7 pixels = 63 points (+1 pad) per block.
// kv_s ALIASES s_s (phase 2 drains all s_s reads before the extra barrier),
// cutting LDS 38.9 -> 25.6 KB => 6 blocks/CU.
// ---------------------------------------------------------------------------
__launch_bounds__(256, 4)
__global__ void dka_kernel(const float* __restrict__ flowf, const bf16* __restrict__ fkvclb,
    const bf16* __restrict__ off3, const bf16* __restrict__ q_bf,
    const bf16* __restrict__ wAkv, const float* __restrict__ bkf, const float* __restrict__ bvf,
    bf16* __restrict__ o_bf)
{
    __shared__ short smem[NPT*200];     // union: s_s [pt][104] then kv_s [pt][200]
    short* s_s  = smem;
    short* kv_s = smem;

    int tid = threadIdx.x;
    int pb0 = blockIdx.x * PPB;

    // --- phase 1A: flow + offset loads for all 3 items ---
    float fxv[3], fyv[3]; unsigned owv[3];
    #pragma unroll
    for (int r = 0; r < 3; r++) {
        int it = r*256 + tid;           // 768 items = 64 pts x 12 groups
        int pt = it / 12, g = it - (it/12)*12;
        int pxl = pt / 9, k = pt - pxl*9;
        int gp0 = pb0 + pxl;
        bool act = (pt < 63) && (gp0 < NPIX);
        int gp = act ? gp0 : (NPIX-1);
        int bb = gp >> 14, p = gp & (Pv-1);
        fxv[r] = flowf[((size_t)bb*2 + 0)*Pv + p];
        fyv[r] = flowf[((size_t)bb*2 + 1)*Pv + p];
        owv[r] = *(const unsigned*)(off3 + (size_t)gp*216 + (g*9 + k)*2);  // (dy,dx)
    }
    // --- phase 1B: coords + all 12 gathers in flight ---
    float w[3][4]; uint4 t4[3][4];
    #pragma unroll
    for (int r = 0; r < 3; r++) {
        int it = r*256 + tid;
        int pt = it / 12, g = it - (it/12)*12;
        int pxl = pt / 9, k = pt - pxl*9;
        int gp0 = pb0 + pxl;
        bool act = (pt < 63) && (gp0 < NPIX);
        int gp = act ? gp0 : (NPIX-1);
        int bb = gp >> 14, p = gp & (Pv-1);
        int py = p >> 7, px = p & (Wv-1);
        unsigned ow = owv[r];
        unsigned short lo = (unsigned short)(ow & 0xFFFFu), hi = (unsigned short)(ow >> 16);
        float dy = b2f(*(bf16*)&lo) + fyv[r];
        float dx = b2f(*(bf16*)&hi) + fxv[r];
        float sx = (float)(px + (k % 3) - 1) + dx;
        float sy = (float)(py + (k / 3) - 1) + dy;
        float x0f = floorf(sx), y0f = floorf(sy);
        float wx = sx - x0f, wy = sy - y0f;
        int x0 = (int)x0f, y0 = (int)y0f;
        const bf16* base = fkvclb + ((size_t)bb*Pv)*96 + g*8;
        #pragma unroll
        for (int t = 0; t < 4; t++) {
            int xi = x0 + (t & 1), yi = y0 + (t >> 1);
            float wt = ((t & 1) ? wx : 1.f - wx) * ((t >> 1) ? wy : 1.f - wy);
            bool vld = (xi >= 0) & (xi < Wv) & (yi >= 0) & (yi < Hv);
            int xc = min(max(xi, 0), Wv-1), yc = min(max(yi, 0), Hv-1);
            w[r][t] = (act && vld) ? wt : 0.f;
            t4[r][t] = *(const uint4*)(base + (size_t)(yc*Wv + xc)*96);
        }
    }
    // --- phase 1C: accumulate + LDS store ---
    #pragma unroll
    for (int r = 0; r < 3; r++) {
        int it = r*256 + tid;
        int pt = it / 12, g = it - (it/12)*12;
        float v[8];
        #pragma unroll
        for (int j = 0; j < 8; j++) v[j] = 0.f;
        #pragma unroll
        for (int t = 0; t < 4; t++) {
            const bf16* pp = (const bf16*)&t4[r][t];
            #pragma unroll
            for (int j = 0; j < 8; j++) v[j] += w[r][t] * b2f(pp[j]);
        }
        s16x8 st;
        #pragma unroll
        for (int j = 0; j < 8; j++) { bf16 bv = f2b(v[j]); st[j] = *(short*)&bv; }
        *(s16x8*)&s_s[pt*104 + g*8] = st;
    }
    __syncthreads();

    // --- phase 2: kv = wAkv @ s  (M=192 split over waves, N=64, K=96) ---
    {
        int wave = tid >> 6, lane = tid & 63;
        int n = lane & 15, kq = lane >> 4;
        fx4 acc[3][4];
        #pragma unroll
        for (int mi = 0; mi < 3; mi++)
            #pragma unroll
            for (int nf = 0; nf < 4; nf++)
                acc[mi][nf] = (fx4){0.f, 0.f, 0.f, 0.f};
        #pragma unroll
        for (int kc = 0; kc < 3; kc++) {
            s16x8 b[4];
            #pragma unroll
            for (int nf = 0; nf < 4; nf++)
                b[nf] = *(const s16x8*)&s_s[(nf*16 + n)*104 + kc*32 + kq*8];
            #pragma unroll
            for (int mi = 0; mi < 3; mi++) {
                s16x8 a = *(const s16x8*)(wAkv + ((size_t)(kc*192 + (wave*3 + mi)*16 + n))*32 + kq*8);
                #pragma unroll
                for (int nf = 0; nf < 4; nf++)
                    acc[mi][nf] = __builtin_amdgcn_mfma_f32_16x16x32_bf16(a, b[nf], acc[mi][nf], 0, 0, 0);
            }
        }
        __syncthreads();   // all s_s reads drained; kv_s may now overwrite the region
        // phase 3: stage kv to LDS. D: col=point(lane&15), row=co((lane>>4)*4+rg)
        #pragma unroll
        for (int mi = 0; mi < 3; mi++)
            #pragma unroll
            for (int nf = 0; nf < 4; nf++) {
                s16x4 st;
                #pragma unroll
                for (int rg = 0; rg < 4; rg++) {
                    bf16 bv = f2b(acc[mi][nf][rg]);
                    st[rg] = *(short*)&bv;
                }
                *(s16x4*)&kv_s[(size_t)(nf*16 + n)*200 + (wave*3 + mi)*16 + kq*4] = st;
            }
    }
    __syncthreads();

    // --- phase 4: logits, softmax over 9 points, weighted v-sum, write o ---
    #pragma unroll
    for (int r = 0; r < 3; r++) {
        int idx = r*256 + tid;
        int pxl = idx / 96, c = idx - (idx/96)*96;
        int gp = pb0 + pxl;
        bool act = (pxl < PPB) && (gp < NPIX);   // uniform per 8-lane group
        float q = 0.f, bkc = 0.f, bvc = 0.f;
        if (act) { q = b2f(q_bf[(size_t)gp*96 + c]); bkc = bkf[c]; bvc = bvf[c]; }
        float lg[9];
        #pragma unroll
        for (int k = 0; k < 9; k++) {
            float kk = 0.f;
            if (act) kk = b2f(*(bf16*)&kv_s[(pxl*9 + k)*200 + c]) + bkc;
            float pr = q * kk;
            pr += __shfl_xor(pr, 1);
            pr += __shfl_xor(pr, 2);
            pr += __shfl_xor(pr, 4);
            lg[k] = pr * 0.35355339059327373f;   // 1/sqrt(8)
        }
        float m = lg[0];
        #pragma unroll
        for (int k = 1; k < 9; k++) m = fmaxf(m, lg[k]);
        float sum = 0.f;
        #pragma unroll
        for (int k = 0; k < 9; k++) { lg[k] = __expf(lg[k] - m); sum += lg[k]; }
        float inv = 1.f / sum;
        float ov = 0.f;
        #pragma unroll
        for (int k = 0; k < 9; k++) {
            float vv = 0.f;
            if (act) vv = b2f(*(bf16*)&kv_s[(pxl*9 + k)*200 + 96 + c]) + bvc;
            ov += (lg[k] * inv) * vv;
        }
        if (act) o_bf[(size_t)gp*96 + c] = f2b(ov);
    }
}

// ---------------------------------------------------------------------------
// Fused tail: x = Wo@o + bo + ft;  h = gelu(Wm1@x + bm1);  out = x + Wm2@h + bm2.
// One wave per block, 16 pixels. x kept in f32 regs for the final residual
// (no xbuf round-trip); ft residual read from cat (bf16 px-major, vectorized).
// ---------------------------------------------------------------------------
__launch_bounds__(64, 4)
__global__ void tail_kernel(const bf16* __restrict__ o_bf, const bf16* __restrict__ cat,
    const bf16* __restrict__ wAo, const bf16* __restrict__ wAm1, const bf16* __restrict__ wAm2,
    const float* __restrict__ bof, const float* __restrict__ bm1f, const float* __restrict__ bm2f,
    const int* __restrict__ flag, void* __restrict__ outp)
{
    __shared__ short o_s[16*104];
    __shared__ short x_s[16*104];
    __shared__ short h_s[16*200];
    int lane = threadIdx.x;
    int n = lane & 15, kq = lane >> 4;
    int gp0 = blockIdx.x * 16;

    // stage o tile: 16 px x 96 ch = 192 uint4
    for (int i = lane; i < 192; i += 64) {
        int px = (i*8)/96, c = (i*8) - ((i*8)/96)*96;
        *(uint4*)&o_s[px*104 + c] = *(const uint4*)(o_bf + (size_t)(gp0+px)*96 + c);
    }
    __syncthreads();

    int gp = gp0 + n;
    int p = gp & (Pv-1), bb = gp >> 14;

    // --- S1: x = Wo @ o + bo + ft ---
    fx4 xacc[6];
    #pragma unroll
    for (int f = 0; f < 6; f++) xacc[f] = (fx4){0.f,0.f,0.f,0.f};
    #pragma unroll
    for (int kc = 0; kc < 3; kc++) {
        s16x8 b = *(const s16x8*)&o_s[n*104 + kc*32 + kq*8];
        #pragma unroll
        for (int f = 0; f < 6; f++) {
            s16x8 a = *(const s16x8*)(wAo + ((size_t)(kc*96 + f*16 + n))*32 + kq*8);
            xacc[f] = __builtin_amdgcn_mfma_f32_16x16x32_bf16(a, b, xacc[f], 0, 0, 0);
        }
    }
    #pragma unroll
    for (int f = 0; f < 6; f++) {
        int co0 = f*16 + kq*4;
        s16x4 ft4 = *(const s16x4*)(cat + (size_t)gp*224 + co0);
        s16x4 st;
        #pragma unroll
        for (int rg = 0; rg < 4; rg++) {
            short sv = ft4[rg];
            xacc[f][rg] += bof[co0+rg] + b2f(*(bf16*)&sv);
            bf16 bv = f2b(xacc[f][rg]);
            st[rg] = *(short*)&bv;
        }
        *(s16x4*)&x_s[n*104 + co0] = st;
    }
    __syncthreads();

    // --- S2: h = gelu(Wm1 @ x + bm1), M=192 ---
    fx4 hacc[12];
    #pragma unroll
    for (int f = 0; f < 12; f++) hacc[f] = (fx4){0.f,0.f,0.f,0.f};
    #pragma unroll
    for (int kc = 0; kc < 3; kc++) {
        s16x8 b = *(const s16x8*)&x_s[n*104 + kc*32 + kq*8];
        #pragma unroll
        for (int f = 0; f < 12; f++) {
            s16x8 a = *(const s16x8*)(wAm1 + ((size_t)(kc*192 + f*16 + n))*32 + kq*8);
            hacc[f] = __builtin_amdgcn_mfma_f32_16x16x32_bf16(a, b, hacc[f], 0, 0, 0);
        }
    }
    #pragma unroll
    for (int f = 0; f < 12; f++) {
        int co0 = f*16 + kq*4;
        s16x4 st;
        #pragma unroll
        for (int rg = 0; rg < 4; rg++) {
            float v = hacc[f][rg] + bm1f[co0+rg];
            float t2 = __expf(1.5957691216057308f*(v + 0.044715f*v*v*v));
            v = v * t2 / (t2 + 1.f);   // fast tanh-GELU
            bf16 bv = f2b(v);
            st[rg] = *(short*)&bv;
        }
        *(s16x4*)&h_s[n*200 + co0] = st;
    }
    __syncthreads();

    // --- S3: out = x + Wm2 @ h + bm2, M=96, K=192 ---
    fx4 oacc[6];
    #pragma unroll
    for (int f = 0; f < 6; f++) oacc[f] = (fx4){0.f,0.f,0.f,0.f};
    #pragma unroll
    for (int kc = 0; kc < 6; kc++) {
        s16x8 b = *(const s16x8*)&h_s[n*200 + kc*32 + kq*8];
        #pragma unroll
        for (int f = 0; f < 6; f++) {
            s16x8 a = *(const s16x8*)(wAm2 + ((size_t)(kc*96 + f*16 + n))*32 + kq*8);
            oacc[f] = __builtin_amdgcn_mfma_f32_16x16x32_bf16(a, b, oacc[f], 0, 0, 0);
        }
    }
    int isf = flag[0];
    #pragma unroll
    for (int f = 0; f < 6; f++) {
        int co0 = f*16 + kq*4;
        #pragma unroll
        for (int rg = 0; rg < 4; rg++) {
            int co = co0 + rg;
            size_t oi = ((size_t)bb*Cv + co)*Pv + p;
            float v = oacc[f][rg] + bm2f[co] + xacc[f][rg];
            if (isf) ((float*)outp)[oi] = v;
            else     ((bf16*)outp)[oi] = f2b(v);
        }
    }
}

// ---------------------------------------------------------------------------
extern "C" void kernel_launch(void* const* d_in, const int* in_sizes, int n_in,
                              void* d_out, int out_size, void* d_ws, size_t ws_size,
                              hipStream_t stream) {
    (void)in_sizes; (void)n_in; (void)out_size; (void)ws_size;

    char* w = (char*)d_ws;
    float* ftf    = (float*)(w + 0);             // 12,582,912
    bf16*  fkvclb = (bf16*) (w + 12582912);      //  6,291,456
    float* flowf  = (float*)(w + 18874368);      //    262,144
    bf16*  wAkv   = (bf16*) (w + 19136512);      //     36,864
    bf16*  wAq    = (bf16*) (w + 19173376);      //     18,432
    bf16*  wAo    = (bf16*) (w + 19191808);      //     18,432
    bf16*  wA1    = (bf16*) (w + 19210240);      //    774,144
    bf16*  wA2    = (bf16*) (w + 19984384);      //    331,776
    bf16*  wA3    = (bf16*) (w + 20316160);      //    442,368 (padded to 256 co)
    bf16*  wAm1   = (bf16*) (w + 20758528);      //     36,864
    bf16*  wAm2   = (bf16*) (w + 20795392);      //     36,864
    float* biasf  = (float*)(w + 20832256);      //      8,192
    int*   flag   = (int*)  (w + 20840448);      //        256
    // region A (14,680,064): cat[gp][224] — live build_cat -> tail (residual source)
    char*  regA   = w + 20840704;
    // region B (14,155,776): r1b (conv1->conv2) / off3 (conv3->dka)
    char*  regB   = w + 35520768;
    // region C (6,291,456): r2b (conv2->conv3) / q_bf (q_gemm->dka)
    char*  regC   = w + 49676544;
    // region D (6,291,456): o_bf (dka->tail)
    char*  regD   = w + 55968000;
    // total 62,259,456 bytes

    bf16*  cat   = (bf16*) regA;
    bf16*  r1b   = (bf16*) regB;
    bf16*  off3  = (bf16*) regB;
    bf16*  r2b   = (bf16*) regC;
    bf16*  q_bf  = (bf16*) regC;
    bf16*  o_bf  = (bf16*) regD;

    detect_dtype<<<1, 256, 0, stream>>>((const unsigned short*)d_in[0], flag);

    prep_all<<<12288, 256, 0, stream>>>(flag,
        d_in[0], d_in[1], d_in[2],
        d_in[3], d_in[4], d_in[5], d_in[6], d_in[7], d_in[8], d_in[9], d_in[10],
        d_in[11], d_in[12], d_in[13], d_in[14], d_in[15], d_in[16], d_in[17], d_in[18],
        d_in[19], d_in[20], d_in[21], d_in[22],
        ftf, fkvclb, flowf, wAq, wAo, wAkv, wA1, wA2, wA3, wAm1, wAm2, biasf);

    build_cat<<<(NPIX*28 + 255)/256, 256, 0, stream>>>(ftf, fkvclb, flowf, cat);

    // conv1: GY=4, COF=3 -> 1024 blocks (4/CU)
    conv_mfma<224, 224, 192, 3, 9, 0, 192, 4><<<1024, 256, 0, stream>>>(
        cat, wA1, biasf + 0,   biasf + 192, nullptr, flag, r1b, nullptr);
    // conv2: GY=3, COF=2 -> 768 blocks (3/CU)
    conv_mfma<192, 192,  96, 2, 9, 0,  96, 3><<<768, 256, 0, stream>>>(
        r1b, wA2, biasf + 384, biasf + 480, nullptr, flag, r2b, nullptr);
    // conv3: GY=4, COF=4 (COTOT=256 padded) -> 1024 blocks (4/CU)
    conv_mfma< 96,  96, 256, 4, 9, 1, 216, 4><<<1024, 256, 0, stream>>>(
        r2b, wA3, biasf + 576, nullptr,     nullptr, flag, off3, nullptr);

    // q = Wq @ feat_t + bq  (reads feat_t channels from cat, stride 224)
    conv_mfma<224,  96,  96, 2, 1, 1,  96, 3><<<768, 256, 0, stream>>>(
        cat, wAq, biasf + 792, nullptr,     nullptr, flag, q_bf, nullptr);

    // fused deformable attention (sample + kv GEMM + softmax + o)
    dka_kernel<<<(NPIX + PPB - 1)/PPB, 256, 0, stream>>>(
        flowf, fkvclb, off3, q_bf, wAkv, biasf + 888, biasf + 984, o_bf);

    // fused tail: o-projection + residual + MLP1(GELU) + MLP2 + residual -> d_out
    tail_kernel<<<NPIX/16, 64, 0, stream>>>(
        o_bf, cat, wAo, wAm1, wAm2,
        biasf + 1080, biasf + 1176, biasf + 1368, flag, d_out);
}